// Round 2
// baseline (8406.424 us; speedup 1.0000x reference)
//
#include <hip/hip_runtime.h>
#include <math.h>

// Problem constants (fixed by the reference module)
#define NB 8
#define LTOK 4096
#define CH 384
#define DH 192
#define HH 64
#define WW 64

static constexpr long BLC  = (long)NB * LTOK * CH;   // 12,582,912 elements
static constexpr long XDBL = (long)NB * 2 * LTOK * 28;

__device__ inline float softplusf_(float x){ return x > 20.f ? x : log1pf(expf(x)); }

template<int NW>
__device__ inline float blockSum(float v, float* sm){
  #pragma unroll
  for (int o = 32; o > 0; o >>= 1) v += __shfl_down(v, o);
  int lane = threadIdx.x & 63, wv = threadIdx.x >> 6;
  if (lane == 0) sm[wv] = v;
  __syncthreads();
  if (threadIdx.x == 0){ float t = 0.f; for (int i = 0; i < NW; i++) t += sm[i]; sm[0] = t; }
  __syncthreads();
  float t = sm[0];
  __syncthreads();
  return t;
}

// ---------------- LayerNorm over C=384 per token ----------------
__global__ __launch_bounds__(128) void k_ln(const float* __restrict__ x,
    const float* __restrict__ g, const float* __restrict__ b, float* __restrict__ xn){
  __shared__ float sm[2];
  long row = blockIdx.x;
  int t = threadIdx.x;
  const float* xr = x + row * CH;
  float v0 = xr[t], v1 = xr[t + 128], v2 = xr[t + 256];
  float s = blockSum<2>(v0 + v1 + v2, sm);
  float m = s * (1.f / CH);
  float d0 = v0 - m, d1 = v1 - m, d2 = v2 - m;
  float vs = blockSum<2>(d0*d0 + d1*d1 + d2*d2, sm);
  float inv = rsqrtf(vs * (1.f / CH) + 1e-5f);
  float* o = xn + row * CH;
  o[t]       = d0 * inv * g[t]       + b[t];
  o[t + 128] = d1 * inv * g[t + 128] + b[t + 128];
  o[t + 256] = d2 * inv * g[t + 256] + b[t + 256];
}

// ---------------- partial pooling (deterministic 2-stage) ----------------
__global__ __launch_bounds__(128) void k_pool(const float* __restrict__ xn, float* __restrict__ pp){
  int c = blockIdx.x * 128 + threadIdx.x;     // 0..383
  int chunk = blockIdx.y, b = blockIdx.z;
  long base = ((long)b * LTOK + chunk * 256) * CH;
  float s = 0.f;
  for (int n = 0; n < 256; n++) s += xn[base + (long)n * CH + c];
  pp[((long)b * 16 + chunk) * CH + c] = s;
}

// ---------------- score MLP + stable argsort (descending) ----------------
__global__ __launch_bounds__(384) void k_score(const float* __restrict__ pp,
    const float* __restrict__ w1, const float* __restrict__ b1,
    const float* __restrict__ w2, const float* __restrict__ b2,
    int* __restrict__ sidx, int* __restrict__ inv){
  __shared__ float poolv[CH];
  __shared__ float hid[192];
  __shared__ float sc[CH];
  int b = blockIdx.x, t = threadIdx.x;
  float s = 0.f;
  for (int ch = 0; ch < 16; ch++) s += pp[((long)b * 16 + ch) * CH + t];
  poolv[t] = s * (1.f / LTOK);
  __syncthreads();
  if (t < 192){
    float h = b1[t];
    for (int c = 0; c < CH; c++) h += poolv[c] * w1[t * CH + c];
    hid[t] = fmaxf(h, 0.f);
  }
  __syncthreads();
  {
    float h = b2[t];
    for (int j = 0; j < 192; j++) h += hid[j] * w2[t * 192 + j];
    sc[t] = 1.f / (1.f + expf(-h));
  }
  __syncthreads();
  float mys = sc[t];
  int rank = 0;
  for (int j = 0; j < CH; j++){
    float o = sc[j];
    rank += (o > mys) || (o == mys && j < t);   // stable descending
  }
  sidx[b * CH + rank] = t;
  inv[b * CH + t] = rank;
}

// ---------------- generic fp32 GEMM: C = A @ B^T (+bias, +resid*scale) ----------------
__global__ __launch_bounds__(256) void k_gemm(
    const float* __restrict__ A, int lda, long aOuter, long aInner,
    const float* __restrict__ B, long bOuter, long bInner,
    float* __restrict__ C, int ldc, long cOuter, long cInner,
    int M, int N, int K, int innerCnt,
    const int* __restrict__ gidx, long gOuter, long gInner,
    const float* __restrict__ bias,
    const float* __restrict__ resid, const float* __restrict__ scale){
  int bz = blockIdx.z;
  int bo = bz / innerCnt, bi = bz - bo * innerCnt;
  const float* Ab = A + (long)bo * aOuter + (long)bi * aInner;
  const float* Bb = B + (long)bo * bOuter + (long)bi * bInner;
  float* Cb = C + (long)bo * cOuter + (long)bi * cInner;
  const int* gb = gidx ? gidx + (long)bo * gOuter + (long)bi * gInner : nullptr;

  __shared__ float As[16][65];
  __shared__ float Bs[16][65];
  int tid = threadIdx.x;
  int kl = tid & 15, rl = tid >> 4;
  int tx = tid & 15, ty = tid >> 4;
  int m0 = blockIdx.y << 6, n0 = blockIdx.x << 6;
  float acc[4][4] = {};
  for (int k0 = 0; k0 < K; k0 += 16){
    int kk = k0 + kl;
    int colA = gb ? gb[kk] : kk;
    #pragma unroll
    for (int p = 0; p < 4; p++){
      As[kl][rl + 16 * p] = Ab[(long)(m0 + rl + 16 * p) * lda + colA];
      Bs[kl][rl + 16 * p] = Bb[(long)(n0 + rl + 16 * p) * K + kk];
    }
    __syncthreads();
    #pragma unroll
    for (int q = 0; q < 16; q++){
      float a[4], bb[4];
      #pragma unroll
      for (int i = 0; i < 4; i++){ a[i] = As[q][ty + 16 * i]; bb[i] = Bs[q][tx + 16 * i]; }
      #pragma unroll
      for (int i = 0; i < 4; i++)
        #pragma unroll
        for (int j = 0; j < 4; j++) acc[i][j] += a[i] * bb[j];
    }
    __syncthreads();
  }
  #pragma unroll
  for (int i = 0; i < 4; i++){
    int m = m0 + ty + 16 * i;
    #pragma unroll
    for (int j = 0; j < 4; j++){
      int n = n0 + tx + 16 * j;
      float v = acc[i][j];
      if (bias) v += bias[n];
      if (resid) v = resid[(long)m * ldc + n] + scale[0] * v;
      Cb[(long)m * ldc + n] = v;
    }
  }
}

// ---------------- depthwise 3x3 conv + bias + silu, write in scan order ----------------
__global__ __launch_bounds__(256) void k_conv(const float* __restrict__ xc,
    const float* __restrict__ cw, const float* __restrict__ cb, float* __restrict__ xcv){
  long idx = (long)blockIdx.x * 256 + threadIdx.x;
  if (idx >= (long)NB * 2 * LTOK * DH) return;
  int di = (int)(idx % DH); long t = idx / DH;
  int p = (int)(t % LTOK); t /= LTOK;
  int g = (int)(t & 1); int b = (int)(t >> 1);
  int h = p >> 6, w = p & 63;
  const float* W = cw + ((long)g * DH + di) * 9;
  long sb = ((long)(b * 2 + g)) * LTOK;
  float s = cb[g * DH + di];
  #pragma unroll
  for (int dh = -1; dh <= 1; dh++){
    int hh = h + dh; if (hh < 0 || hh >= HH) continue;
    #pragma unroll
    for (int dw = -1; dw <= 1; dw++){
      int ww2 = w + dw; if (ww2 < 0 || ww2 >= WW) continue;
      s += W[(dh + 1) * 3 + (dw + 1)] * xc[(sb + hh * WW + ww2) * DH + di];
    }
  }
  s = s / (1.f + expf(-s));                       // silu
  int lscan = (g == 0) ? p : (w * HH + h);        // vertical branch scans columns
  xcv[(sb + (long)lscan) * DH + di] = s;
}

// ---------------- x_dbl projection: 28 outputs (k=0:14, k=1:14) per position ----------------
__global__ __launch_bounds__(256) void k_xdbl(const float* __restrict__ xcv,
    const float* __restrict__ xpw, float* __restrict__ xdbl){
  int bg = blockIdx.y;             // b*2+g
  int g = bg & 1;
  int p0 = blockIdx.x * 8;
  __shared__ float wl[28][193];
  __shared__ float xr[8][192];
  int tid = threadIdx.x;
  for (int i = tid; i < 28 * 192; i += 256){ wl[i / 192][i % 192] = xpw[(long)g * 5376 + i]; }
  for (int i = tid; i < 8 * 192; i += 256){
    xr[i / 192][i % 192] = xcv[((long)bg * LTOK + p0 + i / 192) * DH + (i % 192)];
  }
  __syncthreads();
  int pos = tid >> 5, j = tid & 31;
  if (j < 28){
    float s = 0.f;
    for (int c = 0; c < 192; c++) s += xr[pos][c] * wl[j][c];
    xdbl[((long)bg * LTOK + p0 + pos) * 28 + j] = s;
  }
}

// ---------------- selective scan (S=1), one direction per launch ----------------
// k=0: ydir[l] = y ; k=1: ydir[l] += y  (accumulate both directions in one buffer)
__global__ __launch_bounds__(192) void k_scan(const float* __restrict__ xcv,
    const float* __restrict__ xdbl,
    const float* __restrict__ dtw, const float* __restrict__ dtb,
    const float* __restrict__ alog, const float* __restrict__ ds,
    float* __restrict__ ydir, int k){
  int b = blockIdx.x, g = blockIdx.y;
  int di = threadIdx.x;
  int gk = g * 2 + k;
  float w[12];
  const float* wp = dtw + ((long)gk * DH + di) * 12;
  #pragma unroll
  for (int r = 0; r < 12; r++) w[r] = wp[r];
  float bias = dtb[gk * DH + di];
  float A  = -expf(alog[gk * DH + di]);
  float Dv = ds[gk * DH + di];
  long bg = (long)b * 2 + g;
  const float* xc = xcv + bg * LTOK * DH;
  const float* xd = xdbl + bg * LTOK * 28 + k * 14;
  float* yo = ydir + bg * (long)LTOK * DH + di;
  float h = 0.f;
  int l = (k == 0) ? 0 : (LTOK - 1);
  int dl = (k == 0) ? 1 : -1;
  for (int s = 0; s < LTOK; s++, l += dl){
    const float* row = xd + (long)l * 28;
    float dr = bias;
    #pragma unroll
    for (int r = 0; r < 12; r++) dr += row[r] * w[r];
    float dt = softplusf_(dr);
    float Bv = row[12], Cv = row[13];
    float xv = xc[(long)l * DH + di];
    h = expf(dt * A) * h + dt * Bv * xv;
    float v = h * Cv + Dv * xv;
    if (k == 0) yo[(long)l * DH] = v;
    else        yo[(long)l * DH] += v;
  }
}

// ---------------- combine directions + out-LN + *silu(z) ----------------
__global__ __launch_bounds__(192) void k_combine(const float* __restrict__ ydir,
    const float* __restrict__ zr, const float* __restrict__ ong, const float* __restrict__ onb,
    float* __restrict__ ya){
  __shared__ float sm[3];
  int p = blockIdx.x; int bg = blockIdx.y; int g = bg & 1;
  int h = p >> 6, w = p & 63;
  int l = (g == 0) ? p : (w * HH + h);
  int di = threadIdx.x;
  float y = ydir[((long)bg * LTOK + l) * DH + di];
  float s = blockSum<3>(y, sm);
  float m = s * (1.f / DH);
  float d = y - m;
  float vs = blockSum<3>(d * d, sm);
  float inv = rsqrtf(vs * (1.f / DH) + 1e-5f);
  float yl = d * inv * ong[g * DH + di] + onb[g * DH + di];
  float z = zr[((long)bg * LTOK + p) * DH + di];
  ya[((long)bg * LTOK + p) * DH + di] = yl * (z / (1.f + expf(-z)));
}

// ---------------- gate MLP + un-sort gather + multiply ----------------
__global__ __launch_bounds__(384) void k_gate(const float* __restrict__ xn,
    const float* __restrict__ w1, const float* __restrict__ b1,
    const float* __restrict__ w2, const float* __restrict__ b2,
    const float* __restrict__ ycat, const int* __restrict__ inv,
    float* __restrict__ ga){
  __shared__ float xrow[CH];
  __shared__ float hid[24];
  long row = blockIdx.x;            // b*L + n
  int b = (int)(row >> 12);
  int t = threadIdx.x;
  xrow[t] = xn[row * CH + t];
  __syncthreads();
  int d = t >> 4, l16 = t & 15;
  float p = 0.f;
  for (int c = l16; c < CH; c += 16) p += xrow[c] * w1[d * CH + c];
  #pragma unroll
  for (int o = 8; o > 0; o >>= 1) p += __shfl_down(p, o, 16);
  if (l16 == 0) hid[d] = fmaxf(p + b1[d], 0.f);
  __syncthreads();
  float hsum = b2[t];
  #pragma unroll
  for (int j = 0; j < 24; j++) hsum += hid[j] * w2[t * 24 + j];
  float gate = 1.f / (1.f + expf(-hsum));
  float yr = ycat[row * CH + inv[b * CH + t]];
  ga[row * CH + t] = yr * gate;
}

extern "C" void kernel_launch(void* const* d_in, const int* in_sizes, int n_in,
                              void* d_out, int out_size, void* d_ws, size_t ws_size,
                              hipStream_t stream){
  const float* x       = (const float*)d_in[0];
  const float* norm_g  = (const float*)d_in[1];
  const float* norm_b  = (const float*)d_in[2];
  const float* r_w1    = (const float*)d_in[3];
  const float* r_b1    = (const float*)d_in[4];
  const float* r_w2    = (const float*)d_in[5];
  const float* r_b2    = (const float*)d_in[6];
  const float* in_proj = (const float*)d_in[7];
  const float* conv_w  = (const float*)d_in[8];
  const float* conv_b  = (const float*)d_in[9];
  const float* xp_w    = (const float*)d_in[10];
  const float* dt_w    = (const float*)d_in[11];
  const float* dt_b    = (const float*)d_in[12];
  const float* A_log   = (const float*)d_in[13];
  const float* Ds      = (const float*)d_in[14];
  const float* on_g    = (const float*)d_in[15];
  const float* on_b    = (const float*)d_in[16];
  const float* op_w    = (const float*)d_in[17];
  const float* ci_w1   = (const float*)d_in[18];
  const float* ci_b1   = (const float*)d_in[19];
  const float* ci_w2   = (const float*)d_in[20];
  const float* ci_b2   = (const float*)d_in[21];
  const float* proj_w  = (const float*)d_in[22];
  const float* proj_b  = (const float*)d_in[23];
  const float* skip    = (const float*)d_in[24];
  float* out = (float*)d_out;
  float* ws  = (float*)d_ws;

  // Compact workspace layout (floats): 4*BLC + XDBL + pool + idx  (~209 MB)
  float* xn   = ws;                 // BLC  LN output (live to end)
  float* buf1 = xn + BLC;           // BLC  xcp (pre-conv) -> ydir (scan out) -> ga
  float* buf2 = buf1 + BLC;         // BLC  zr (raw z)     -> ycat
  float* buf3 = buf2 + BLC;         // BLC  xcv (scan-order conv out) -> ya
  float* xdbl = buf3 + BLC;         // XDBL
  float* pp   = xdbl + XDBL;        // NB*16*CH pooling partials
  int*  sidx  = (int*)(pp + NB * 16 * CH);
  int*  inv   = sidx + NB * CH;

  size_t need = ((size_t)(4 * BLC + XDBL + NB * 16 * CH)) * 4 + (size_t)NB * CH * 2 * 4 + 4096;
  if (ws_size < need) return;   // diagnostic: leaves d_out zeroed -> absmax = max|ref|

  k_ln<<<NB * LTOK, 128, 0, stream>>>(x, norm_g, norm_b, xn);
  k_pool<<<dim3(3, 16, NB), 128, 0, stream>>>(xn, pp);
  k_score<<<NB, 384, 0, stream>>>(pp, r_w1, r_b1, r_w2, r_b2, sidx, inv);

  float* xcp = buf1;
  float* zr  = buf2;
  // in_proj: xc = gather(xn) @ W[0:192]^T ; z = gather(xn) @ W[192:384]^T
  k_gemm<<<dim3(3, LTOK / 64, NB * 2), 256, 0, stream>>>(
      xn, CH, (long)LTOK * CH, 0,
      in_proj, 0, (long)CH * DH,
      xcp, DH, (long)2 * LTOK * DH, (long)LTOK * DH,
      LTOK, DH, DH, 2,
      sidx, CH, DH,
      nullptr, nullptr, nullptr);
  k_gemm<<<dim3(3, LTOK / 64, NB * 2), 256, 0, stream>>>(
      xn, CH, (long)LTOK * CH, 0,
      in_proj + 192 * 192, 0, (long)CH * DH,
      zr, DH, (long)2 * LTOK * DH, (long)LTOK * DH,
      LTOK, DH, DH, 2,
      sidx, CH, DH,
      nullptr, nullptr, nullptr);

  float* xcv = buf3;
  k_conv<<<(int)(((long)NB * 2 * LTOK * DH + 255) / 256), 256, 0, stream>>>(xcp, conv_w, conv_b, xcv);
  k_xdbl<<<dim3(LTOK / 8, NB * 2), 256, 0, stream>>>(xcv, xp_w, xdbl);

  float* ydir = buf1;   // xcp dead after conv
  k_scan<<<dim3(NB, 2), 192, 0, stream>>>(xcv, xdbl, dt_w, dt_b, A_log, Ds, ydir, 0);
  k_scan<<<dim3(NB, 2), 192, 0, stream>>>(xcv, xdbl, dt_w, dt_b, A_log, Ds, ydir, 1);

  float* ya = buf3;     // xcv dead after scans
  k_combine<<<dim3(LTOK, NB * 2), 192, 0, stream>>>(ydir, zr, on_g, on_b, ya);

  float* ycat = buf2;   // zr dead after combine
  k_gemm<<<dim3(3, LTOK / 64, NB * 2), 256, 0, stream>>>(
      ya, DH, (long)2 * LTOK * DH, (long)LTOK * DH,
      op_w, 0, (long)DH * DH,
      ycat, CH, (long)LTOK * CH, DH,
      LTOK, DH, DH, 2,
      nullptr, 0, 0,
      nullptr, nullptr, nullptr);

  float* ga = buf1;     // ydir dead after combine
  k_gate<<<NB * LTOK, 384, 0, stream>>>(xn, ci_w1, ci_b1, ci_w2, ci_b2, ycat, inv, ga);

  // final: out = x + skip * (ga @ proj_w^T + proj_b)
  k_gemm<<<dim3(CH / 64, (NB * LTOK) / 64, 1), 256, 0, stream>>>(
      ga, CH, 0, 0,
      proj_w, 0, 0,
      out, CH, 0, 0,
      NB * LTOK, CH, CH, 1,
      nullptr, 0, 0,
      proj_b, x, skip);
}

// Round 3
// 1482.762 us; speedup vs baseline: 5.6694x; 5.6694x over previous
//
#include <hip/hip_runtime.h>
#include <math.h>

// Problem constants (fixed by the reference module)
#define NB 8
#define LTOK 4096
#define CH 384
#define DH 192
#define HH 64
#define WW 64
#define NCHK 64      // chunks per sequence
#define CHS 64       // steps per chunk (LTOK / NCHK)

static constexpr long BLC  = (long)NB * LTOK * CH;   // 12,582,912 elements
static constexpr long XDBL = (long)NB * 2 * LTOK * 28;
static constexpr long CSTATE = (long)NB * 2 * 2 * NCHK * DH;  // 393,216 per buffer

__device__ inline float softplusf_(float x){ return x > 20.f ? x : log1pf(expf(x)); }

template<int NW>
__device__ inline float blockSum(float v, float* sm){
  #pragma unroll
  for (int o = 32; o > 0; o >>= 1) v += __shfl_down(v, o);
  int lane = threadIdx.x & 63, wv = threadIdx.x >> 6;
  if (lane == 0) sm[wv] = v;
  __syncthreads();
  if (threadIdx.x == 0){ float t = 0.f; for (int i = 0; i < NW; i++) t += sm[i]; sm[0] = t; }
  __syncthreads();
  float t = sm[0];
  __syncthreads();
  return t;
}

// ---------------- LayerNorm over C=384 per token ----------------
__global__ __launch_bounds__(128) void k_ln(const float* __restrict__ x,
    const float* __restrict__ g, const float* __restrict__ b, float* __restrict__ xn){
  __shared__ float sm[2];
  long row = blockIdx.x;
  int t = threadIdx.x;
  const float* xr = x + row * CH;
  float v0 = xr[t], v1 = xr[t + 128], v2 = xr[t + 256];
  float s = blockSum<2>(v0 + v1 + v2, sm);
  float m = s * (1.f / CH);
  float d0 = v0 - m, d1 = v1 - m, d2 = v2 - m;
  float vs = blockSum<2>(d0*d0 + d1*d1 + d2*d2, sm);
  float inv = rsqrtf(vs * (1.f / CH) + 1e-5f);
  float* o = xn + row * CH;
  o[t]       = d0 * inv * g[t]       + b[t];
  o[t + 128] = d1 * inv * g[t + 128] + b[t + 128];
  o[t + 256] = d2 * inv * g[t + 256] + b[t + 256];
}

// ---------------- partial pooling (deterministic 2-stage) ----------------
__global__ __launch_bounds__(128) void k_pool(const float* __restrict__ xn, float* __restrict__ pp){
  int c = blockIdx.x * 128 + threadIdx.x;     // 0..383
  int chunk = blockIdx.y, b = blockIdx.z;
  long base = ((long)b * LTOK + chunk * 256) * CH;
  float s = 0.f;
  for (int n = 0; n < 256; n++) s += xn[base + (long)n * CH + c];
  pp[((long)b * 16 + chunk) * CH + c] = s;
}

// ---------------- score MLP + stable argsort (descending) ----------------
__global__ __launch_bounds__(384) void k_score(const float* __restrict__ pp,
    const float* __restrict__ w1, const float* __restrict__ b1,
    const float* __restrict__ w2, const float* __restrict__ b2,
    int* __restrict__ sidx, int* __restrict__ inv){
  __shared__ float poolv[CH];
  __shared__ float hid[192];
  __shared__ float sc[CH];
  int b = blockIdx.x, t = threadIdx.x;
  float s = 0.f;
  for (int ch = 0; ch < 16; ch++) s += pp[((long)b * 16 + ch) * CH + t];
  poolv[t] = s * (1.f / LTOK);
  __syncthreads();
  if (t < 192){
    float h = b1[t];
    for (int c = 0; c < CH; c++) h += poolv[c] * w1[t * CH + c];
    hid[t] = fmaxf(h, 0.f);
  }
  __syncthreads();
  {
    float h = b2[t];
    for (int j = 0; j < 192; j++) h += hid[j] * w2[t * 192 + j];
    sc[t] = 1.f / (1.f + expf(-h));
  }
  __syncthreads();
  float mys = sc[t];
  int rank = 0;
  for (int j = 0; j < CH; j++){
    float o = sc[j];
    rank += (o > mys) || (o == mys && j < t);   // stable descending
  }
  sidx[b * CH + rank] = t;
  inv[b * CH + t] = rank;
}

// ---------------- generic fp32 GEMM: C = A @ B^T (+bias, +resid*scale) ----------------
__global__ __launch_bounds__(256) void k_gemm(
    const float* __restrict__ A, int lda, long aOuter, long aInner,
    const float* __restrict__ B, long bOuter, long bInner,
    float* __restrict__ C, int ldc, long cOuter, long cInner,
    int M, int N, int K, int innerCnt,
    const int* __restrict__ gidx, long gOuter, long gInner,
    const float* __restrict__ bias,
    const float* __restrict__ resid, const float* __restrict__ scale){
  int bz = blockIdx.z;
  int bo = bz / innerCnt, bi = bz - bo * innerCnt;
  const float* Ab = A + (long)bo * aOuter + (long)bi * aInner;
  const float* Bb = B + (long)bo * bOuter + (long)bi * bInner;
  float* Cb = C + (long)bo * cOuter + (long)bi * cInner;
  const int* gb = gidx ? gidx + (long)bo * gOuter + (long)bi * gInner : nullptr;

  __shared__ float As[16][65];
  __shared__ float Bs[16][65];
  int tid = threadIdx.x;
  int kl = tid & 15, rl = tid >> 4;
  int tx = tid & 15, ty = tid >> 4;
  int m0 = blockIdx.y << 6, n0 = blockIdx.x << 6;
  float acc[4][4] = {};
  for (int k0 = 0; k0 < K; k0 += 16){
    int kk = k0 + kl;
    int colA = gb ? gb[kk] : kk;
    #pragma unroll
    for (int p = 0; p < 4; p++){
      As[kl][rl + 16 * p] = Ab[(long)(m0 + rl + 16 * p) * lda + colA];
      Bs[kl][rl + 16 * p] = Bb[(long)(n0 + rl + 16 * p) * K + kk];
    }
    __syncthreads();
    #pragma unroll
    for (int q = 0; q < 16; q++){
      float a[4], bb[4];
      #pragma unroll
      for (int i = 0; i < 4; i++){ a[i] = As[q][ty + 16 * i]; bb[i] = Bs[q][tx + 16 * i]; }
      #pragma unroll
      for (int i = 0; i < 4; i++)
        #pragma unroll
        for (int j = 0; j < 4; j++) acc[i][j] += a[i] * bb[j];
    }
    __syncthreads();
  }
  #pragma unroll
  for (int i = 0; i < 4; i++){
    int m = m0 + ty + 16 * i;
    #pragma unroll
    for (int j = 0; j < 4; j++){
      int n = n0 + tx + 16 * j;
      float v = acc[i][j];
      if (bias) v += bias[n];
      if (resid) v = resid[(long)m * ldc + n] + scale[0] * v;
      Cb[(long)m * ldc + n] = v;
    }
  }
}

// ---------------- depthwise 3x3 conv + bias + silu, write in scan order ----------------
__global__ __launch_bounds__(256) void k_conv(const float* __restrict__ xc,
    const float* __restrict__ cw, const float* __restrict__ cb, float* __restrict__ xcv){
  long idx = (long)blockIdx.x * 256 + threadIdx.x;
  if (idx >= (long)NB * 2 * LTOK * DH) return;
  int di = (int)(idx % DH); long t = idx / DH;
  int p = (int)(t % LTOK); t /= LTOK;
  int g = (int)(t & 1); int b = (int)(t >> 1);
  int h = p >> 6, w = p & 63;
  const float* W = cw + ((long)g * DH + di) * 9;
  long sb = ((long)(b * 2 + g)) * LTOK;
  float s = cb[g * DH + di];
  #pragma unroll
  for (int dh = -1; dh <= 1; dh++){
    int hh = h + dh; if (hh < 0 || hh >= HH) continue;
    #pragma unroll
    for (int dw = -1; dw <= 1; dw++){
      int ww2 = w + dw; if (ww2 < 0 || ww2 >= WW) continue;
      s += W[(dh + 1) * 3 + (dw + 1)] * xc[(sb + hh * WW + ww2) * DH + di];
    }
  }
  s = s / (1.f + expf(-s));                       // silu
  int lscan = (g == 0) ? p : (w * HH + h);        // vertical branch scans columns
  xcv[(sb + (long)lscan) * DH + di] = s;
}

// ---------------- x_dbl projection: 28 outputs (k=0:14, k=1:14) per position ----------------
__global__ __launch_bounds__(256) void k_xdbl(const float* __restrict__ xcv,
    const float* __restrict__ xpw, float* __restrict__ xdbl){
  int bg = blockIdx.y;             // b*2+g
  int g = bg & 1;
  int p0 = blockIdx.x * 8;
  __shared__ float wl[28][193];
  __shared__ float xr[8][192];
  int tid = threadIdx.x;
  for (int i = tid; i < 28 * 192; i += 256){ wl[i / 192][i % 192] = xpw[(long)g * 5376 + i]; }
  for (int i = tid; i < 8 * 192; i += 256){
    xr[i / 192][i % 192] = xcv[((long)bg * LTOK + p0 + i / 192) * DH + (i % 192)];
  }
  __syncthreads();
  int pos = tid >> 5, j = tid & 31;
  if (j < 28){
    float s = 0.f;
    for (int c = 0; c < 192; c++) s += xr[pos][c] * wl[j][c];
    xdbl[((long)bg * LTOK + p0 + pos) * 28 + j] = s;
  }
}

// ---------------- chunked parallel selective scan (S=1) ----------------
// Phase 1: per (bg, k, chunk) compose 64 affine steps -> (P, S)
__global__ __launch_bounds__(192) void k_scan_p1(const float* __restrict__ xcv,
    const float* __restrict__ xdbl,
    const float* __restrict__ dtw, const float* __restrict__ dtb,
    const float* __restrict__ alog,
    float* __restrict__ cP, float* __restrict__ cS){
  int bg = blockIdx.x, k = blockIdx.y, c = blockIdx.z;
  int g = bg & 1;
  int di = threadIdx.x;
  int gk = g * 2 + k;
  float w[12];
  const float* wp = dtw + ((long)gk * DH + di) * 12;
  #pragma unroll
  for (int r = 0; r < 12; r++) w[r] = wp[r];
  float bias = dtb[gk * DH + di];
  float A = -expf(alog[gk * DH + di]);
  const float* xc = xcv + (long)bg * LTOK * DH;
  const float* xd = xdbl + (long)bg * LTOK * 28 + k * 14;
  float P = 1.f, S = 0.f;
  int l  = (k == 0) ? c * CHS : (LTOK - 1 - c * CHS);
  int dl = (k == 0) ? 1 : -1;
  for (int s = 0; s < CHS; s++, l += dl){
    const float* row = xd + (long)l * 28;
    float dr = bias;
    #pragma unroll
    for (int r = 0; r < 12; r++) dr += row[r] * w[r];
    float dt = softplusf_(dr);
    float a = expf(dt * A);
    float bx = dt * row[12] * xc[(long)l * DH + di];
    P *= a;
    S = a * S + bx;
  }
  long idx = (((long)(bg * 2 + k)) * NCHK + c) * DH + di;
  cP[idx] = P;
  cS[idx] = S;
}

// Phase 2: sequential composition over 64 chunks -> entry state h0 per chunk
__global__ __launch_bounds__(192) void k_scan_p2(const float* __restrict__ cP,
    const float* __restrict__ cS, float* __restrict__ h0){
  int bgk = blockIdx.x;            // 0..31
  int di = threadIdx.x;
  float h = 0.f;
  for (int c = 0; c < NCHK; c++){
    long idx = ((long)bgk * NCHK + c) * DH + di;
    h0[idx] = h;
    h = cP[idx] * h + cS[idx];
  }
}

// Phase 3: per (bg, chunk) recompute both directions from h0; write fwd, add bwd.
__global__ __launch_bounds__(192) void k_scan_p3(const float* __restrict__ xcv,
    const float* __restrict__ xdbl,
    const float* __restrict__ dtw, const float* __restrict__ dtb,
    const float* __restrict__ alog, const float* __restrict__ ds,
    const float* __restrict__ h0, float* __restrict__ ydir){
  int bg = blockIdx.x, c = blockIdx.y;
  int g = bg & 1;
  int di = threadIdx.x;
  const float* xc = xcv + (long)bg * LTOK * DH;
  float* yo = ydir + (long)bg * LTOK * DH + di;
  #pragma unroll
  for (int k = 0; k < 2; k++){
    int gk = g * 2 + k;
    float w[12];
    const float* wp = dtw + ((long)gk * DH + di) * 12;
    #pragma unroll
    for (int r = 0; r < 12; r++) w[r] = wp[r];
    float bias = dtb[gk * DH + di];
    float A  = -expf(alog[gk * DH + di]);
    float Dv = ds[gk * DH + di];
    const float* xd = xdbl + (long)bg * LTOK * 28 + k * 14;
    int cc = (k == 0) ? c : (NCHK - 1 - c);    // reverse-scan chunk covering same positions
    float h = h0[(((long)(bg * 2 + k)) * NCHK + cc) * DH + di];
    int l  = (k == 0) ? c * CHS : (c * CHS + CHS - 1);
    int dl = (k == 0) ? 1 : -1;
    for (int s = 0; s < CHS; s++, l += dl){
      const float* row = xd + (long)l * 28;
      float dr = bias;
      #pragma unroll
      for (int r = 0; r < 12; r++) dr += row[r] * w[r];
      float dt = softplusf_(dr);
      float a = expf(dt * A);
      float xv = xc[(long)l * DH + di];
      h = a * h + dt * row[12] * xv;
      float v = h * row[13] + Dv * xv;
      if (k == 0) yo[(long)l * DH] = v;
      else        yo[(long)l * DH] += v;
    }
  }
}

// ---------------- combine directions + out-LN + *silu(z) ----------------
__global__ __launch_bounds__(192) void k_combine(const float* __restrict__ ydir,
    const float* __restrict__ zr, const float* __restrict__ ong, const float* __restrict__ onb,
    float* __restrict__ ya){
  __shared__ float sm[3];
  int p = blockIdx.x; int bg = blockIdx.y; int g = bg & 1;
  int h = p >> 6, w = p & 63;
  int l = (g == 0) ? p : (w * HH + h);
  int di = threadIdx.x;
  float y = ydir[((long)bg * LTOK + l) * DH + di];
  float s = blockSum<3>(y, sm);
  float m = s * (1.f / DH);
  float d = y - m;
  float vs = blockSum<3>(d * d, sm);
  float inv = rsqrtf(vs * (1.f / DH) + 1e-5f);
  float yl = d * inv * ong[g * DH + di] + onb[g * DH + di];
  float z = zr[((long)bg * LTOK + p) * DH + di];
  ya[((long)bg * LTOK + p) * DH + di] = yl * (z / (1.f + expf(-z)));
}

// ---------------- gate MLP + un-sort gather + multiply ----------------
__global__ __launch_bounds__(384) void k_gate(const float* __restrict__ xn,
    const float* __restrict__ w1, const float* __restrict__ b1,
    const float* __restrict__ w2, const float* __restrict__ b2,
    const float* __restrict__ ycat, const int* __restrict__ inv,
    float* __restrict__ ga){
  __shared__ float xrow[CH];
  __shared__ float hid[24];
  long row = blockIdx.x;            // b*L + n
  int b = (int)(row >> 12);
  int t = threadIdx.x;
  xrow[t] = xn[row * CH + t];
  __syncthreads();
  int d = t >> 4, l16 = t & 15;
  float p = 0.f;
  for (int c = l16; c < CH; c += 16) p += xrow[c] * w1[d * CH + c];
  #pragma unroll
  for (int o = 8; o > 0; o >>= 1) p += __shfl_down(p, o, 16);
  if (l16 == 0) hid[d] = fmaxf(p + b1[d], 0.f);
  __syncthreads();
  float hsum = b2[t];
  #pragma unroll
  for (int j = 0; j < 24; j++) hsum += hid[j] * w2[t * 24 + j];
  float gate = 1.f / (1.f + expf(-hsum));
  float yr = ycat[row * CH + inv[b * CH + t]];
  ga[row * CH + t] = yr * gate;
}

extern "C" void kernel_launch(void* const* d_in, const int* in_sizes, int n_in,
                              void* d_out, int out_size, void* d_ws, size_t ws_size,
                              hipStream_t stream){
  const float* x       = (const float*)d_in[0];
  const float* norm_g  = (const float*)d_in[1];
  const float* norm_b  = (const float*)d_in[2];
  const float* r_w1    = (const float*)d_in[3];
  const float* r_b1    = (const float*)d_in[4];
  const float* r_w2    = (const float*)d_in[5];
  const float* r_b2    = (const float*)d_in[6];
  const float* in_proj = (const float*)d_in[7];
  const float* conv_w  = (const float*)d_in[8];
  const float* conv_b  = (const float*)d_in[9];
  const float* xp_w    = (const float*)d_in[10];
  const float* dt_w    = (const float*)d_in[11];
  const float* dt_b    = (const float*)d_in[12];
  const float* A_log   = (const float*)d_in[13];
  const float* Ds      = (const float*)d_in[14];
  const float* on_g    = (const float*)d_in[15];
  const float* on_b    = (const float*)d_in[16];
  const float* op_w    = (const float*)d_in[17];
  const float* ci_w1   = (const float*)d_in[18];
  const float* ci_b1   = (const float*)d_in[19];
  const float* ci_w2   = (const float*)d_in[20];
  const float* ci_b2   = (const float*)d_in[21];
  const float* proj_w  = (const float*)d_in[22];
  const float* proj_b  = (const float*)d_in[23];
  const float* skip    = (const float*)d_in[24];
  float* out = (float*)d_out;
  float* ws  = (float*)d_ws;

  // Workspace layout (floats): 4*BLC + XDBL + pool + idx + 3*CSTATE (~214 MB)
  float* xn   = ws;                 // BLC  LN output (live to end)
  float* buf1 = xn + BLC;           // BLC  xcp (pre-conv) -> ydir (scan out) -> ga
  float* buf2 = buf1 + BLC;         // BLC  zr (raw z)     -> ycat
  float* buf3 = buf2 + BLC;         // BLC  xcv (scan-order conv out) -> ya
  float* xdbl = buf3 + BLC;         // XDBL
  float* pp   = xdbl + XDBL;        // NB*16*CH pooling partials
  int*  sidx  = (int*)(pp + NB * 16 * CH);
  int*  inv   = sidx + NB * CH;
  float* cP   = (float*)(inv + NB * CH);
  float* cS   = cP + CSTATE;
  float* h0   = cS + CSTATE;

  size_t need = ((size_t)(4 * BLC + XDBL + NB * 16 * CH + 3 * CSTATE)) * 4
              + (size_t)NB * CH * 2 * 4 + 4096;
  if (ws_size < need) return;   // diagnostic: leaves d_out zeroed -> absmax = max|ref|

  k_ln<<<NB * LTOK, 128, 0, stream>>>(x, norm_g, norm_b, xn);
  k_pool<<<dim3(3, 16, NB), 128, 0, stream>>>(xn, pp);
  k_score<<<NB, 384, 0, stream>>>(pp, r_w1, r_b1, r_w2, r_b2, sidx, inv);

  float* xcp = buf1;
  float* zr  = buf2;
  // in_proj: xc = gather(xn) @ W[0:192]^T ; z = gather(xn) @ W[192:384]^T
  k_gemm<<<dim3(3, LTOK / 64, NB * 2), 256, 0, stream>>>(
      xn, CH, (long)LTOK * CH, 0,
      in_proj, 0, (long)CH * DH,
      xcp, DH, (long)2 * LTOK * DH, (long)LTOK * DH,
      LTOK, DH, DH, 2,
      sidx, CH, DH,
      nullptr, nullptr, nullptr);
  k_gemm<<<dim3(3, LTOK / 64, NB * 2), 256, 0, stream>>>(
      xn, CH, (long)LTOK * CH, 0,
      in_proj + 192 * 192, 0, (long)CH * DH,
      zr, DH, (long)2 * LTOK * DH, (long)LTOK * DH,
      LTOK, DH, DH, 2,
      sidx, CH, DH,
      nullptr, nullptr, nullptr);

  float* xcv = buf3;
  k_conv<<<(int)(((long)NB * 2 * LTOK * DH + 255) / 256), 256, 0, stream>>>(xcp, conv_w, conv_b, xcv);
  k_xdbl<<<dim3(LTOK / 8, NB * 2), 256, 0, stream>>>(xcv, xp_w, xdbl);

  // chunked parallel scan
  k_scan_p1<<<dim3(NB * 2, 2, NCHK), 192, 0, stream>>>(xcv, xdbl, dt_w, dt_b, A_log, cP, cS);
  k_scan_p2<<<NB * 2 * 2, 192, 0, stream>>>(cP, cS, h0);
  float* ydir = buf1;   // xcp dead after conv
  k_scan_p3<<<dim3(NB * 2, NCHK), 192, 0, stream>>>(xcv, xdbl, dt_w, dt_b, A_log, Ds, h0, ydir);

  float* ya = buf3;     // xcv dead after scan p3
  k_combine<<<dim3(LTOK, NB * 2), 192, 0, stream>>>(ydir, zr, on_g, on_b, ya);

  float* ycat = buf2;   // zr dead after combine
  k_gemm<<<dim3(3, LTOK / 64, NB * 2), 256, 0, stream>>>(
      ya, DH, (long)2 * LTOK * DH, (long)LTOK * DH,
      op_w, 0, (long)DH * DH,
      ycat, CH, (long)LTOK * CH, DH,
      LTOK, DH, DH, 2,
      nullptr, 0, 0,
      nullptr, nullptr, nullptr);

  float* ga = buf1;     // ydir dead after combine
  k_gate<<<NB * LTOK, 384, 0, stream>>>(xn, ci_w1, ci_b1, ci_w2, ci_b2, ycat, inv, ga);

  // final: out = x + skip * (ga @ proj_w^T + proj_b)
  k_gemm<<<dim3(CH / 64, (NB * LTOK) / 64, 1), 256, 0, stream>>>(
      ga, CH, 0, 0,
      proj_w, 0, 0,
      out, CH, 0, 0,
      NB * LTOK, CH, CH, 1,
      nullptr, 0, 0,
      proj_b, x, skip);
}

// Round 4
// 820.591 us; speedup vs baseline: 10.2444x; 1.8069x over previous
//
#include <hip/hip_runtime.h>
#include <math.h>

// Problem constants (fixed by the reference module)
#define NB 8
#define LTOK 4096
#define CH 384
#define DH 192
#define HH 64
#define WW 64
#define NCHK 64      // chunks per sequence
#define CHS 64       // steps per chunk (LTOK / NCHK)

static constexpr long BLC  = (long)NB * LTOK * CH;   // 12,582,912 elements
static constexpr long XDBL = (long)NB * 2 * LTOK * 28;
static constexpr long CSTATE = (long)NB * 2 * 2 * NCHK * DH;  // 393,216 per buffer

typedef unsigned short u16;
typedef u16   u16x8 __attribute__((ext_vector_type(8)));
typedef short s16x8 __attribute__((ext_vector_type(8)));
typedef float f32x4 __attribute__((ext_vector_type(4)));

__device__ inline float softplusf_(float x){ return x > 20.f ? x : log1pf(expf(x)); }
__device__ inline u16 f2bf(float f){
  unsigned int u = __float_as_uint(f);
  return (u16)((u + 0x7FFFu + ((u >> 16) & 1u)) >> 16);
}
__device__ inline float bf2f(u16 h){ return __uint_as_float(((unsigned int)h) << 16); }

template<int NW>
__device__ inline float blockSum(float v, float* sm){
  #pragma unroll
  for (int o = 32; o > 0; o >>= 1) v += __shfl_down(v, o);
  int lane = threadIdx.x & 63, wv = threadIdx.x >> 6;
  if (lane == 0) sm[wv] = v;
  __syncthreads();
  if (threadIdx.x == 0){ float t = 0.f; for (int i = 0; i < NW; i++) t += sm[i]; sm[0] = t; }
  __syncthreads();
  float t = sm[0];
  __syncthreads();
  return t;
}

// ---------------- LayerNorm over C=384 per token ----------------
__global__ __launch_bounds__(128) void k_ln(const float* __restrict__ x,
    const float* __restrict__ g, const float* __restrict__ b, float* __restrict__ xn){
  __shared__ float sm[2];
  long row = blockIdx.x;
  int t = threadIdx.x;
  const float* xr = x + row * CH;
  float v0 = xr[t], v1 = xr[t + 128], v2 = xr[t + 256];
  float s = blockSum<2>(v0 + v1 + v2, sm);
  float m = s * (1.f / CH);
  float d0 = v0 - m, d1 = v1 - m, d2 = v2 - m;
  float vs = blockSum<2>(d0*d0 + d1*d1 + d2*d2, sm);
  float inv = rsqrtf(vs * (1.f / CH) + 1e-5f);
  float* o = xn + row * CH;
  o[t]       = d0 * inv * g[t]       + b[t];
  o[t + 128] = d1 * inv * g[t + 128] + b[t + 128];
  o[t + 256] = d2 * inv * g[t + 256] + b[t + 256];
}

// ---------------- partial pooling ----------------
__global__ __launch_bounds__(128) void k_pool(const float* __restrict__ xn, float* __restrict__ pp){
  int c = blockIdx.x * 128 + threadIdx.x;
  int chunk = blockIdx.y, b = blockIdx.z;
  long base = ((long)b * LTOK + chunk * 256) * CH;
  float s = 0.f;
  for (int n = 0; n < 256; n++) s += xn[base + (long)n * CH + c];
  pp[((long)b * 16 + chunk) * CH + c] = s;
}

// ---------------- score MLP + stable argsort (descending) ----------------
__global__ __launch_bounds__(384) void k_score(const float* __restrict__ pp,
    const float* __restrict__ w1, const float* __restrict__ b1,
    const float* __restrict__ w2, const float* __restrict__ b2,
    int* __restrict__ sidx, int* __restrict__ inv){
  __shared__ float poolv[CH];
  __shared__ float hid[192];
  __shared__ float sc[CH];
  int b = blockIdx.x, t = threadIdx.x;
  float s = 0.f;
  for (int ch = 0; ch < 16; ch++) s += pp[((long)b * 16 + ch) * CH + t];
  poolv[t] = s * (1.f / LTOK);
  __syncthreads();
  if (t < 192){
    float h = b1[t];
    for (int c = 0; c < CH; c++) h += poolv[c] * w1[t * CH + c];
    hid[t] = fmaxf(h, 0.f);
  }
  __syncthreads();
  {
    float h = b2[t];
    for (int j = 0; j < 192; j++) h += hid[j] * w2[t * 192 + j];
    sc[t] = 1.f / (1.f + expf(-h));
  }
  __syncthreads();
  float mys = sc[t];
  int rank = 0;
  for (int j = 0; j < CH; j++){
    float o = sc[j];
    rank += (o > mys) || (o == mys && j < t);
  }
  sidx[b * CH + rank] = t;
  inv[b * CH + t] = rank;
}

// ---------------- cast fp32 -> bf16 (weights) ----------------
__global__ __launch_bounds__(256) void k_cast(const float* __restrict__ s,
    u16* __restrict__ d, int n){
  int i = blockIdx.x * 256 + threadIdx.x;
  if (i < n) d[i] = f2bf(s[i]);
}

// ---------------- gather sorted channels + cast to bf16 ----------------
__global__ __launch_bounds__(384) void k_castgather(const float* __restrict__ xn,
    const int* __restrict__ sidx, u16* __restrict__ As){
  long row = blockIdx.x;
  int b = (int)(row >> 12);
  int t = threadIdx.x;
  int c = sidx[b * CH + t];
  As[row * CH + t] = f2bf(xn[row * CH + c]);
}

// ---------------- bf16 MFMA GEMM: C = A @ B^T ----------------
// A (M,K) bf16 row-major lda; B (N,K) bf16 row-major ldb=K.
// MODE 1: split epilogue: n<192 -> Cf fp32 [m*192+n]; n>=192 -> Ch bf16 [m*192+n-192]
// MODE 2: Ch bf16 [m*ldc+n]
// MODE 3: Cf fp32 [m*ldc+n] = resid + skip*(v + bias[n])
template<int BN, int MODE>
__global__ __launch_bounds__(256) void k_mm(
    const u16* __restrict__ A, int lda, long aOuter, long aInner,
    const u16* __restrict__ B, long bInner,
    float* __restrict__ Cf, u16* __restrict__ Ch,
    long cOuter, long cInner, int ldc,
    int K, int innerCnt,
    const float* __restrict__ bias, const float* __restrict__ resid,
    const float* __restrict__ skip){
  constexpr int BM = 128;
  constexpr int AI = 2;                 // A stage issues (128*32 u16 / (256 thr * 8))
  constexpr int BI = (BN * 32) / (256 * 8); // 2 (BN=128) or 1 (BN=64)
  constexpr int NJ = BN / 32;           // N-frags per wave (4 or 2)
  __shared__ u16 sA[BM * 32];
  __shared__ u16 sB[BN * 32];

  int bz = blockIdx.z;
  int bo = bz / innerCnt, bi_ = bz - bo * innerCnt;
  const u16* Ab = A + (long)bo * aOuter + (long)bi_ * aInner;
  const u16* Bb = B + (long)bi_ * bInner;
  int tid = threadIdx.x;
  int m0 = blockIdx.y * BM, n0 = blockIdx.x * BN;
  int wv = tid >> 6, l = tid & 63;
  int wm = (wv >> 1) * 64, wn = (wv & 1) * (BN / 2);
  int kg = l >> 4, lr = l & 15;

  f32x4 acc[4][NJ];
  #pragma unroll
  for (int i = 0; i < 4; i++)
    #pragma unroll
    for (int j = 0; j < NJ; j++)
      #pragma unroll
      for (int r = 0; r < 4; r++) acc[i][j][r] = 0.f;

  // fragment LDS offsets (u16 units), XOR-swizzled: slot ^= (row&3)
  int aoffU[4], boffU[NJ];
  #pragma unroll
  for (int i = 0; i < 4; i++){
    int r = wm + i * 16 + lr;
    aoffU[i] = r * 32 + ((kg * 8) ^ ((r & 3) << 3));
  }
  #pragma unroll
  for (int j = 0; j < NJ; j++){
    int r = wn + j * 16 + lr;
    boffU[j] = r * 32 + ((kg * 8) ^ ((r & 3) << 3));
  }

  u16x8 ra[AI], rb[BI];
  // prefetch k0 = 0
  #pragma unroll
  for (int q = 0; q < AI; q++){
    int i = q * 256 + tid; int row = i >> 2, sl = i & 3, ss = sl ^ (row & 3);
    ra[q] = *(const u16x8*)(Ab + (long)(m0 + row) * lda + ss * 8);
  }
  #pragma unroll
  for (int q = 0; q < BI; q++){
    int i = q * 256 + tid; int row = i >> 2, sl = i & 3, ss = sl ^ (row & 3);
    rb[q] = *(const u16x8*)(Bb + (long)(n0 + row) * K + ss * 8);
  }

  int nks = K >> 5;
  for (int ks = 0; ks < nks; ks++){
    __syncthreads();   // previous compute done reading LDS
    #pragma unroll
    for (int q = 0; q < AI; q++){
      int i = q * 256 + tid; int row = i >> 2, sl = i & 3;
      *(u16x8*)(sA + row * 32 + sl * 8) = ra[q];
    }
    #pragma unroll
    for (int q = 0; q < BI; q++){
      int i = q * 256 + tid; int row = i >> 2, sl = i & 3;
      *(u16x8*)(sB + row * 32 + sl * 8) = rb[q];
    }
    __syncthreads();
    if (ks + 1 < nks){
      int k0 = (ks + 1) * 32;
      #pragma unroll
      for (int q = 0; q < AI; q++){
        int i = q * 256 + tid; int row = i >> 2, sl = i & 3, ss = sl ^ (row & 3);
        ra[q] = *(const u16x8*)(Ab + (long)(m0 + row) * lda + k0 + ss * 8);
      }
      #pragma unroll
      for (int q = 0; q < BI; q++){
        int i = q * 256 + tid; int row = i >> 2, sl = i & 3, ss = sl ^ (row & 3);
        rb[q] = *(const u16x8*)(Bb + (long)(n0 + row) * K + k0 + ss * 8);
      }
    }
    s16x8 af[4];
    #pragma unroll
    for (int i = 0; i < 4; i++) af[i] = *(const s16x8*)(sA + aoffU[i]);
    s16x8 bfr[NJ];
    #pragma unroll
    for (int j = 0; j < NJ; j++) bfr[j] = *(const s16x8*)(sB + boffU[j]);
    #pragma unroll
    for (int i = 0; i < 4; i++)
      #pragma unroll
      for (int j = 0; j < NJ; j++)
        acc[i][j] = __builtin_amdgcn_mfma_f32_16x16x32_bf16(af[i], bfr[j], acc[i][j], 0, 0, 0);
  }

  long zc = (long)bo * cOuter + (long)bi_ * cInner;
  #pragma unroll
  for (int i = 0; i < 4; i++){
    #pragma unroll
    for (int j = 0; j < NJ; j++){
      #pragma unroll
      for (int r = 0; r < 4; r++){
        int m = m0 + wm + i * 16 + kg * 4 + r;
        int n = n0 + wn + j * 16 + lr;
        float v = acc[i][j][r];
        if constexpr (MODE == 1){
          if (n < 192) Cf[zc + (long)m * 192 + n] = v;
          else         Ch[zc + (long)m * 192 + (n - 192)] = f2bf(v);
        } else if constexpr (MODE == 2){
          Ch[zc + (long)m * ldc + n] = f2bf(v);
        } else {
          float vb = v + bias[n];
          long o = (long)m * ldc + n;
          Cf[o] = resid[o] + skip[0] * vb;
        }
      }
    }
  }
}

// ---------------- depthwise 3x3 conv + bias + silu, write in scan order ----------------
__global__ __launch_bounds__(256) void k_conv(const float* __restrict__ xc,
    const float* __restrict__ cw, const float* __restrict__ cb, float* __restrict__ xcv){
  long idx = (long)blockIdx.x * 256 + threadIdx.x;
  if (idx >= (long)NB * 2 * LTOK * DH) return;
  int di = (int)(idx % DH); long t = idx / DH;
  int p = (int)(t % LTOK); t /= LTOK;
  int g = (int)(t & 1); int b = (int)(t >> 1);
  int h = p >> 6, w = p & 63;
  const float* W = cw + ((long)g * DH + di) * 9;
  long sb = ((long)(b * 2 + g)) * LTOK;
  float s = cb[g * DH + di];
  #pragma unroll
  for (int dh = -1; dh <= 1; dh++){
    int hh = h + dh; if (hh < 0 || hh >= HH) continue;
    #pragma unroll
    for (int dw = -1; dw <= 1; dw++){
      int ww2 = w + dw; if (ww2 < 0 || ww2 >= WW) continue;
      s += W[(dh + 1) * 3 + (dw + 1)] * xc[(sb + hh * WW + ww2) * DH + di];
    }
  }
  s = s / (1.f + expf(-s));                       // silu
  int lscan = (g == 0) ? p : (w * HH + h);        // vertical branch scans columns
  xcv[(sb + (long)lscan) * DH + di] = s;
}

// ---------------- x_dbl projection: 28 outputs per position ----------------
__global__ __launch_bounds__(256) void k_xdbl(const float* __restrict__ xcv,
    const float* __restrict__ xpw, float* __restrict__ xdbl){
  int bg = blockIdx.y;
  int g = bg & 1;
  int p0 = blockIdx.x * 8;
  __shared__ float wl[28][193];
  __shared__ float xr[8][192];
  int tid = threadIdx.x;
  for (int i = tid; i < 28 * 192; i += 256){ wl[i / 192][i % 192] = xpw[(long)g * 5376 + i]; }
  for (int i = tid; i < 8 * 192; i += 256){
    xr[i / 192][i % 192] = xcv[((long)bg * LTOK + p0 + i / 192) * DH + (i % 192)];
  }
  __syncthreads();
  int pos = tid >> 5, j = tid & 31;
  if (j < 28){
    float s = 0.f;
    for (int c = 0; c < 192; c++) s += xr[pos][c] * wl[j][c];
    xdbl[((long)bg * LTOK + p0 + pos) * 28 + j] = s;
  }
}

// ---------------- chunked parallel selective scan (S=1) ----------------
__global__ __launch_bounds__(192) void k_scan_p1(const float* __restrict__ xcv,
    const float* __restrict__ xdbl,
    const float* __restrict__ dtw, const float* __restrict__ dtb,
    const float* __restrict__ alog,
    float* __restrict__ cP, float* __restrict__ cS){
  int bg = blockIdx.x, k = blockIdx.y, c = blockIdx.z;
  int g = bg & 1;
  int di = threadIdx.x;
  int gk = g * 2 + k;
  float w[12];
  const float* wp = dtw + ((long)gk * DH + di) * 12;
  #pragma unroll
  for (int r = 0; r < 12; r++) w[r] = wp[r];
  float bias = dtb[gk * DH + di];
  float A = -expf(alog[gk * DH + di]);
  const float* xc = xcv + (long)bg * LTOK * DH;
  const float* xd = xdbl + (long)bg * LTOK * 28 + k * 14;
  float P = 1.f, S = 0.f;
  int l  = (k == 0) ? c * CHS : (LTOK - 1 - c * CHS);
  int dl = (k == 0) ? 1 : -1;
  for (int s = 0; s < CHS; s++, l += dl){
    const float* row = xd + (long)l * 28;
    float dr = bias;
    #pragma unroll
    for (int r = 0; r < 12; r++) dr += row[r] * w[r];
    float dt = softplusf_(dr);
    float a = expf(dt * A);
    float bx = dt * row[12] * xc[(long)l * DH + di];
    P *= a;
    S = a * S + bx;
  }
  long idx = (((long)(bg * 2 + k)) * NCHK + c) * DH + di;
  cP[idx] = P;
  cS[idx] = S;
}

__global__ __launch_bounds__(192) void k_scan_p2(const float* __restrict__ cP,
    const float* __restrict__ cS, float* __restrict__ h0){
  int bgk = blockIdx.x;
  int di = threadIdx.x;
  float h = 0.f;
  for (int c = 0; c < NCHK; c++){
    long idx = ((long)bgk * NCHK + c) * DH + di;
    h0[idx] = h;
    h = cP[idx] * h + cS[idx];
  }
}

__global__ __launch_bounds__(192) void k_scan_p3(const float* __restrict__ xcv,
    const float* __restrict__ xdbl,
    const float* __restrict__ dtw, const float* __restrict__ dtb,
    const float* __restrict__ alog, const float* __restrict__ ds,
    const float* __restrict__ h0, float* __restrict__ ydir){
  int bg = blockIdx.x, c = blockIdx.y;
  int g = bg & 1;
  int di = threadIdx.x;
  const float* xc = xcv + (long)bg * LTOK * DH;
  float* yo = ydir + (long)bg * LTOK * DH + di;
  #pragma unroll
  for (int k = 0; k < 2; k++){
    int gk = g * 2 + k;
    float w[12];
    const float* wp = dtw + ((long)gk * DH + di) * 12;
    #pragma unroll
    for (int r = 0; r < 12; r++) w[r] = wp[r];
    float bias = dtb[gk * DH + di];
    float A  = -expf(alog[gk * DH + di]);
    float Dv = ds[gk * DH + di];
    const float* xd = xdbl + (long)bg * LTOK * 28 + k * 14;
    int cc = (k == 0) ? c : (NCHK - 1 - c);
    float h = h0[(((long)(bg * 2 + k)) * NCHK + cc) * DH + di];
    int l  = (k == 0) ? c * CHS : (c * CHS + CHS - 1);
    int dl = (k == 0) ? 1 : -1;
    for (int s = 0; s < CHS; s++, l += dl){
      const float* row = xd + (long)l * 28;
      float dr = bias;
      #pragma unroll
      for (int r = 0; r < 12; r++) dr += row[r] * w[r];
      float dt = softplusf_(dr);
      float a = expf(dt * A);
      float xv = xc[(long)l * DH + di];
      h = a * h + dt * row[12] * xv;
      float v = h * row[13] + Dv * xv;
      if (k == 0) yo[(long)l * DH] = v;
      else        yo[(long)l * DH] += v;
    }
  }
}

// ---------------- combine directions + out-LN + *silu(z) -> bf16 ----------------
__global__ __launch_bounds__(192) void k_combine(const float* __restrict__ ydir,
    const u16* __restrict__ zh, const float* __restrict__ ong, const float* __restrict__ onb,
    u16* __restrict__ yab){
  __shared__ float sm[3];
  int p = blockIdx.x; int bg = blockIdx.y; int g = bg & 1;
  int h = p >> 6, w = p & 63;
  int l = (g == 0) ? p : (w * HH + h);
  int di = threadIdx.x;
  float y = ydir[((long)bg * LTOK + l) * DH + di];
  float s = blockSum<3>(y, sm);
  float m = s * (1.f / DH);
  float d = y - m;
  float vs = blockSum<3>(d * d, sm);
  float inv = rsqrtf(vs * (1.f / DH) + 1e-5f);
  float yl = d * inv * ong[g * DH + di] + onb[g * DH + di];
  float z = bf2f(zh[((long)bg * LTOK + p) * DH + di]);
  yab[((long)bg * LTOK + p) * DH + di] = f2bf(yl * (z / (1.f + expf(-z))));
}

// ---------------- gate MLP + un-sort gather + multiply -> bf16 ----------------
__global__ __launch_bounds__(384) void k_gate(const float* __restrict__ xn,
    const float* __restrict__ w1, const float* __restrict__ b1,
    const float* __restrict__ w2, const float* __restrict__ b2,
    const u16* __restrict__ ycat, const int* __restrict__ inv,
    u16* __restrict__ gab){
  __shared__ float xrow[CH];
  __shared__ float hid[24];
  long row = blockIdx.x;
  int b = (int)(row >> 12);
  int t = threadIdx.x;
  xrow[t] = xn[row * CH + t];
  __syncthreads();
  int d = t >> 4, l16 = t & 15;
  float p = 0.f;
  for (int c = l16; c < CH; c += 16) p += xrow[c] * w1[d * CH + c];
  #pragma unroll
  for (int o = 8; o > 0; o >>= 1) p += __shfl_down(p, o, 16);
  if (l16 == 0) hid[d] = fmaxf(p + b1[d], 0.f);
  __syncthreads();
  float hsum = b2[t];
  #pragma unroll
  for (int j = 0; j < 24; j++) hsum += hid[j] * w2[t * 24 + j];
  float gate = 1.f / (1.f + expf(-hsum));
  float yr = bf2f(ycat[row * CH + inv[b * CH + t]]);
  gab[row * CH + t] = f2bf(yr * gate);
}

extern "C" void kernel_launch(void* const* d_in, const int* in_sizes, int n_in,
                              void* d_out, int out_size, void* d_ws, size_t ws_size,
                              hipStream_t stream){
  const float* x       = (const float*)d_in[0];
  const float* norm_g  = (const float*)d_in[1];
  const float* norm_b  = (const float*)d_in[2];
  const float* r_w1    = (const float*)d_in[3];
  const float* r_b1    = (const float*)d_in[4];
  const float* r_w2    = (const float*)d_in[5];
  const float* r_b2    = (const float*)d_in[6];
  const float* in_proj = (const float*)d_in[7];
  const float* conv_w  = (const float*)d_in[8];
  const float* conv_b  = (const float*)d_in[9];
  const float* xp_w    = (const float*)d_in[10];
  const float* dt_w    = (const float*)d_in[11];
  const float* dt_b    = (const float*)d_in[12];
  const float* A_log   = (const float*)d_in[13];
  const float* Ds      = (const float*)d_in[14];
  const float* on_g    = (const float*)d_in[15];
  const float* on_b    = (const float*)d_in[16];
  const float* op_w    = (const float*)d_in[17];
  const float* ci_w1   = (const float*)d_in[18];
  const float* ci_b1   = (const float*)d_in[19];
  const float* ci_w2   = (const float*)d_in[20];
  const float* ci_b2   = (const float*)d_in[21];
  const float* proj_w  = (const float*)d_in[22];
  const float* proj_b  = (const float*)d_in[23];
  const float* skip    = (const float*)d_in[24];
  float* out = (float*)d_out;
  float* ws  = (float*)d_ws;

  // Workspace (floats): xn BLC | bufA BLC | bufB BLC/2 | bufC BLC | scr BLC/2 | small (~202 MB)
  float* xn   = ws;
  float* bufA = xn + BLC;           // xcb f32 -> ydir f32 -> gab bf16
  float* bufB = bufA + BLC;         // zh bf16 -> ycat bf16   (BLC u16 = BLC/2 floats)
  float* bufC = bufB + BLC / 2;     // xcv f32 -> yab bf16
  float* scr  = bufC + BLC;         // A_s bf16 -> xdbl + cP/cS/h0
  float* pp   = scr + BLC / 2;
  int*  sidx  = (int*)(pp + NB * 16 * CH);
  int*  inv   = sidx + NB * CH;
  u16*  wip   = (u16*)(inv + NB * CH);   // in_proj bf16: 2*384*192
  u16*  wop   = wip + 2 * 384 * 192;     // op_w bf16: 2*192*192
  u16*  wpj   = wop + 2 * 192 * 192;     // proj_w bf16: 384*384

  size_t need = ((size_t)(4 * BLC) + NB * 16 * CH) * 4
              + (size_t)NB * CH * 2 * 4 + (2*384*192 + 2*192*192 + 384*384) * 2 + 8192;
  if (ws_size < need) return;

  // aliases
  u16*  As   = (u16*)scr;                 // sorted bf16 activations (dead after in_proj mm)
  float* xcb = bufA;
  u16*  zh   = (u16*)bufB;
  float* xcv = bufC;
  float* xdbl = scr;                       // after As dead
  float* cP  = xdbl + XDBL;
  float* cS  = cP + CSTATE;
  float* h0  = cS + CSTATE;
  float* ydir = bufA;
  u16*  yab  = (u16*)bufC;
  u16*  ycat = (u16*)bufB;
  u16*  gab  = (u16*)bufA;

  k_ln<<<NB * LTOK, 128, 0, stream>>>(x, norm_g, norm_b, xn);
  k_cast<<<(2*384*192 + 255)/256, 256, 0, stream>>>(in_proj, wip, 2*384*192);
  k_cast<<<(2*192*192 + 255)/256, 256, 0, stream>>>(op_w,    wop, 2*192*192);
  k_cast<<<(384*384   + 255)/256, 256, 0, stream>>>(proj_w,  wpj, 384*384);
  k_pool<<<dim3(3, 16, NB), 128, 0, stream>>>(xn, pp);
  k_score<<<NB, 384, 0, stream>>>(pp, r_w1, r_b1, r_w2, r_b2, sidx, inv);
  k_castgather<<<NB * LTOK, 384, 0, stream>>>(xn, sidx, As);

  // in_proj: per (b,g): [4096x192]@[384x192]^T -> xc fp32 + z bf16 (split epilogue)
  k_mm<128, 1><<<dim3(3, 32, 16), 256, 0, stream>>>(
      As, CH, (long)LTOK * CH, 192,
      wip, (long)384 * 192,
      xcb, zh, (long)2 * LTOK * DH, (long)LTOK * DH, 0,
      192, 2, nullptr, nullptr, nullptr);

  k_conv<<<(int)(((long)NB * 2 * LTOK * DH + 255) / 256), 256, 0, stream>>>(xcb, conv_w, conv_b, xcv);
  k_xdbl<<<dim3(LTOK / 8, NB * 2), 256, 0, stream>>>(xcv, xp_w, xdbl);

  k_scan_p1<<<dim3(NB * 2, 2, NCHK), 192, 0, stream>>>(xcv, xdbl, dt_w, dt_b, A_log, cP, cS);
  k_scan_p2<<<NB * 2 * 2, 192, 0, stream>>>(cP, cS, h0);
  k_scan_p3<<<dim3(NB * 2, NCHK), 192, 0, stream>>>(xcv, xdbl, dt_w, dt_b, A_log, Ds, h0, ydir);

  k_combine<<<dim3(LTOK, NB * 2), 192, 0, stream>>>(ydir, zh, on_g, on_b, yab);

  // out_proj: per (b,g): [4096x192]@[192x192]^T -> ycat bf16 (col offset g*192)
  k_mm<64, 2><<<dim3(3, 32, 16), 256, 0, stream>>>(
      yab, DH, (long)2 * LTOK * DH, (long)LTOK * DH,
      wop, (long)192 * 192,
      nullptr, ycat, (long)LTOK * CH, 192, CH,
      192, 2, nullptr, nullptr, nullptr);

  k_gate<<<NB * LTOK, 384, 0, stream>>>(xn, ci_w1, ci_b1, ci_w2, ci_b2, ycat, inv, gab);

  // final: out = x + skip * (gab @ proj_w^T + proj_b)
  k_mm<128, 3><<<dim3(3, 256, 1), 256, 0, stream>>>(
      gab, CH, 0, 0,
      wpj, 0,
      out, nullptr, 0, 0, CH,
      CH, 1, proj_b, x, skip);
}

// Round 5
// 702.592 us; speedup vs baseline: 11.9649x; 1.1679x over previous
//
#include <hip/hip_runtime.h>
#include <math.h>

// Problem constants (fixed by the reference module)
#define NB 8
#define LTOK 4096
#define CH 384
#define DH 192
#define HH 64
#define WW 64
#define NCHK 64      // chunks per sequence
#define CHS 64       // steps per chunk (LTOK / NCHK)

static constexpr long BLC  = (long)NB * LTOK * CH;   // 12,582,912 elements
static constexpr long XDBL = (long)NB * 2 * LTOK * 28;
static constexpr long CSTATE = (long)NB * 2 * 2 * NCHK * DH;  // 393,216 per buffer

typedef unsigned short u16;
typedef u16   u16x8 __attribute__((ext_vector_type(8)));
typedef short s16x8 __attribute__((ext_vector_type(8)));
typedef float f32x4 __attribute__((ext_vector_type(4)));

__device__ inline float softplusf_(float x){ return x > 20.f ? x : log1pf(expf(x)); }
__device__ inline u16 f2bf(float f){
  unsigned int u = __float_as_uint(f);
  return (u16)((u + 0x7FFFu + ((u >> 16) & 1u)) >> 16);
}
__device__ inline float bf2f(u16 h){ return __uint_as_float(((unsigned int)h) << 16); }

template<int NW>
__device__ inline float blockSum(float v, float* sm){
  #pragma unroll
  for (int o = 32; o > 0; o >>= 1) v += __shfl_down(v, o);
  int lane = threadIdx.x & 63, wv = threadIdx.x >> 6;
  if (lane == 0) sm[wv] = v;
  __syncthreads();
  if (threadIdx.x == 0){ float t = 0.f; for (int i = 0; i < NW; i++) t += sm[i]; sm[0] = t; }
  __syncthreads();
  float t = sm[0];
  __syncthreads();
  return t;
}

// ---------------- LayerNorm over C=384 per token ----------------
__global__ __launch_bounds__(128) void k_ln(const float* __restrict__ x,
    const float* __restrict__ g, const float* __restrict__ b, float* __restrict__ xn){
  __shared__ float sm[2];
  long row = blockIdx.x;
  int t = threadIdx.x;
  const float* xr = x + row * CH;
  float v0 = xr[t], v1 = xr[t + 128], v2 = xr[t + 256];
  float s = blockSum<2>(v0 + v1 + v2, sm);
  float m = s * (1.f / CH);
  float d0 = v0 - m, d1 = v1 - m, d2 = v2 - m;
  float vs = blockSum<2>(d0*d0 + d1*d1 + d2*d2, sm);
  float inv = rsqrtf(vs * (1.f / CH) + 1e-5f);
  float* o = xn + row * CH;
  o[t]       = d0 * inv * g[t]       + b[t];
  o[t + 128] = d1 * inv * g[t + 128] + b[t + 128];
  o[t + 256] = d2 * inv * g[t + 256] + b[t + 256];
}

// ---------------- partial pooling ----------------
__global__ __launch_bounds__(128) void k_pool(const float* __restrict__ xn, float* __restrict__ pp){
  int c = blockIdx.x * 128 + threadIdx.x;
  int chunk = blockIdx.y, b = blockIdx.z;
  long base = ((long)b * LTOK + chunk * 256) * CH;
  float s = 0.f;
  for (int n = 0; n < 256; n++) s += xn[base + (long)n * CH + c];
  pp[((long)b * 16 + chunk) * CH + c] = s;
}

// ---------------- score MLP + stable argsort (descending) ----------------
__global__ __launch_bounds__(384) void k_score(const float* __restrict__ pp,
    const float* __restrict__ w1, const float* __restrict__ b1,
    const float* __restrict__ w2, const float* __restrict__ b2,
    int* __restrict__ sidx, int* __restrict__ inv){
  __shared__ float poolv[CH];
  __shared__ float hid[192];
  __shared__ float sc[CH];
  int b = blockIdx.x, t = threadIdx.x;
  float s = 0.f;
  for (int ch = 0; ch < 16; ch++) s += pp[((long)b * 16 + ch) * CH + t];
  poolv[t] = s * (1.f / LTOK);
  __syncthreads();
  if (t < 192){
    float h = b1[t];
    for (int c = 0; c < CH; c++) h += poolv[c] * w1[t * CH + c];
    hid[t] = fmaxf(h, 0.f);
  }
  __syncthreads();
  {
    float h = b2[t];
    for (int j = 0; j < 192; j++) h += hid[j] * w2[t * 192 + j];
    sc[t] = 1.f / (1.f + expf(-h));
  }
  __syncthreads();
  float mys = sc[t];
  int rank = 0;
  for (int j = 0; j < CH; j++){
    float o = sc[j];
    rank += (o > mys) || (o == mys && j < t);
  }
  sidx[b * CH + rank] = t;
  inv[b * CH + t] = rank;
}

// ---------------- cast fp32 -> bf16 (weights) ----------------
__global__ __launch_bounds__(256) void k_cast(const float* __restrict__ s,
    u16* __restrict__ d, int n){
  int i = blockIdx.x * 256 + threadIdx.x;
  if (i < n) d[i] = f2bf(s[i]);
}

// ---------------- gather sorted channels + cast to bf16 ----------------
__global__ __launch_bounds__(384) void k_castgather(const float* __restrict__ xn,
    const int* __restrict__ sidx, u16* __restrict__ As){
  long row = blockIdx.x;
  int b = (int)(row >> 12);
  int t = threadIdx.x;
  int c = sidx[b * CH + t];
  As[row * CH + t] = f2bf(xn[row * CH + c]);
}

// ---------------- prep gate-MLP weights: gathered w1 (per batch), padded w2, b1 ----------------
__global__ __launch_bounds__(256) void k_prepw(const float* __restrict__ w1,
    const float* __restrict__ b1, const float* __restrict__ w2,
    const int* __restrict__ sidx, u16* __restrict__ w1g, u16* __restrict__ w2p,
    float* __restrict__ b1p){
  int b = blockIdx.x, tid = threadIdx.x;
  if (b < NB){
    const int* sx = sidx + b * CH;
    for (int i = tid; i < 32 * CH; i += 256){
      int j = i / CH, r = i - j * CH;
      float v = (j < 24) ? w1[j * CH + sx[r]] : 0.f;
      w1g[(long)b * 32 * CH + i] = f2bf(v);
    }
  } else {
    for (int i = tid; i < CH * 32; i += 256){
      int n = i >> 5, j = i & 31;
      w2p[i] = f2bf((j < 24) ? w2[n * 24 + j] : 0.f);
    }
    if (tid < 32) b1p[tid] = (tid < 24) ? b1[tid] : 0.f;
  }
}

// ---------------- gate stage 1: hid = relu(As @ w1g^T + b1p), bf16 out ----------------
__global__ __launch_bounds__(256) void k_hid(const u16* __restrict__ As,
    const u16* __restrict__ w1g, const float* __restrict__ b1p,
    u16* __restrict__ hidp){
  __shared__ u16 sA[128 * 32];
  __shared__ u16 sB[32 * 32];
  int b = blockIdx.y;
  const u16* Ab = As + (long)b * LTOK * CH;
  const u16* Bb = w1g + (long)b * 32 * CH;
  int tid = threadIdx.x;
  int m0 = blockIdx.x * 128;
  int wv = tid >> 6, l = tid & 63;
  int wm = wv * 32;
  int kg = l >> 4, lr = l & 15;

  f32x4 acc[2][2];
  #pragma unroll
  for (int i = 0; i < 2; i++)
    #pragma unroll
    for (int j = 0; j < 2; j++)
      #pragma unroll
      for (int r = 0; r < 4; r++) acc[i][j][r] = 0.f;

  int aoffU[2], boffU[2];
  #pragma unroll
  for (int i = 0; i < 2; i++){
    int r = wm + i * 16 + lr;
    aoffU[i] = r * 32 + ((kg * 8) ^ ((r & 3) << 3));
  }
  #pragma unroll
  for (int j = 0; j < 2; j++){
    int r = j * 16 + lr;
    boffU[j] = r * 32 + ((kg * 8) ^ ((r & 3) << 3));
  }

  u16x8 ra[2], rbv;
  #pragma unroll
  for (int q = 0; q < 2; q++){
    int i = q * 256 + tid; int row = i >> 2, sl = i & 3, ss = sl ^ (row & 3);
    ra[q] = *(const u16x8*)(Ab + (long)(m0 + row) * CH + ss * 8);
  }
  if (tid < 128){
    int row = tid >> 2, sl = tid & 3, ss = sl ^ (row & 3);
    rbv = *(const u16x8*)(Bb + (long)row * CH + ss * 8);
  }

  const int nks = CH / 32;   // 12
  for (int ks = 0; ks < nks; ks++){
    __syncthreads();
    #pragma unroll
    for (int q = 0; q < 2; q++){
      int i = q * 256 + tid; int row = i >> 2, sl = i & 3;
      *(u16x8*)(sA + row * 32 + sl * 8) = ra[q];
    }
    if (tid < 128){
      int row = tid >> 2, sl = tid & 3;
      *(u16x8*)(sB + row * 32 + sl * 8) = rbv;
    }
    __syncthreads();
    if (ks + 1 < nks){
      int k0 = (ks + 1) * 32;
      #pragma unroll
      for (int q = 0; q < 2; q++){
        int i = q * 256 + tid; int row = i >> 2, sl = i & 3, ss = sl ^ (row & 3);
        ra[q] = *(const u16x8*)(Ab + (long)(m0 + row) * CH + k0 + ss * 8);
      }
      if (tid < 128){
        int row = tid >> 2, sl = tid & 3, ss = sl ^ (row & 3);
        rbv = *(const u16x8*)(Bb + (long)row * CH + k0 + ss * 8);
      }
    }
    s16x8 af[2], bfr[2];
    #pragma unroll
    for (int i = 0; i < 2; i++) af[i] = *(const s16x8*)(sA + aoffU[i]);
    #pragma unroll
    for (int j = 0; j < 2; j++) bfr[j] = *(const s16x8*)(sB + boffU[j]);
    #pragma unroll
    for (int i = 0; i < 2; i++)
      #pragma unroll
      for (int j = 0; j < 2; j++)
        acc[i][j] = __builtin_amdgcn_mfma_f32_16x16x32_bf16(af[i], bfr[j], acc[i][j], 0, 0, 0);
  }

  #pragma unroll
  for (int i = 0; i < 2; i++)
    #pragma unroll
    for (int j = 0; j < 2; j++)
      #pragma unroll
      for (int r = 0; r < 4; r++){
        int m = m0 + wm + i * 16 + kg * 4 + r;
        int n = j * 16 + lr;
        float v = fmaxf(acc[i][j][r] + b1p[n], 0.f);
        hidp[((long)b * LTOK + m) * 32 + n] = f2bf(v);
      }
}

// ---------------- bf16 MFMA GEMM: C = A @ B^T ----------------
// MODE 1: split epilogue: n<192 -> Cf fp32; n>=192 -> Ch bf16
// MODE 2: Ch bf16 [m*ldc+n]
// MODE 3: Cf fp32 = resid + skip*(v + bias[n])
// MODE 4: gate = sigmoid(v+bias[n]); Ch[m*ldc+n] = bf16(gate * bf2f(gy[m*ldc+ginv[(m>>12)*CH+n]]))
template<int BN, int MODE>
__global__ __launch_bounds__(256) void k_mm(
    const u16* __restrict__ A, int lda, long aOuter, long aInner,
    const u16* __restrict__ B, long bInner,
    float* __restrict__ Cf, u16* __restrict__ Ch,
    long cOuter, long cInner, int ldc,
    int K, int innerCnt,
    const float* __restrict__ bias, const float* __restrict__ resid,
    const float* __restrict__ skip,
    const u16* __restrict__ gy, const int* __restrict__ ginv){
  constexpr int BM = 128;
  constexpr int AI = 2;
  constexpr int BI = (BN * 32) / (256 * 8);
  constexpr int NJ = BN / 32;
  __shared__ u16 sA[BM * 32];
  __shared__ u16 sB[BN * 32];

  int bz = blockIdx.z;
  int bo = bz / innerCnt, bi_ = bz - bo * innerCnt;
  const u16* Ab = A + (long)bo * aOuter + (long)bi_ * aInner;
  const u16* Bb = B + (long)bi_ * bInner;
  int tid = threadIdx.x;
  int m0 = blockIdx.y * BM, n0 = blockIdx.x * BN;
  int wv = tid >> 6, l = tid & 63;
  int wm = (wv >> 1) * 64, wn = (wv & 1) * (BN / 2);
  int kg = l >> 4, lr = l & 15;

  f32x4 acc[4][NJ];
  #pragma unroll
  for (int i = 0; i < 4; i++)
    #pragma unroll
    for (int j = 0; j < NJ; j++)
      #pragma unroll
      for (int r = 0; r < 4; r++) acc[i][j][r] = 0.f;

  int aoffU[4], boffU[NJ];
  #pragma unroll
  for (int i = 0; i < 4; i++){
    int r = wm + i * 16 + lr;
    aoffU[i] = r * 32 + ((kg * 8) ^ ((r & 3) << 3));
  }
  #pragma unroll
  for (int j = 0; j < NJ; j++){
    int r = wn + j * 16 + lr;
    boffU[j] = r * 32 + ((kg * 8) ^ ((r & 3) << 3));
  }

  u16x8 ra[AI], rb[BI];
  #pragma unroll
  for (int q = 0; q < AI; q++){
    int i = q * 256 + tid; int row = i >> 2, sl = i & 3, ss = sl ^ (row & 3);
    ra[q] = *(const u16x8*)(Ab + (long)(m0 + row) * lda + ss * 8);
  }
  #pragma unroll
  for (int q = 0; q < BI; q++){
    int i = q * 256 + tid; int row = i >> 2, sl = i & 3, ss = sl ^ (row & 3);
    rb[q] = *(const u16x8*)(Bb + (long)(n0 + row) * K + ss * 8);
  }

  int nks = K >> 5;
  for (int ks = 0; ks < nks; ks++){
    __syncthreads();
    #pragma unroll
    for (int q = 0; q < AI; q++){
      int i = q * 256 + tid; int row = i >> 2, sl = i & 3;
      *(u16x8*)(sA + row * 32 + sl * 8) = ra[q];
    }
    #pragma unroll
    for (int q = 0; q < BI; q++){
      int i = q * 256 + tid; int row = i >> 2, sl = i & 3;
      *(u16x8*)(sB + row * 32 + sl * 8) = rb[q];
    }
    __syncthreads();
    if (ks + 1 < nks){
      int k0 = (ks + 1) * 32;
      #pragma unroll
      for (int q = 0; q < AI; q++){
        int i = q * 256 + tid; int row = i >> 2, sl = i & 3, ss = sl ^ (row & 3);
        ra[q] = *(const u16x8*)(Ab + (long)(m0 + row) * lda + k0 + ss * 8);
      }
      #pragma unroll
      for (int q = 0; q < BI; q++){
        int i = q * 256 + tid; int row = i >> 2, sl = i & 3, ss = sl ^ (row & 3);
        rb[q] = *(const u16x8*)(Bb + (long)(n0 + row) * K + k0 + ss * 8);
      }
    }
    s16x8 af[4];
    #pragma unroll
    for (int i = 0; i < 4; i++) af[i] = *(const s16x8*)(sA + aoffU[i]);
    s16x8 bfr[NJ];
    #pragma unroll
    for (int j = 0; j < NJ; j++) bfr[j] = *(const s16x8*)(sB + boffU[j]);
    #pragma unroll
    for (int i = 0; i < 4; i++)
      #pragma unroll
      for (int j = 0; j < NJ; j++)
        acc[i][j] = __builtin_amdgcn_mfma_f32_16x16x32_bf16(af[i], bfr[j], acc[i][j], 0, 0, 0);
  }

  long zc = (long)bo * cOuter + (long)bi_ * cInner;
  #pragma unroll
  for (int i = 0; i < 4; i++){
    #pragma unroll
    for (int j = 0; j < NJ; j++){
      #pragma unroll
      for (int r = 0; r < 4; r++){
        int m = m0 + wm + i * 16 + kg * 4 + r;
        int n = n0 + wn + j * 16 + lr;
        float v = acc[i][j][r];
        if constexpr (MODE == 1){
          if (n < 192) Cf[zc + (long)m * 192 + n] = v;
          else         Ch[zc + (long)m * 192 + (n - 192)] = f2bf(v);
        } else if constexpr (MODE == 2){
          Ch[zc + (long)m * ldc + n] = f2bf(v);
        } else if constexpr (MODE == 3){
          float vb = v + bias[n];
          long o = (long)m * ldc + n;
          Cf[o] = resid[o] + skip[0] * vb;
        } else {
          float gate = 1.f / (1.f + expf(-(v + bias[n])));
          int bt = m >> 12;
          float yr = bf2f(gy[(long)m * ldc + ginv[bt * CH + n]]);
          Ch[(long)m * ldc + n] = f2bf(yr * gate);
        }
      }
    }
  }
}

// ---------------- depthwise 3x3 conv + bias + silu, write in scan order ----------------
__global__ __launch_bounds__(256) void k_conv(const float* __restrict__ xc,
    const float* __restrict__ cw, const float* __restrict__ cb, float* __restrict__ xcv){
  long idx = (long)blockIdx.x * 256 + threadIdx.x;
  if (idx >= (long)NB * 2 * LTOK * DH) return;
  int di = (int)(idx % DH); long t = idx / DH;
  int p = (int)(t % LTOK); t /= LTOK;
  int g = (int)(t & 1); int b = (int)(t >> 1);
  int h = p >> 6, w = p & 63;
  const float* W = cw + ((long)g * DH + di) * 9;
  long sb = ((long)(b * 2 + g)) * LTOK;
  float s = cb[g * DH + di];
  #pragma unroll
  for (int dh = -1; dh <= 1; dh++){
    int hh = h + dh; if (hh < 0 || hh >= HH) continue;
    #pragma unroll
    for (int dw = -1; dw <= 1; dw++){
      int ww2 = w + dw; if (ww2 < 0 || ww2 >= WW) continue;
      s += W[(dh + 1) * 3 + (dw + 1)] * xc[(sb + hh * WW + ww2) * DH + di];
    }
  }
  s = s / (1.f + expf(-s));
  int lscan = (g == 0) ? p : (w * HH + h);
  xcv[(sb + (long)lscan) * DH + di] = s;
}

// ---------------- x_dbl projection: 28 outputs per position ----------------
__global__ __launch_bounds__(256) void k_xdbl(const float* __restrict__ xcv,
    const float* __restrict__ xpw, float* __restrict__ xdbl){
  int bg = blockIdx.y;
  int g = bg & 1;
  int p0 = blockIdx.x * 8;
  __shared__ float wl[28][193];
  __shared__ float xr[8][192];
  int tid = threadIdx.x;
  for (int i = tid; i < 28 * 192; i += 256){ wl[i / 192][i % 192] = xpw[(long)g * 5376 + i]; }
  for (int i = tid; i < 8 * 192; i += 256){
    xr[i / 192][i % 192] = xcv[((long)bg * LTOK + p0 + i / 192) * DH + (i % 192)];
  }
  __syncthreads();
  int pos = tid >> 5, j = tid & 31;
  if (j < 28){
    float s = 0.f;
    for (int c = 0; c < 192; c++) s += xr[pos][c] * wl[j][c];
    xdbl[((long)bg * LTOK + p0 + pos) * 28 + j] = s;
  }
}

// ---------------- chunked parallel selective scan (S=1) ----------------
__global__ __launch_bounds__(192) void k_scan_p1(const float* __restrict__ xcv,
    const float* __restrict__ xdbl,
    const float* __restrict__ dtw, const float* __restrict__ dtb,
    const float* __restrict__ alog,
    float* __restrict__ cP, float* __restrict__ cS){
  int bg = blockIdx.x, k = blockIdx.y, c = blockIdx.z;
  int g = bg & 1;
  int di = threadIdx.x;
  int gk = g * 2 + k;
  float w[12];
  const float* wp = dtw + ((long)gk * DH + di) * 12;
  #pragma unroll
  for (int r = 0; r < 12; r++) w[r] = wp[r];
  float bias = dtb[gk * DH + di];
  float A = -expf(alog[gk * DH + di]);
  const float* xc = xcv + (long)bg * LTOK * DH;
  const float* xd = xdbl + (long)bg * LTOK * 28 + k * 14;
  float P = 1.f, S = 0.f;
  int l  = (k == 0) ? c * CHS : (LTOK - 1 - c * CHS);
  int dl = (k == 0) ? 1 : -1;
  for (int s = 0; s < CHS; s++, l += dl){
    const float* row = xd + (long)l * 28;
    float dr = bias;
    #pragma unroll
    for (int r = 0; r < 12; r++) dr += row[r] * w[r];
    float dt = softplusf_(dr);
    float a = expf(dt * A);
    float bx = dt * row[12] * xc[(long)l * DH + di];
    P *= a;
    S = a * S + bx;
  }
  long idx = (((long)(bg * 2 + k)) * NCHK + c) * DH + di;
  cP[idx] = P;
  cS[idx] = S;
}

__global__ __launch_bounds__(192) void k_scan_p2(const float* __restrict__ cP,
    const float* __restrict__ cS, float* __restrict__ h0){
  int bgk = blockIdx.x;
  int di = threadIdx.x;
  float h = 0.f;
  for (int c = 0; c < NCHK; c++){
    long idx = ((long)bgk * NCHK + c) * DH + di;
    h0[idx] = h;
    h = cP[idx] * h + cS[idx];
  }
}

__global__ __launch_bounds__(192) void k_scan_p3(const float* __restrict__ xcv,
    const float* __restrict__ xdbl,
    const float* __restrict__ dtw, const float* __restrict__ dtb,
    const float* __restrict__ alog, const float* __restrict__ ds,
    const float* __restrict__ h0, float* __restrict__ ydir){
  int bg = blockIdx.x, c = blockIdx.y;
  int g = bg & 1;
  int di = threadIdx.x;
  const float* xc = xcv + (long)bg * LTOK * DH;
  float* yo = ydir + (long)bg * LTOK * DH + di;
  #pragma unroll
  for (int k = 0; k < 2; k++){
    int gk = g * 2 + k;
    float w[12];
    const float* wp = dtw + ((long)gk * DH + di) * 12;
    #pragma unroll
    for (int r = 0; r < 12; r++) w[r] = wp[r];
    float bias = dtb[gk * DH + di];
    float A  = -expf(alog[gk * DH + di]);
    float Dv = ds[gk * DH + di];
    const float* xd = xdbl + (long)bg * LTOK * 28 + k * 14;
    int cc = (k == 0) ? c : (NCHK - 1 - c);
    float h = h0[(((long)(bg * 2 + k)) * NCHK + cc) * DH + di];
    int l  = (k == 0) ? c * CHS : (c * CHS + CHS - 1);
    int dl = (k == 0) ? 1 : -1;
    for (int s = 0; s < CHS; s++, l += dl){
      const float* row = xd + (long)l * 28;
      float dr = bias;
      #pragma unroll
      for (int r = 0; r < 12; r++) dr += row[r] * w[r];
      float dt = softplusf_(dr);
      float a = expf(dt * A);
      float xv = xc[(long)l * DH + di];
      h = a * h + dt * row[12] * xv;
      float v = h * row[13] + Dv * xv;
      if (k == 0) yo[(long)l * DH] = v;
      else        yo[(long)l * DH] += v;
    }
  }
}

// ---------------- combine directions + out-LN + *silu(z) -> bf16 ----------------
__global__ __launch_bounds__(192) void k_combine(const float* __restrict__ ydir,
    const u16* __restrict__ zh, const float* __restrict__ ong, const float* __restrict__ onb,
    u16* __restrict__ yab){
  __shared__ float sm[3];
  int p = blockIdx.x; int bg = blockIdx.y; int g = bg & 1;
  int h = p >> 6, w = p & 63;
  int l = (g == 0) ? p : (w * HH + h);
  int di = threadIdx.x;
  float y = ydir[((long)bg * LTOK + l) * DH + di];
  float s = blockSum<3>(y, sm);
  float m = s * (1.f / DH);
  float d = y - m;
  float vs = blockSum<3>(d * d, sm);
  float inv = rsqrtf(vs * (1.f / DH) + 1e-5f);
  float yl = d * inv * ong[g * DH + di] + onb[g * DH + di];
  float z = bf2f(zh[((long)bg * LTOK + p) * DH + di]);
  yab[((long)bg * LTOK + p) * DH + di] = f2bf(yl * (z / (1.f + expf(-z))));
}

extern "C" void kernel_launch(void* const* d_in, const int* in_sizes, int n_in,
                              void* d_out, int out_size, void* d_ws, size_t ws_size,
                              hipStream_t stream){
  const float* x       = (const float*)d_in[0];
  const float* norm_g  = (const float*)d_in[1];
  const float* norm_b  = (const float*)d_in[2];
  const float* r_w1    = (const float*)d_in[3];
  const float* r_b1    = (const float*)d_in[4];
  const float* r_w2    = (const float*)d_in[5];
  const float* r_b2    = (const float*)d_in[6];
  const float* in_proj = (const float*)d_in[7];
  const float* conv_w  = (const float*)d_in[8];
  const float* conv_b  = (const float*)d_in[9];
  const float* xp_w    = (const float*)d_in[10];
  const float* dt_w    = (const float*)d_in[11];
  const float* dt_b    = (const float*)d_in[12];
  const float* A_log   = (const float*)d_in[13];
  const float* Ds      = (const float*)d_in[14];
  const float* on_g    = (const float*)d_in[15];
  const float* on_b    = (const float*)d_in[16];
  const float* op_w    = (const float*)d_in[17];
  const float* ci_w1   = (const float*)d_in[18];
  const float* ci_b1   = (const float*)d_in[19];
  const float* ci_w2   = (const float*)d_in[20];
  const float* ci_b2   = (const float*)d_in[21];
  const float* proj_w  = (const float*)d_in[22];
  const float* proj_b  = (const float*)d_in[23];
  const float* skip    = (const float*)d_in[24];
  float* out = (float*)d_out;
  float* ws  = (float*)d_ws;

  // Workspace (floats): xn BLC | bufA BLC | bufB BLC/2 | bufC BLC | scr BLC/2 | tail
  float* xn   = ws;
  float* bufA = xn + BLC;           // xcb f32 -> ydir f32 -> gab bf16
  float* bufB = bufA + BLC;         // zh bf16 -> ycat bf16
  float* bufC = bufB + BLC / 2;     // xcv f32 -> yab bf16
  float* scr  = bufC + BLC;         // As bf16 -> xdbl + cP/cS/h0
  float* pp   = scr + BLC / 2;
  int*  sidx  = (int*)(pp + NB * 16 * CH);
  int*  inv   = sidx + NB * CH;
  u16*  wip   = (u16*)(inv + NB * CH);   // in_proj bf16: 2*384*192
  u16*  wop   = wip + 2 * 384 * 192;     // op_w bf16: 2*192*192
  u16*  wpj   = wop + 2 * 192 * 192;     // proj_w bf16: 384*384
  u16*  w1g   = wpj + 384 * 384;         // gathered ci_w1: NB*32*384
  u16*  w2p   = w1g + NB * 32 * CH;      // padded ci_w2: 384*32
  float* b1p  = (float*)(w2p + CH * 32); // padded ci_b1: 32
  u16*  hidp  = (u16*)(b1p + 32);        // gate hidden: 32768*32 bf16

  size_t need = ((size_t)(4 * BLC) + NB * 16 * CH) * 4
              + (size_t)NB * CH * 2 * 4
              + (size_t)(2*384*192 + 2*192*192 + 384*384 + NB*32*CH + CH*32) * 2
              + 32 * 4 + (size_t)NB * LTOK * 32 * 2 + 8192;
  if (ws_size < need) return;

  // aliases
  u16*  As   = (u16*)scr;
  float* xcb = bufA;
  u16*  zh   = (u16*)bufB;
  float* xcv = bufC;
  float* xdbl = scr;                       // after As dead (post k_hid)
  float* cP  = xdbl + XDBL;
  float* cS  = cP + CSTATE;
  float* h0  = cS + CSTATE;
  float* ydir = bufA;
  u16*  yab  = (u16*)bufC;
  u16*  ycat = (u16*)bufB;
  u16*  gab  = (u16*)bufA;

  k_ln<<<NB * LTOK, 128, 0, stream>>>(x, norm_g, norm_b, xn);
  k_cast<<<(2*384*192 + 255)/256, 256, 0, stream>>>(in_proj, wip, 2*384*192);
  k_cast<<<(2*192*192 + 255)/256, 256, 0, stream>>>(op_w,    wop, 2*192*192);
  k_cast<<<(384*384   + 255)/256, 256, 0, stream>>>(proj_w,  wpj, 384*384);
  k_pool<<<dim3(3, 16, NB), 128, 0, stream>>>(xn, pp);
  k_score<<<NB, 384, 0, stream>>>(pp, r_w1, r_b1, r_w2, r_b2, sidx, inv);
  k_castgather<<<NB * LTOK, 384, 0, stream>>>(xn, sidx, As);
  k_prepw<<<NB + 1, 256, 0, stream>>>(ci_w1, ci_b1, ci_w2, sidx, w1g, w2p, b1p);

  // in_proj: per (b,g): [4096x192]@[384x192]^T -> xc fp32 + z bf16 (split epilogue)
  k_mm<128, 1><<<dim3(3, 32, 16), 256, 0, stream>>>(
      As, CH, (long)LTOK * CH, 192,
      wip, (long)384 * 192,
      xcb, zh, (long)2 * LTOK * DH, (long)LTOK * DH, 0,
      192, 2, nullptr, nullptr, nullptr, nullptr, nullptr);

  // gate stage 1 (uses As; must precede xdbl overwrite)
  k_hid<<<dim3(32, NB), 256, 0, stream>>>(As, w1g, b1p, hidp);

  k_conv<<<(int)(((long)NB * 2 * LTOK * DH + 255) / 256), 256, 0, stream>>>(xcb, conv_w, conv_b, xcv);
  k_xdbl<<<dim3(LTOK / 8, NB * 2), 256, 0, stream>>>(xcv, xp_w, xdbl);

  k_scan_p1<<<dim3(NB * 2, 2, NCHK), 192, 0, stream>>>(xcv, xdbl, dt_w, dt_b, A_log, cP, cS);
  k_scan_p2<<<NB * 2 * 2, 192, 0, stream>>>(cP, cS, h0);
  k_scan_p3<<<dim3(NB * 2, NCHK), 192, 0, stream>>>(xcv, xdbl, dt_w, dt_b, A_log, Ds, h0, ydir);

  k_combine<<<dim3(LTOK, NB * 2), 192, 0, stream>>>(ydir, zh, on_g, on_b, yab);

  // out_proj: per (b,g): [4096x192]@[192x192]^T -> ycat bf16 (col offset g*192)
  k_mm<64, 2><<<dim3(3, 32, 16), 256, 0, stream>>>(
      yab, DH, (long)2 * LTOK * DH, (long)LTOK * DH,
      wop, (long)192 * 192,
      nullptr, ycat, (long)LTOK * CH, 192, CH,
      192, 2, nullptr, nullptr, nullptr, nullptr, nullptr);

  // gate stage 2 + un-sort gather + multiply: gab = sigmoid(hid@w2p^T+b2) * ycat[inv]
  k_mm<128, 4><<<dim3(3, 256, 1), 256, 0, stream>>>(
      hidp, 32, 0, 0,
      w2p, 0,
      nullptr, gab, 0, 0, CH,
      32, 1, ci_b2, nullptr, nullptr, ycat, inv);

  // final: out = x + skip * (gab @ proj_w^T + proj_b)
  k_mm<128, 3><<<dim3(3, 256, 1), 256, 0, stream>>>(
      gab, CH, 0, 0,
      wpj, 0,
      out, nullptr, 0, 0, CH,
      CH, 1, proj_b, x, skip, nullptr, nullptr);
}

// Round 6
// 678.737 us; speedup vs baseline: 12.3854x; 1.0351x over previous
//
#include <hip/hip_runtime.h>
#include <math.h>

// Problem constants (fixed by the reference module)
#define NB 8
#define LTOK 4096
#define CH 384
#define DH 192
#define HH 64
#define WW 64
#define NCHK 128     // chunks per sequence
#define CHS 32       // steps per chunk (LTOK / NCHK)

static constexpr long BLC  = (long)NB * LTOK * CH;   // 12,582,912 elements
static constexpr long CST  = (long)32 * NCHK * DH;   // 786,432 per chunk-state buffer

typedef unsigned short u16;
typedef u16   u16x8 __attribute__((ext_vector_type(8)));
typedef short s16x8 __attribute__((ext_vector_type(8)));
typedef float f32x4 __attribute__((ext_vector_type(4)));

__device__ inline float softplusf_(float x){ return x > 20.f ? x : log1pf(expf(x)); }
__device__ inline u16 f2bf(float f){
  unsigned int u = __float_as_uint(f);
  return (u16)((u + 0x7FFFu + ((u >> 16) & 1u)) >> 16);
}
__device__ inline float bf2f(u16 h){ return __uint_as_float(((unsigned int)h) << 16); }

template<int NW>
__device__ inline float blockSum(float v, float* sm){
  #pragma unroll
  for (int o = 32; o > 0; o >>= 1) v += __shfl_down(v, o);
  int lane = threadIdx.x & 63, wv = threadIdx.x >> 6;
  if (lane == 0) sm[wv] = v;
  __syncthreads();
  if (threadIdx.x == 0){ float t = 0.f; for (int i = 0; i < NW; i++) t += sm[i]; sm[0] = t; }
  __syncthreads();
  float t = sm[0];
  __syncthreads();
  return t;
}

// ---------------- LayerNorm over C=384 per token ----------------
__global__ __launch_bounds__(128) void k_ln(const float* __restrict__ x,
    const float* __restrict__ g, const float* __restrict__ b, float* __restrict__ xn){
  __shared__ float sm[2];
  long row = blockIdx.x;
  int t = threadIdx.x;
  const float* xr = x + row * CH;
  float v0 = xr[t], v1 = xr[t + 128], v2 = xr[t + 256];
  float s = blockSum<2>(v0 + v1 + v2, sm);
  float m = s * (1.f / CH);
  float d0 = v0 - m, d1 = v1 - m, d2 = v2 - m;
  float vs = blockSum<2>(d0*d0 + d1*d1 + d2*d2, sm);
  float inv = rsqrtf(vs * (1.f / CH) + 1e-5f);
  float* o = xn + row * CH;
  o[t]       = d0 * inv * g[t]       + b[t];
  o[t + 128] = d1 * inv * g[t + 128] + b[t + 128];
  o[t + 256] = d2 * inv * g[t + 256] + b[t + 256];
}

// ---------------- partial pooling ----------------
__global__ __launch_bounds__(128) void k_pool(const float* __restrict__ xn, float* __restrict__ pp){
  int c = blockIdx.x * 128 + threadIdx.x;
  int chunk = blockIdx.y, b = blockIdx.z;
  long base = ((long)b * LTOK + chunk * 256) * CH;
  float s = 0.f;
  for (int n = 0; n < 256; n++) s += xn[base + (long)n * CH + c];
  pp[((long)b * 16 + chunk) * CH + c] = s;
}

// ---------------- score MLP + stable argsort (descending) ----------------
__global__ __launch_bounds__(384) void k_score(const float* __restrict__ pp,
    const float* __restrict__ w1, const float* __restrict__ b1,
    const float* __restrict__ w2, const float* __restrict__ b2,
    int* __restrict__ sidx, int* __restrict__ inv){
  __shared__ float poolv[CH];
  __shared__ float hid[192];
  __shared__ float sc[CH];
  int b = blockIdx.x, t = threadIdx.x;
  float s = 0.f;
  for (int ch = 0; ch < 16; ch++) s += pp[((long)b * 16 + ch) * CH + t];
  poolv[t] = s * (1.f / LTOK);
  __syncthreads();
  if (t < 192){
    float h = b1[t];
    for (int c = 0; c < CH; c++) h += poolv[c] * w1[t * CH + c];
    hid[t] = fmaxf(h, 0.f);
  }
  __syncthreads();
  {
    float h = b2[t];
    for (int j = 0; j < 192; j++) h += hid[j] * w2[t * 192 + j];
    sc[t] = 1.f / (1.f + expf(-h));
  }
  __syncthreads();
  float mys = sc[t];
  int rank = 0;
  for (int j = 0; j < CH; j++){
    float o = sc[j];
    rank += (o > mys) || (o == mys && j < t);
  }
  sidx[b * CH + rank] = t;
  inv[b * CH + t] = rank;
}

// ---------------- cast fp32 -> bf16 (weights) ----------------
__global__ __launch_bounds__(256) void k_cast(const float* __restrict__ s,
    u16* __restrict__ d, int n){
  int i = blockIdx.x * 256 + threadIdx.x;
  if (i < n) d[i] = f2bf(s[i]);
}

// ---------------- gather sorted channels + cast to bf16 ----------------
__global__ __launch_bounds__(384) void k_castgather(const float* __restrict__ xn,
    const int* __restrict__ sidx, u16* __restrict__ As){
  long row = blockIdx.x;
  int b = (int)(row >> 12);
  int t = threadIdx.x;
  int c = sidx[b * CH + t];
  As[row * CH + t] = f2bf(xn[row * CH + c]);
}

// ---------------- prep gate-MLP weights: gathered w1 (per batch), padded w2, b1 ----------------
__global__ __launch_bounds__(256) void k_prepw(const float* __restrict__ w1,
    const float* __restrict__ b1, const float* __restrict__ w2,
    const int* __restrict__ sidx, u16* __restrict__ w1g, u16* __restrict__ w2p,
    float* __restrict__ b1p){
  int b = blockIdx.x, tid = threadIdx.x;
  if (b < NB){
    const int* sx = sidx + b * CH;
    for (int i = tid; i < 32 * CH; i += 256){
      int j = i / CH, r = i - j * CH;
      float v = (j < 24) ? w1[j * CH + sx[r]] : 0.f;
      w1g[(long)b * 32 * CH + i] = f2bf(v);
    }
  } else {
    for (int i = tid; i < CH * 32; i += 256){
      int n = i >> 5, j = i & 31;
      w2p[i] = f2bf((j < 24) ? w2[n * 24 + j] : 0.f);
    }
    if (tid < 32) b1p[tid] = (tid < 24) ? b1[tid] : 0.f;
  }
}

// ---------------- prep fused dt matrices: M_gk[di][c] = sum_r dtw[gk][di][r]*xpw[g][k][r][c] ----------------
__global__ __launch_bounds__(256) void k_prepM(const float* __restrict__ dtw,
    const float* __restrict__ xpw, u16* __restrict__ Mw){
  int gk = blockIdx.y;
  int g = gk >> 1, k = gk & 1;
  int idx = blockIdx.x * 256 + threadIdx.x;   // < 36864
  int di = idx / 192, c = idx - di * 192;
  float s = 0.f;
  #pragma unroll
  for (int r = 0; r < 12; r++)
    s += dtw[((long)gk * 192 + di) * 12 + r] * xpw[(long)g * 5376 + (k * 14 + r) * 192 + c];
  Mw[(long)gk * 36864 + idx] = f2bf(s);
}

// ---------------- gate stage 1: hid = relu(As @ w1g^T + b1p), bf16 out ----------------
__global__ __launch_bounds__(256) void k_hid(const u16* __restrict__ As,
    const u16* __restrict__ w1g, const float* __restrict__ b1p,
    u16* __restrict__ hidp){
  __shared__ u16 sA[128 * 32];
  __shared__ u16 sB[32 * 32];
  int b = blockIdx.y;
  const u16* Ab = As + (long)b * LTOK * CH;
  const u16* Bb = w1g + (long)b * 32 * CH;
  int tid = threadIdx.x;
  int m0 = blockIdx.x * 128;
  int wv = tid >> 6, l = tid & 63;
  int wm = wv * 32;
  int kg = l >> 4, lr = l & 15;

  f32x4 acc[2][2];
  #pragma unroll
  for (int i = 0; i < 2; i++)
    #pragma unroll
    for (int j = 0; j < 2; j++)
      #pragma unroll
      for (int r = 0; r < 4; r++) acc[i][j][r] = 0.f;

  int aoffU[2], boffU[2];
  #pragma unroll
  for (int i = 0; i < 2; i++){
    int r = wm + i * 16 + lr;
    aoffU[i] = r * 32 + ((kg * 8) ^ ((r & 3) << 3));
  }
  #pragma unroll
  for (int j = 0; j < 2; j++){
    int r = j * 16 + lr;
    boffU[j] = r * 32 + ((kg * 8) ^ ((r & 3) << 3));
  }

  u16x8 ra[2], rbv;
  #pragma unroll
  for (int q = 0; q < 2; q++){
    int i = q * 256 + tid; int row = i >> 2, sl = i & 3, ss = sl ^ (row & 3);
    ra[q] = *(const u16x8*)(Ab + (long)(m0 + row) * CH + ss * 8);
  }
  if (tid < 128){
    int row = tid >> 2, sl = tid & 3, ss = sl ^ (row & 3);
    rbv = *(const u16x8*)(Bb + (long)row * CH + ss * 8);
  }

  const int nks = CH / 32;   // 12
  for (int ks = 0; ks < nks; ks++){
    __syncthreads();
    #pragma unroll
    for (int q = 0; q < 2; q++){
      int i = q * 256 + tid; int row = i >> 2, sl = i & 3;
      *(u16x8*)(sA + row * 32 + sl * 8) = ra[q];
    }
    if (tid < 128){
      int row = tid >> 2, sl = tid & 3;
      *(u16x8*)(sB + row * 32 + sl * 8) = rbv;
    }
    __syncthreads();
    if (ks + 1 < nks){
      int k0 = (ks + 1) * 32;
      #pragma unroll
      for (int q = 0; q < 2; q++){
        int i = q * 256 + tid; int row = i >> 2, sl = i & 3, ss = sl ^ (row & 3);
        ra[q] = *(const u16x8*)(Ab + (long)(m0 + row) * CH + k0 + ss * 8);
      }
      if (tid < 128){
        int row = tid >> 2, sl = tid & 3, ss = sl ^ (row & 3);
        rbv = *(const u16x8*)(Bb + (long)row * CH + k0 + ss * 8);
      }
    }
    s16x8 af[2], bfr[2];
    #pragma unroll
    for (int i = 0; i < 2; i++) af[i] = *(const s16x8*)(sA + aoffU[i]);
    #pragma unroll
    for (int j = 0; j < 2; j++) bfr[j] = *(const s16x8*)(sB + boffU[j]);
    #pragma unroll
    for (int i = 0; i < 2; i++)
      #pragma unroll
      for (int j = 0; j < 2; j++)
        acc[i][j] = __builtin_amdgcn_mfma_f32_16x16x32_bf16(af[i], bfr[j], acc[i][j], 0, 0, 0);
  }

  #pragma unroll
  for (int i = 0; i < 2; i++)
    #pragma unroll
    for (int j = 0; j < 2; j++)
      #pragma unroll
      for (int r = 0; r < 4; r++){
        int m = m0 + wm + i * 16 + kg * 4 + r;
        int n = j * 16 + lr;
        float v = fmaxf(acc[i][j][r] + b1p[n], 0.f);
        hidp[((long)b * LTOK + m) * 32 + n] = f2bf(v);
      }
}

// ---------------- bf16 MFMA GEMM: C = A @ B^T ----------------
// MODE 1: split epilogue: n<192 -> Cf fp32; n>=192 -> Ch bf16
// MODE 2: Ch bf16 [m*ldc+n]
// MODE 3: Cf fp32 = resid + skip*(v + bias[n])
// MODE 4: gate = sigmoid(v+bias[n]); Ch[m*ldc+n] = bf16(gate * bf2f(gy[m*ldc+ginv[(m>>12)*CH+n]]))
template<int BN, int MODE>
__global__ __launch_bounds__(256) void k_mm(
    const u16* __restrict__ A, int lda, long aOuter, long aInner,
    const u16* __restrict__ B, long bInner,
    float* __restrict__ Cf, u16* __restrict__ Ch,
    long cOuter, long cInner, int ldc,
    int K, int innerCnt,
    const float* __restrict__ bias, const float* __restrict__ resid,
    const float* __restrict__ skip,
    const u16* __restrict__ gy, const int* __restrict__ ginv){
  constexpr int BM = 128;
  constexpr int AI = 2;
  constexpr int BI = (BN * 32) / (256 * 8);
  constexpr int NJ = BN / 32;
  __shared__ u16 sA[BM * 32];
  __shared__ u16 sB[BN * 32];

  int bz = blockIdx.z;
  int bo = bz / innerCnt, bi_ = bz - bo * innerCnt;
  const u16* Ab = A + (long)bo * aOuter + (long)bi_ * aInner;
  const u16* Bb = B + (long)bi_ * bInner;
  int tid = threadIdx.x;
  int m0 = blockIdx.y * BM, n0 = blockIdx.x * BN;
  int wv = tid >> 6, l = tid & 63;
  int wm = (wv >> 1) * 64, wn = (wv & 1) * (BN / 2);
  int kg = l >> 4, lr = l & 15;

  f32x4 acc[4][NJ];
  #pragma unroll
  for (int i = 0; i < 4; i++)
    #pragma unroll
    for (int j = 0; j < NJ; j++)
      #pragma unroll
      for (int r = 0; r < 4; r++) acc[i][j][r] = 0.f;

  int aoffU[4], boffU[NJ];
  #pragma unroll
  for (int i = 0; i < 4; i++){
    int r = wm + i * 16 + lr;
    aoffU[i] = r * 32 + ((kg * 8) ^ ((r & 3) << 3));
  }
  #pragma unroll
  for (int j = 0; j < NJ; j++){
    int r = wn + j * 16 + lr;
    boffU[j] = r * 32 + ((kg * 8) ^ ((r & 3) << 3));
  }

  u16x8 ra[AI], rb[BI];
  #pragma unroll
  for (int q = 0; q < AI; q++){
    int i = q * 256 + tid; int row = i >> 2, sl = i & 3, ss = sl ^ (row & 3);
    ra[q] = *(const u16x8*)(Ab + (long)(m0 + row) * lda + ss * 8);
  }
  #pragma unroll
  for (int q = 0; q < BI; q++){
    int i = q * 256 + tid; int row = i >> 2, sl = i & 3, ss = sl ^ (row & 3);
    rb[q] = *(const u16x8*)(Bb + (long)(n0 + row) * K + ss * 8);
  }

  int nks = K >> 5;
  for (int ks = 0; ks < nks; ks++){
    __syncthreads();
    #pragma unroll
    for (int q = 0; q < AI; q++){
      int i = q * 256 + tid; int row = i >> 2, sl = i & 3;
      *(u16x8*)(sA + row * 32 + sl * 8) = ra[q];
    }
    #pragma unroll
    for (int q = 0; q < BI; q++){
      int i = q * 256 + tid; int row = i >> 2, sl = i & 3;
      *(u16x8*)(sB + row * 32 + sl * 8) = rb[q];
    }
    __syncthreads();
    if (ks + 1 < nks){
      int k0 = (ks + 1) * 32;
      #pragma unroll
      for (int q = 0; q < AI; q++){
        int i = q * 256 + tid; int row = i >> 2, sl = i & 3, ss = sl ^ (row & 3);
        ra[q] = *(const u16x8*)(Ab + (long)(m0 + row) * lda + k0 + ss * 8);
      }
      #pragma unroll
      for (int q = 0; q < BI; q++){
        int i = q * 256 + tid; int row = i >> 2, sl = i & 3, ss = sl ^ (row & 3);
        rb[q] = *(const u16x8*)(Bb + (long)(n0 + row) * K + k0 + ss * 8);
      }
    }
    s16x8 af[4];
    #pragma unroll
    for (int i = 0; i < 4; i++) af[i] = *(const s16x8*)(sA + aoffU[i]);
    s16x8 bfr[NJ];
    #pragma unroll
    for (int j = 0; j < NJ; j++) bfr[j] = *(const s16x8*)(sB + boffU[j]);
    #pragma unroll
    for (int i = 0; i < 4; i++)
      #pragma unroll
      for (int j = 0; j < NJ; j++)
        acc[i][j] = __builtin_amdgcn_mfma_f32_16x16x32_bf16(af[i], bfr[j], acc[i][j], 0, 0, 0);
  }

  long zc = (long)bo * cOuter + (long)bi_ * cInner;
  #pragma unroll
  for (int i = 0; i < 4; i++){
    #pragma unroll
    for (int j = 0; j < NJ; j++){
      #pragma unroll
      for (int r = 0; r < 4; r++){
        int m = m0 + wm + i * 16 + kg * 4 + r;
        int n = n0 + wn + j * 16 + lr;
        float v = acc[i][j][r];
        if constexpr (MODE == 1){
          if (n < 192) Cf[zc + (long)m * 192 + n] = v;
          else         Ch[zc + (long)m * 192 + (n - 192)] = f2bf(v);
        } else if constexpr (MODE == 2){
          Ch[zc + (long)m * ldc + n] = f2bf(v);
        } else if constexpr (MODE == 3){
          float vb = v + bias[n];
          long o = (long)m * ldc + n;
          Cf[o] = resid[o] + skip[0] * vb;
        } else {
          float gate = 1.f / (1.f + expf(-(v + bias[n])));
          int bt = m >> 12;
          float yr = bf2f(gy[(long)m * ldc + ginv[bt * CH + n]]);
          Ch[(long)m * ldc + n] = f2bf(yr * gate);
        }
      }
    }
  }
}

// ---------------- fused dt GEMM: dtraw = xcvh @ M^T, epilogue packs (a, dt*B) bf16x2 ----------------
__global__ __launch_bounds__(256) void k_dt(
    const u16* __restrict__ xcvh, const u16* __restrict__ Mw,
    const float* __restrict__ dtb, const float* __restrict__ alog,
    const float* __restrict__ bc, unsigned* __restrict__ pck){
  constexpr int BM = 128, BN = 64, AI = 2, BI = 1, NJ = 2;
  __shared__ u16 sA[BM * 32];
  __shared__ u16 sB[BN * 32];
  int z = blockIdx.z;                 // bg*2 + k
  int bg = z >> 1, kk_ = z & 1, g = bg & 1, gk = g * 2 + kk_;
  const u16* Ab = xcvh + (long)bg * LTOK * 192;
  const u16* Bb = Mw + (long)gk * 36864;
  int tid = threadIdx.x;
  int m0 = blockIdx.y * BM, n0 = blockIdx.x * BN;
  int wv = tid >> 6, l = tid & 63;
  int wm = (wv >> 1) * 64, wn = (wv & 1) * 32;
  int kg = l >> 4, lr = l & 15;

  f32x4 acc[4][NJ];
  #pragma unroll
  for (int i = 0; i < 4; i++)
    #pragma unroll
    for (int j = 0; j < NJ; j++)
      #pragma unroll
      for (int r = 0; r < 4; r++) acc[i][j][r] = 0.f;

  int aoffU[4], boffU[NJ];
  #pragma unroll
  for (int i = 0; i < 4; i++){
    int r = wm + i * 16 + lr;
    aoffU[i] = r * 32 + ((kg * 8) ^ ((r & 3) << 3));
  }
  #pragma unroll
  for (int j = 0; j < NJ; j++){
    int r = wn + j * 16 + lr;
    boffU[j] = r * 32 + ((kg * 8) ^ ((r & 3) << 3));
  }

  u16x8 ra[AI], rb[BI];
  #pragma unroll
  for (int q = 0; q < AI; q++){
    int i = q * 256 + tid; int row = i >> 2, sl = i & 3, ss = sl ^ (row & 3);
    ra[q] = *(const u16x8*)(Ab + (long)(m0 + row) * 192 + ss * 8);
  }
  {
    int i = tid; int row = i >> 2, sl = i & 3, ss = sl ^ (row & 3);
    rb[0] = *(const u16x8*)(Bb + (long)(n0 + row) * 192 + ss * 8);
  }

  const int nks = 6;   // K = 192
  for (int ks = 0; ks < nks; ks++){
    __syncthreads();
    #pragma unroll
    for (int q = 0; q < AI; q++){
      int i = q * 256 + tid; int row = i >> 2, sl = i & 3;
      *(u16x8*)(sA + row * 32 + sl * 8) = ra[q];
    }
    {
      int row = tid >> 2, sl = tid & 3;
      *(u16x8*)(sB + row * 32 + sl * 8) = rb[0];
    }
    __syncthreads();
    if (ks + 1 < nks){
      int k0 = (ks + 1) * 32;
      #pragma unroll
      for (int q = 0; q < AI; q++){
        int i = q * 256 + tid; int row = i >> 2, sl = i & 3, ss = sl ^ (row & 3);
        ra[q] = *(const u16x8*)(Ab + (long)(m0 + row) * 192 + k0 + ss * 8);
      }
      {
        int row = tid >> 2, sl = tid & 3, ss = sl ^ (row & 3);
        rb[0] = *(const u16x8*)(Bb + (long)(n0 + row) * 192 + k0 + ss * 8);
      }
    }
    s16x8 af[4], bfr[NJ];
    #pragma unroll
    for (int i = 0; i < 4; i++) af[i] = *(const s16x8*)(sA + aoffU[i]);
    #pragma unroll
    for (int j = 0; j < NJ; j++) bfr[j] = *(const s16x8*)(sB + boffU[j]);
    #pragma unroll
    for (int i = 0; i < 4; i++)
      #pragma unroll
      for (int j = 0; j < NJ; j++)
        acc[i][j] = __builtin_amdgcn_mfma_f32_16x16x32_bf16(af[i], bfr[j], acc[i][j], 0, 0, 0);
  }

  #pragma unroll
  for (int i = 0; i < 4; i++){
    #pragma unroll
    for (int j = 0; j < NJ; j++){
      #pragma unroll
      for (int r = 0; r < 4; r++){
        int m = m0 + wm + i * 16 + kg * 4 + r;
        int n = n0 + wn + j * 16 + lr;
        float dtv = softplusf_(acc[i][j][r] + dtb[gk * 192 + n]);
        float av = expf(-dtv * expf(alog[gk * 192 + n]));
        float Bv = bc[((long)z * LTOK + m) * 2];
        pck[((long)z * LTOK + m) * 192 + n] =
            ((unsigned)f2bf(dtv * Bv) << 16) | (unsigned)f2bf(av);
      }
    }
  }
}

// ---------------- depthwise 3x3 conv + bias + silu, write bf16 in scan order ----------------
__global__ __launch_bounds__(256) void k_conv(const float* __restrict__ xc,
    const float* __restrict__ cw, const float* __restrict__ cb, u16* __restrict__ xcvh){
  long idx = (long)blockIdx.x * 256 + threadIdx.x;
  if (idx >= (long)NB * 2 * LTOK * DH) return;
  int di = (int)(idx % DH); long t = idx / DH;
  int p = (int)(t % LTOK); t /= LTOK;
  int g = (int)(t & 1); int b = (int)(t >> 1);
  int h = p >> 6, w = p & 63;
  const float* W = cw + ((long)g * DH + di) * 9;
  long sb = ((long)(b * 2 + g)) * LTOK;
  float s = cb[g * DH + di];
  #pragma unroll
  for (int dh = -1; dh <= 1; dh++){
    int hh = h + dh; if (hh < 0 || hh >= HH) continue;
    #pragma unroll
    for (int dw = -1; dw <= 1; dw++){
      int ww2 = w + dw; if (ww2 < 0 || ww2 >= WW) continue;
      s += W[(dh + 1) * 3 + (dw + 1)] * xc[(sb + hh * WW + ww2) * DH + di];
    }
  }
  s = s / (1.f + expf(-s));
  int lscan = (g == 0) ? p : (w * HH + h);
  xcvh[(sb + (long)lscan) * DH + di] = f2bf(s);
}

// ---------------- B/C projection: 4 outputs per position ----------------
__global__ __launch_bounds__(256) void k_bc(const u16* __restrict__ xcvh,
    const float* __restrict__ xpw, float* __restrict__ bc){
  int bg = blockIdx.y;
  int g = bg & 1;
  int p0 = blockIdx.x * 8;
  __shared__ float wl[4][192];
  __shared__ float xr[8][192];
  int tid = threadIdx.x;
  for (int i = tid; i < 4 * 192; i += 256){
    int j = i / 192, c = i - j * 192;
    int k = j >> 1, col = 12 + (j & 1);
    wl[j][c] = xpw[(long)g * 5376 + (k * 14 + col) * 192 + c];
  }
  for (int i = tid; i < 8 * 192; i += 256){
    xr[i / 192][i % 192] = bf2f(xcvh[((long)bg * LTOK + p0 + i / 192) * DH + (i % 192)]);
  }
  __syncthreads();
  int pos = tid >> 5, j = tid & 31;
  if (j < 4){
    float s = 0.f;
    for (int c = 0; c < 192; c++) s += xr[pos][c] * wl[j][c];
    int k = j >> 1;
    bc[(((long)(bg * 2 + k)) * LTOK + p0 + pos) * 2 + (j & 1)] = s;
  }
}

// ---------------- chunked parallel selective scan (precomputed a, dtB) ----------------
__global__ __launch_bounds__(192) void k_scan_p1(const unsigned* __restrict__ pck,
    const u16* __restrict__ xcvh, float* __restrict__ cP, float* __restrict__ cS){
  int bg = blockIdx.x, k = blockIdx.y, c = blockIdx.z;
  int z = bg * 2 + k;
  int di = threadIdx.x;
  const unsigned* pk = pck + (long)z * LTOK * 192 + di;
  const u16* xc = xcvh + (long)bg * LTOK * 192 + di;
  float P = 1.f, S = 0.f;
  int l  = (k == 0) ? c * CHS : (LTOK - 1 - c * CHS);
  int dl = (k == 0) ? 1 : -1;
  for (int s = 0; s < CHS; s++, l += dl){
    unsigned v = pk[(long)l * 192];
    float a  = bf2f((u16)(v & 0xFFFFu));
    float dB = bf2f((u16)(v >> 16));
    float xv = bf2f(xc[(long)l * 192]);
    P *= a;
    S = a * S + dB * xv;
  }
  long idx = ((long)z * NCHK + c) * 192 + di;
  cP[idx] = P;
  cS[idx] = S;
}

__global__ __launch_bounds__(192) void k_scan_p2(const float* __restrict__ cP,
    const float* __restrict__ cS, float* __restrict__ h0){
  int z = blockIdx.x;              // 0..31
  int di = threadIdx.x;
  float h = 0.f;
  for (int c = 0; c < NCHK; c++){
    long idx = ((long)z * NCHK + c) * 192 + di;
    h0[idx] = h;
    h = cP[idx] * h + cS[idx];
  }
}

__global__ __launch_bounds__(192) void k_scan_p3(const unsigned* __restrict__ pck,
    const u16* __restrict__ xcvh, const float* __restrict__ bc,
    const float* __restrict__ ds, const float* __restrict__ h0,
    u16* __restrict__ ydir){
  int bg = blockIdx.x, c = blockIdx.y;
  int g = bg & 1;
  int di = threadIdx.x;
  const u16* xc = xcvh + (long)bg * LTOK * 192 + di;
  u16* yo = ydir + (long)bg * LTOK * 192 + di;
  #pragma unroll
  for (int k = 0; k < 2; k++){
    int z = bg * 2 + k, gk = g * 2 + k;
    float Dv = ds[gk * 192 + di];
    const unsigned* pk = pck + (long)z * LTOK * 192 + di;
    const float* bcp = bc + (long)z * LTOK * 2;
    int cc = (k == 0) ? c : (NCHK - 1 - c);
    float h = h0[((long)z * NCHK + cc) * 192 + di];
    int l  = (k == 0) ? c * CHS : (c * CHS + CHS - 1);
    int dl = (k == 0) ? 1 : -1;
    for (int s = 0; s < CHS; s++, l += dl){
      unsigned v = pk[(long)l * 192];
      float a  = bf2f((u16)(v & 0xFFFFu));
      float dB = bf2f((u16)(v >> 16));
      float xv = bf2f(xc[(long)l * 192]);
      h = a * h + dB * xv;
      float y = h * bcp[l * 2 + 1] + Dv * xv;
      if (k == 0) yo[(long)l * 192] = f2bf(y);
      else        yo[(long)l * 192] = f2bf(bf2f(yo[(long)l * 192]) + y);
    }
  }
}

// ---------------- combine directions + out-LN + *silu(z) -> bf16 ----------------
__global__ __launch_bounds__(192) void k_combine(const u16* __restrict__ ydir,
    const u16* __restrict__ zh, const float* __restrict__ ong, const float* __restrict__ onb,
    u16* __restrict__ yab){
  __shared__ float sm[3];
  int p = blockIdx.x; int bg = blockIdx.y; int g = bg & 1;
  int h = p >> 6, w = p & 63;
  int l = (g == 0) ? p : (w * HH + h);
  int di = threadIdx.x;
  float y = bf2f(ydir[((long)bg * LTOK + l) * DH + di]);
  float s = blockSum<3>(y, sm);
  float m = s * (1.f / DH);
  float d = y - m;
  float vs = blockSum<3>(d * d, sm);
  float inv = rsqrtf(vs * (1.f / DH) + 1e-5f);
  float yl = d * inv * ong[g * DH + di] + onb[g * DH + di];
  float z = bf2f(zh[((long)bg * LTOK + p) * DH + di]);
  yab[((long)bg * LTOK + p) * DH + di] = f2bf(yl * (z / (1.f + expf(-z))));
}

extern "C" void kernel_launch(void* const* d_in, const int* in_sizes, int n_in,
                              void* d_out, int out_size, void* d_ws, size_t ws_size,
                              hipStream_t stream){
  const float* x       = (const float*)d_in[0];
  const float* norm_g  = (const float*)d_in[1];
  const float* norm_b  = (const float*)d_in[2];
  const float* r_w1    = (const float*)d_in[3];
  const float* r_b1    = (const float*)d_in[4];
  const float* r_w2    = (const float*)d_in[5];
  const float* r_b2    = (const float*)d_in[6];
  const float* in_proj = (const float*)d_in[7];
  const float* conv_w  = (const float*)d_in[8];
  const float* conv_b  = (const float*)d_in[9];
  const float* xp_w    = (const float*)d_in[10];
  const float* dt_w    = (const float*)d_in[11];
  const float* dt_b    = (const float*)d_in[12];
  const float* A_log   = (const float*)d_in[13];
  const float* Ds      = (const float*)d_in[14];
  const float* on_g    = (const float*)d_in[15];
  const float* on_b    = (const float*)d_in[16];
  const float* op_w    = (const float*)d_in[17];
  const float* ci_w1   = (const float*)d_in[18];
  const float* ci_b1   = (const float*)d_in[19];
  const float* ci_w2   = (const float*)d_in[20];
  const float* ci_b2   = (const float*)d_in[21];
  const float* proj_w  = (const float*)d_in[22];
  const float* proj_b  = (const float*)d_in[23];
  const float* skip    = (const float*)d_in[24];
  float* out = (float*)d_out;
  float* ws  = (float*)d_ws;

  // Regions (floats):
  // R12 = ws[0 .. 2*BLC)      : xn fp32 (BLC) + xcb fp32 (BLC)  -> later pck u32 (2*BLC)
  // R3  = [2*BLC .. 2.5*BLC)  : zh bf16 -> ycat bf16
  // R4  = [2.5B .. 3*BLC)     : xcvh bf16 -> yab bf16
  // R5  = [3*BLC .. 3.5*BLC)  : As bf16 -> ydir bf16
  float* xn   = ws;
  float* xcb  = ws + BLC;
  float* R3   = ws + 2 * BLC;
  float* R4   = R3 + BLC / 2;
  float* R5   = R4 + BLC / 2;
  float* pp   = R5 + BLC / 2;
  int*  sidx  = (int*)(pp + NB * 16 * CH);
  int*  inv   = sidx + NB * CH;
  u16*  wip   = (u16*)(inv + NB * CH);   // 2*384*192
  u16*  wop   = wip + 2 * 384 * 192;     // 2*192*192
  u16*  wpj   = wop + 2 * 192 * 192;     // 384*384
  u16*  w1g   = wpj + 384 * 384;         // NB*32*384
  u16*  w2p   = w1g + NB * 32 * CH;      // 384*32
  u16*  Mw    = w2p + CH * 32;           // 4*192*192
  float* b1p  = (float*)(Mw + 4 * 192 * 192);
  u16*  hidp  = (u16*)(b1p + 32);        // NB*4096*32
  float* bc   = (float*)(hidp + (long)NB * LTOK * 32);  // 32*4096*2
  float* cP   = bc + 32 * LTOK * 2;
  float* cS   = cP + CST;
  float* h0   = cS + CST;

  size_t need = ((size_t)(2 * BLC) + 3 * (BLC / 2) + NB * 16 * CH + 32 * LTOK * 2 + 3 * CST + 64) * 4
              + (size_t)(2 * NB * CH) * 4
              + ((size_t)2*384*192 + 2*192*192 + 384*384 + NB*32*CH + CH*32 + 4*192*192
                 + (size_t)NB * LTOK * 32) * 2
              + 8192;
  if (ws_size < need) return;

  // aliases
  u16*  As   = (u16*)R5;
  u16*  zh   = (u16*)R3;
  u16*  xcvh = (u16*)R4;
  unsigned* pck = (unsigned*)ws;        // spans R12 (xn, xcb both dead by then)
  u16*  ydir = (u16*)R5;
  u16*  yab  = (u16*)R4;
  u16*  ycat = (u16*)R3;
  u16*  gab  = (u16*)xcb;

  k_ln<<<NB * LTOK, 128, 0, stream>>>(x, norm_g, norm_b, xn);
  k_cast<<<(2*384*192 + 255)/256, 256, 0, stream>>>(in_proj, wip, 2*384*192);
  k_cast<<<(2*192*192 + 255)/256, 256, 0, stream>>>(op_w,    wop, 2*192*192);
  k_cast<<<(384*384   + 255)/256, 256, 0, stream>>>(proj_w,  wpj, 384*384);
  k_prepM<<<dim3(144, 4), 256, 0, stream>>>(dt_w, xp_w, Mw);
  k_pool<<<dim3(3, 16, NB), 128, 0, stream>>>(xn, pp);
  k_score<<<NB, 384, 0, stream>>>(pp, r_w1, r_b1, r_w2, r_b2, sidx, inv);
  k_castgather<<<NB * LTOK, 384, 0, stream>>>(xn, sidx, As);
  k_prepw<<<NB + 1, 256, 0, stream>>>(ci_w1, ci_b1, ci_w2, sidx, w1g, w2p, b1p);

  // in_proj: per (b,g): [4096x192]@[384x192]^T -> xcb fp32 + zh bf16
  k_mm<128, 1><<<dim3(3, 32, 16), 256, 0, stream>>>(
      As, CH, (long)LTOK * CH, 192,
      wip, (long)384 * 192,
      xcb, zh, (long)2 * LTOK * DH, (long)LTOK * DH, 0,
      192, 2, nullptr, nullptr, nullptr, nullptr, nullptr);

  // gate stage 1 (uses As; before R5 is recycled by scan p3)
  k_hid<<<dim3(32, NB), 256, 0, stream>>>(As, w1g, b1p, hidp);

  k_conv<<<(int)(((long)NB * 2 * LTOK * DH + 255) / 256), 256, 0, stream>>>(xcb, conv_w, conv_b, xcvh);
  k_bc<<<dim3(LTOK / 8, NB * 2), 256, 0, stream>>>(xcvh, xp_w, bc);

  // fused dt GEMM -> packed (a, dt*B) bf16x2 (overwrites xn+xcb regions)
  k_dt<<<dim3(3, 32, 32), 256, 0, stream>>>(xcvh, Mw, dt_b, A_log, bc, pck);

  k_scan_p1<<<dim3(NB * 2, 2, NCHK), 192, 0, stream>>>(pck, xcvh, cP, cS);
  k_scan_p2<<<32, 192, 0, stream>>>(cP, cS, h0);
  k_scan_p3<<<dim3(NB * 2, NCHK), 192, 0, stream>>>(pck, xcvh, bc, Ds, h0, ydir);

  k_combine<<<dim3(LTOK, NB * 2), 192, 0, stream>>>(ydir, zh, on_g, on_b, yab);

  // out_proj: per (b,g): [4096x192]@[192x192]^T -> ycat bf16 (col offset g*192)
  k_mm<64, 2><<<dim3(3, 32, 16), 256, 0, stream>>>(
      yab, DH, (long)2 * LTOK * DH, (long)LTOK * DH,
      wop, (long)192 * 192,
      nullptr, ycat, (long)LTOK * CH, 192, CH,
      192, 2, nullptr, nullptr, nullptr, nullptr, nullptr);

  // gate stage 2 + un-sort gather + multiply
  k_mm<128, 4><<<dim3(3, 256, 1), 256, 0, stream>>>(
      hidp, 32, 0, 0,
      w2p, 0,
      nullptr, gab, 0, 0, CH,
      32, 1, ci_b2, nullptr, nullptr, ycat, inv);

  // final: out = x + skip * (gab @ proj_w^T + proj_b)
  k_mm<128, 3><<<dim3(3, 256, 1), 256, 0, stream>>>(
      gab, CH, 0, 0,
      wpj, 0,
      out, nullptr, 0, 0, CH,
      CH, 1, proj_b, x, skip, nullptr, nullptr);
}

// Round 7
// 546.866 us; speedup vs baseline: 15.3720x; 1.2411x over previous
//
#include <hip/hip_runtime.h>
#include <math.h>

// Problem constants (fixed by the reference module)
#define NB 8
#define LTOK 4096
#define CH 384
#define DH 192
#define HH 64
#define WW 64
#define NCHK 128     // chunks per sequence
#define CHS 32       // steps per chunk (LTOK / NCHK)

static constexpr long BLC  = (long)NB * LTOK * CH;   // 12,582,912 elements
static constexpr long CST  = (long)32 * NCHK * DH;   // 786,432 per chunk-state buffer

typedef unsigned short u16;
typedef u16   u16x8 __attribute__((ext_vector_type(8)));
typedef short s16x8 __attribute__((ext_vector_type(8)));
typedef float f32x4 __attribute__((ext_vector_type(4)));

__device__ inline u16 f2bf(float f){
  unsigned int u = __float_as_uint(f);
  return (u16)((u + 0x7FFFu + ((u >> 16) & 1u)) >> 16);
}
__device__ inline float bf2f(u16 h){ return __uint_as_float(((unsigned int)h) << 16); }
__device__ inline float fsigmoid(float x){ return 1.f / (1.f + __expf(-x)); }

template<int NW>
__device__ inline float blockSum(float v, float* sm){
  #pragma unroll
  for (int o = 32; o > 0; o >>= 1) v += __shfl_down(v, o);
  int lane = threadIdx.x & 63, wv = threadIdx.x >> 6;
  if (lane == 0) sm[wv] = v;
  __syncthreads();
  if (threadIdx.x == 0){ float t = 0.f; for (int i = 0; i < NW; i++) t += sm[i]; sm[0] = t; }
  __syncthreads();
  float t = sm[0];
  __syncthreads();
  return t;
}

// ---------------- LayerNorm over C=384 per token ----------------
__global__ __launch_bounds__(128) void k_ln(const float* __restrict__ x,
    const float* __restrict__ g, const float* __restrict__ b, float* __restrict__ xn){
  __shared__ float sm[2];
  long row = blockIdx.x;
  int t = threadIdx.x;
  const float* xr = x + row * CH;
  float v0 = xr[t], v1 = xr[t + 128], v2 = xr[t + 256];
  float s = blockSum<2>(v0 + v1 + v2, sm);
  float m = s * (1.f / CH);
  float d0 = v0 - m, d1 = v1 - m, d2 = v2 - m;
  float vs = blockSum<2>(d0*d0 + d1*d1 + d2*d2, sm);
  float inv = rsqrtf(vs * (1.f / CH) + 1e-5f);
  float* o = xn + row * CH;
  o[t]       = d0 * inv * g[t]       + b[t];
  o[t + 128] = d1 * inv * g[t + 128] + b[t + 128];
  o[t + 256] = d2 * inv * g[t + 256] + b[t + 256];
}

// ---------------- partial pooling ----------------
__global__ __launch_bounds__(128) void k_pool(const float* __restrict__ xn, float* __restrict__ pp){
  int c = blockIdx.x * 128 + threadIdx.x;
  int chunk = blockIdx.y, b = blockIdx.z;
  long base = ((long)b * LTOK + chunk * 256) * CH;
  float s = 0.f;
  for (int n = 0; n < 256; n++) s += xn[base + (long)n * CH + c];
  pp[((long)b * 16 + chunk) * CH + c] = s;
}

// ---------------- score MLP + stable argsort (descending) ----------------
__global__ __launch_bounds__(384) void k_score(const float* __restrict__ pp,
    const float* __restrict__ w1, const float* __restrict__ b1,
    const float* __restrict__ w2, const float* __restrict__ b2,
    int* __restrict__ sidx, int* __restrict__ inv){
  __shared__ float poolv[CH];
  __shared__ float hid[192];
  __shared__ float sc[CH];
  int b = blockIdx.x, t = threadIdx.x;
  float s = 0.f;
  for (int ch = 0; ch < 16; ch++) s += pp[((long)b * 16 + ch) * CH + t];
  poolv[t] = s * (1.f / LTOK);
  __syncthreads();
  if (t < 192){
    float h = b1[t];
    for (int c = 0; c < CH; c++) h += poolv[c] * w1[t * CH + c];
    hid[t] = fmaxf(h, 0.f);
  }
  __syncthreads();
  {
    float h = b2[t];
    for (int j = 0; j < 192; j++) h += hid[j] * w2[t * 192 + j];
    sc[t] = 1.f / (1.f + expf(-h));
  }
  __syncthreads();
  float mys = sc[t];
  int rank = 0;
  for (int j = 0; j < CH; j++){
    float o = sc[j];
    rank += (o > mys) || (o == mys && j < t);
  }
  sidx[b * CH + rank] = t;
  inv[b * CH + t] = rank;
}

// ---------------- cast fp32 -> bf16 (weights) ----------------
__global__ __launch_bounds__(256) void k_cast(const float* __restrict__ s,
    u16* __restrict__ d, int n){
  int i = blockIdx.x * 256 + threadIdx.x;
  if (i < n) d[i] = f2bf(s[i]);
}

// ---------------- precompute A table: Atab = -exp(A_log) ----------------
__global__ __launch_bounds__(256) void k_prepA(const float* __restrict__ alog,
    float* __restrict__ Atab){
  int i = blockIdx.x * 256 + threadIdx.x;
  if (i < 4 * 192) Atab[i] = -expf(alog[i]);
}

// ---------------- gather sorted channels + cast to bf16 ----------------
__global__ __launch_bounds__(384) void k_castgather(const float* __restrict__ xn,
    const int* __restrict__ sidx, u16* __restrict__ As){
  long row = blockIdx.x;
  int b = (int)(row >> 12);
  int t = threadIdx.x;
  int c = sidx[b * CH + t];
  As[row * CH + t] = f2bf(xn[row * CH + c]);
}

// ---------------- prep gate-MLP weights: gathered w1 (per batch), padded w2, b1 ----------------
__global__ __launch_bounds__(256) void k_prepw(const float* __restrict__ w1,
    const float* __restrict__ b1, const float* __restrict__ w2,
    const int* __restrict__ sidx, u16* __restrict__ w1g, u16* __restrict__ w2p,
    float* __restrict__ b1p){
  int b = blockIdx.x, tid = threadIdx.x;
  if (b < NB){
    const int* sx = sidx + b * CH;
    for (int i = tid; i < 32 * CH; i += 256){
      int j = i / CH, r = i - j * CH;
      float v = (j < 24) ? w1[j * CH + sx[r]] : 0.f;
      w1g[(long)b * 32 * CH + i] = f2bf(v);
    }
  } else {
    for (int i = tid; i < CH * 32; i += 256){
      int n = i >> 5, j = i & 31;
      w2p[i] = f2bf((j < 24) ? w2[n * 24 + j] : 0.f);
    }
    if (tid < 32) b1p[tid] = (tid < 24) ? b1[tid] : 0.f;
  }
}

// ---------------- prep fused dt matrices: M_gk[di][c] = sum_r dtw[gk][di][r]*xpw[g][k][r][c] ----------------
__global__ __launch_bounds__(256) void k_prepM(const float* __restrict__ dtw,
    const float* __restrict__ xpw, u16* __restrict__ Mw){
  int gk = blockIdx.y;
  int g = gk >> 1, k = gk & 1;
  int idx = blockIdx.x * 256 + threadIdx.x;   // < 36864
  int di = idx / 192, c = idx - di * 192;
  float s = 0.f;
  #pragma unroll
  for (int r = 0; r < 12; r++)
    s += dtw[((long)gk * 192 + di) * 12 + r] * xpw[(long)g * 5376 + (k * 14 + r) * 192 + c];
  Mw[(long)gk * 36864 + idx] = f2bf(s);
}

// ---------------- gate stage 1: hid = relu(As @ w1g^T + b1p), bf16 out ----------------
__global__ __launch_bounds__(256) void k_hid(const u16* __restrict__ As,
    const u16* __restrict__ w1g, const float* __restrict__ b1p,
    u16* __restrict__ hidp){
  __shared__ u16 sA[128 * 32];
  __shared__ u16 sB[32 * 32];
  int b = blockIdx.y;
  const u16* Ab = As + (long)b * LTOK * CH;
  const u16* Bb = w1g + (long)b * 32 * CH;
  int tid = threadIdx.x;
  int m0 = blockIdx.x * 128;
  int wv = tid >> 6, l = tid & 63;
  int wm = wv * 32;
  int kg = l >> 4, lr = l & 15;

  f32x4 acc[2][2];
  #pragma unroll
  for (int i = 0; i < 2; i++)
    #pragma unroll
    for (int j = 0; j < 2; j++)
      #pragma unroll
      for (int r = 0; r < 4; r++) acc[i][j][r] = 0.f;

  int aoffU[2], boffU[2];
  #pragma unroll
  for (int i = 0; i < 2; i++){
    int r = wm + i * 16 + lr;
    aoffU[i] = r * 32 + ((kg * 8) ^ ((r & 3) << 3));
  }
  #pragma unroll
  for (int j = 0; j < 2; j++){
    int r = j * 16 + lr;
    boffU[j] = r * 32 + ((kg * 8) ^ ((r & 3) << 3));
  }

  u16x8 ra[2], rbv;
  #pragma unroll
  for (int q = 0; q < 2; q++){
    int i = q * 256 + tid; int row = i >> 2, sl = i & 3, ss = sl ^ (row & 3);
    ra[q] = *(const u16x8*)(Ab + (long)(m0 + row) * CH + ss * 8);
  }
  if (tid < 128){
    int row = tid >> 2, sl = tid & 3, ss = sl ^ (row & 3);
    rbv = *(const u16x8*)(Bb + (long)row * CH + ss * 8);
  }

  const int nks = CH / 32;   // 12
  for (int ks = 0; ks < nks; ks++){
    __syncthreads();
    #pragma unroll
    for (int q = 0; q < 2; q++){
      int i = q * 256 + tid; int row = i >> 2, sl = i & 3;
      *(u16x8*)(sA + row * 32 + sl * 8) = ra[q];
    }
    if (tid < 128){
      int row = tid >> 2, sl = tid & 3;
      *(u16x8*)(sB + row * 32 + sl * 8) = rbv;
    }
    __syncthreads();
    if (ks + 1 < nks){
      int k0 = (ks + 1) * 32;
      #pragma unroll
      for (int q = 0; q < 2; q++){
        int i = q * 256 + tid; int row = i >> 2, sl = i & 3, ss = sl ^ (row & 3);
        ra[q] = *(const u16x8*)(Ab + (long)(m0 + row) * CH + k0 + ss * 8);
      }
      if (tid < 128){
        int row = tid >> 2, sl = tid & 3, ss = sl ^ (row & 3);
        rbv = *(const u16x8*)(Bb + (long)row * CH + k0 + ss * 8);
      }
    }
    s16x8 af[2], bfr[2];
    #pragma unroll
    for (int i = 0; i < 2; i++) af[i] = *(const s16x8*)(sA + aoffU[i]);
    #pragma unroll
    for (int j = 0; j < 2; j++) bfr[j] = *(const s16x8*)(sB + boffU[j]);
    #pragma unroll
    for (int i = 0; i < 2; i++)
      #pragma unroll
      for (int j = 0; j < 2; j++)
        acc[i][j] = __builtin_amdgcn_mfma_f32_16x16x32_bf16(af[i], bfr[j], acc[i][j], 0, 0, 0);
  }

  #pragma unroll
  for (int i = 0; i < 2; i++)
    #pragma unroll
    for (int j = 0; j < 2; j++)
      #pragma unroll
      for (int r = 0; r < 4; r++){
        int m = m0 + wm + i * 16 + kg * 4 + r;
        int n = j * 16 + lr;
        float v = fmaxf(acc[i][j][r] + b1p[n], 0.f);
        hidp[((long)b * LTOK + m) * 32 + n] = f2bf(v);
      }
}

// ---------------- bf16 MFMA GEMM: C = A @ B^T ----------------
// MODE 1: split epilogue: n<192 -> ((u16*)Cf) bf16 [m*192+n]; n>=192 -> Ch bf16 [m*192+n-192]
// MODE 2: Ch bf16 [m*ldc+n]
// MODE 3: Cf fp32 = resid + skip*(v + bias[n])
// MODE 4: gate = sigmoid(v+bias[n]); Ch[m*ldc+n] = bf16(gate * bf2f(gy[m*ldc+ginv[(m>>12)*CH+n]]))
template<int BN, int MODE>
__global__ __launch_bounds__(256) void k_mm(
    const u16* __restrict__ A, int lda, long aOuter, long aInner,
    const u16* __restrict__ B, long bInner,
    float* __restrict__ Cf, u16* __restrict__ Ch,
    long cOuter, long cInner, int ldc,
    int K, int innerCnt,
    const float* __restrict__ bias, const float* __restrict__ resid,
    const float* __restrict__ skip,
    const u16* __restrict__ gy, const int* __restrict__ ginv){
  constexpr int BM = 128;
  constexpr int AI = 2;
  constexpr int BI = (BN * 32) / (256 * 8);
  constexpr int NJ = BN / 32;
  __shared__ u16 sA[BM * 32];
  __shared__ u16 sB[BN * 32];

  int bz = blockIdx.z;
  int bo = bz / innerCnt, bi_ = bz - bo * innerCnt;
  const u16* Ab = A + (long)bo * aOuter + (long)bi_ * aInner;
  const u16* Bb = B + (long)bi_ * bInner;
  int tid = threadIdx.x;
  int m0 = blockIdx.y * BM, n0 = blockIdx.x * BN;
  int wv = tid >> 6, l = tid & 63;
  int wm = (wv >> 1) * 64, wn = (wv & 1) * (BN / 2);
  int kg = l >> 4, lr = l & 15;

  f32x4 acc[4][NJ];
  #pragma unroll
  for (int i = 0; i < 4; i++)
    #pragma unroll
    for (int j = 0; j < NJ; j++)
      #pragma unroll
      for (int r = 0; r < 4; r++) acc[i][j][r] = 0.f;

  int aoffU[4], boffU[NJ];
  #pragma unroll
  for (int i = 0; i < 4; i++){
    int r = wm + i * 16 + lr;
    aoffU[i] = r * 32 + ((kg * 8) ^ ((r & 3) << 3));
  }
  #pragma unroll
  for (int j = 0; j < NJ; j++){
    int r = wn + j * 16 + lr;
    boffU[j] = r * 32 + ((kg * 8) ^ ((r & 3) << 3));
  }

  u16x8 ra[AI], rb[BI];
  #pragma unroll
  for (int q = 0; q < AI; q++){
    int i = q * 256 + tid; int row = i >> 2, sl = i & 3, ss = sl ^ (row & 3);
    ra[q] = *(const u16x8*)(Ab + (long)(m0 + row) * lda + ss * 8);
  }
  #pragma unroll
  for (int q = 0; q < BI; q++){
    int i = q * 256 + tid; int row = i >> 2, sl = i & 3, ss = sl ^ (row & 3);
    rb[q] = *(const u16x8*)(Bb + (long)(n0 + row) * K + ss * 8);
  }

  int nks = K >> 5;
  for (int ks = 0; ks < nks; ks++){
    __syncthreads();
    #pragma unroll
    for (int q = 0; q < AI; q++){
      int i = q * 256 + tid; int row = i >> 2, sl = i & 3;
      *(u16x8*)(sA + row * 32 + sl * 8) = ra[q];
    }
    #pragma unroll
    for (int q = 0; q < BI; q++){
      int i = q * 256 + tid; int row = i >> 2, sl = i & 3;
      *(u16x8*)(sB + row * 32 + sl * 8) = rb[q];
    }
    __syncthreads();
    if (ks + 1 < nks){
      int k0 = (ks + 1) * 32;
      #pragma unroll
      for (int q = 0; q < AI; q++){
        int i = q * 256 + tid; int row = i >> 2, sl = i & 3, ss = sl ^ (row & 3);
        ra[q] = *(const u16x8*)(Ab + (long)(m0 + row) * lda + k0 + ss * 8);
      }
      #pragma unroll
      for (int q = 0; q < BI; q++){
        int i = q * 256 + tid; int row = i >> 2, sl = i & 3, ss = sl ^ (row & 3);
        rb[q] = *(const u16x8*)(Bb + (long)(n0 + row) * K + k0 + ss * 8);
      }
    }
    s16x8 af[4];
    #pragma unroll
    for (int i = 0; i < 4; i++) af[i] = *(const s16x8*)(sA + aoffU[i]);
    s16x8 bfr[NJ];
    #pragma unroll
    for (int j = 0; j < NJ; j++) bfr[j] = *(const s16x8*)(sB + boffU[j]);
    #pragma unroll
    for (int i = 0; i < 4; i++)
      #pragma unroll
      for (int j = 0; j < NJ; j++)
        acc[i][j] = __builtin_amdgcn_mfma_f32_16x16x32_bf16(af[i], bfr[j], acc[i][j], 0, 0, 0);
  }

  long zc = (long)bo * cOuter + (long)bi_ * cInner;
  #pragma unroll
  for (int i = 0; i < 4; i++){
    #pragma unroll
    for (int j = 0; j < NJ; j++){
      #pragma unroll
      for (int r = 0; r < 4; r++){
        int m = m0 + wm + i * 16 + kg * 4 + r;
        int n = n0 + wn + j * 16 + lr;
        float v = acc[i][j][r];
        if constexpr (MODE == 1){
          if (n < 192) ((u16*)Cf)[zc + (long)m * 192 + n] = f2bf(v);
          else         Ch[zc + (long)m * 192 + (n - 192)] = f2bf(v);
        } else if constexpr (MODE == 2){
          Ch[zc + (long)m * ldc + n] = f2bf(v);
        } else if constexpr (MODE == 3){
          float vb = v + bias[n];
          long o = (long)m * ldc + n;
          Cf[o] = resid[o] + skip[0] * vb;
        } else {
          float gate = fsigmoid(v + bias[n]);
          int bt = m >> 12;
          float yr = bf2f(gy[(long)m * ldc + ginv[bt * CH + n]]);
          Ch[(long)m * ldc + n] = f2bf(yr * gate);
        }
      }
    }
  }
}

// ---------------- fused dt GEMM: dtraw = xcvh @ M^T; epilogue packs (dt*B*x, a) bf16x2 ----------------
__global__ __launch_bounds__(256) void k_dt(
    const u16* __restrict__ xcvh, const u16* __restrict__ Mw,
    const float* __restrict__ dtb, const float* __restrict__ Atab,
    const float* __restrict__ bc, unsigned* __restrict__ pck){
  constexpr int BM = 128, BN = 64, AI = 2, NJ = 2;
  __shared__ u16 sA[BM * 32];
  __shared__ u16 sB[BN * 32];
  int z = blockIdx.z;                 // bg*2 + k
  int bg = z >> 1, kk_ = z & 1, g = bg & 1, gk = g * 2 + kk_;
  const u16* Ab = xcvh + (long)bg * LTOK * 192;
  const u16* Bb = Mw + (long)gk * 36864;
  int tid = threadIdx.x;
  int m0 = blockIdx.y * BM, n0 = blockIdx.x * BN;
  int wv = tid >> 6, l = tid & 63;
  int wm = (wv >> 1) * 64, wn = (wv & 1) * 32;
  int kg = l >> 4, lr = l & 15;

  f32x4 acc[4][NJ];
  #pragma unroll
  for (int i = 0; i < 4; i++)
    #pragma unroll
    for (int j = 0; j < NJ; j++)
      #pragma unroll
      for (int r = 0; r < 4; r++) acc[i][j][r] = 0.f;

  int aoffU[4], boffU[NJ];
  #pragma unroll
  for (int i = 0; i < 4; i++){
    int r = wm + i * 16 + lr;
    aoffU[i] = r * 32 + ((kg * 8) ^ ((r & 3) << 3));
  }
  #pragma unroll
  for (int j = 0; j < NJ; j++){
    int r = wn + j * 16 + lr;
    boffU[j] = r * 32 + ((kg * 8) ^ ((r & 3) << 3));
  }

  u16x8 ra[AI], rb0;
  #pragma unroll
  for (int q = 0; q < AI; q++){
    int i = q * 256 + tid; int row = i >> 2, sl = i & 3, ss = sl ^ (row & 3);
    ra[q] = *(const u16x8*)(Ab + (long)(m0 + row) * 192 + ss * 8);
  }
  {
    int row = tid >> 2, sl = tid & 3, ss = sl ^ (row & 3);
    rb0 = *(const u16x8*)(Bb + (long)(n0 + row) * 192 + ss * 8);
  }

  const int nks = 6;   // K = 192
  for (int ks = 0; ks < nks; ks++){
    __syncthreads();
    #pragma unroll
    for (int q = 0; q < AI; q++){
      int i = q * 256 + tid; int row = i >> 2, sl = i & 3;
      *(u16x8*)(sA + row * 32 + sl * 8) = ra[q];
    }
    {
      int row = tid >> 2, sl = tid & 3;
      *(u16x8*)(sB + row * 32 + sl * 8) = rb0;
    }
    __syncthreads();
    if (ks + 1 < nks){
      int k0 = (ks + 1) * 32;
      #pragma unroll
      for (int q = 0; q < AI; q++){
        int i = q * 256 + tid; int row = i >> 2, sl = i & 3, ss = sl ^ (row & 3);
        ra[q] = *(const u16x8*)(Ab + (long)(m0 + row) * 192 + k0 + ss * 8);
      }
      {
        int row = tid >> 2, sl = tid & 3, ss = sl ^ (row & 3);
        rb0 = *(const u16x8*)(Bb + (long)(n0 + row) * 192 + k0 + ss * 8);
      }
    }
    s16x8 af[4], bfr[NJ];
    #pragma unroll
    for (int i = 0; i < 4; i++) af[i] = *(const s16x8*)(sA + aoffU[i]);
    #pragma unroll
    for (int j = 0; j < NJ; j++) bfr[j] = *(const s16x8*)(sB + boffU[j]);
    #pragma unroll
    for (int i = 0; i < 4; i++)
      #pragma unroll
      for (int j = 0; j < NJ; j++)
        acc[i][j] = __builtin_amdgcn_mfma_f32_16x16x32_bf16(af[i], bfr[j], acc[i][j], 0, 0, 0);
  }

  #pragma unroll
  for (int i = 0; i < 4; i++){
    #pragma unroll
    for (int j = 0; j < NJ; j++){
      #pragma unroll
      for (int r = 0; r < 4; r++){
        int m = m0 + wm + i * 16 + kg * 4 + r;
        int n = n0 + wn + j * 16 + lr;
        // dt = softplus(raw + bias) via native exp/log; a = exp(A*dt) = native
        float rr = acc[i][j][r] + dtb[gk * 192 + n];
        float dtv = __logf(1.f + __expf(rr));
        float av  = __expf(Atab[gk * 192 + n] * dtv);
        float Bv  = bc[((long)z * LTOK + m) * 2];
        float xv  = bf2f(xcvh[((long)bg * LTOK + m) * 192 + n]);
        pck[((long)z * LTOK + m) * 192 + n] =
            ((unsigned)f2bf(dtv * Bv * xv) << 16) | (unsigned)f2bf(av);
      }
    }
  }
}

// ---------------- depthwise 3x3 conv (bf16 in) + bias + silu, write bf16 in scan order ----------------
__global__ __launch_bounds__(256) void k_conv(const u16* __restrict__ xch,
    const float* __restrict__ cw, const float* __restrict__ cb, u16* __restrict__ xcvh){
  long idx = (long)blockIdx.x * 256 + threadIdx.x;
  if (idx >= (long)NB * 2 * LTOK * DH) return;
  int di = (int)(idx % DH); long t = idx / DH;
  int p = (int)(t % LTOK); t /= LTOK;
  int g = (int)(t & 1); int b = (int)(t >> 1);
  int h = p >> 6, w = p & 63;
  const float* W = cw + ((long)g * DH + di) * 9;
  long sb = ((long)(b * 2 + g)) * LTOK;
  float s = cb[g * DH + di];
  #pragma unroll
  for (int dh = -1; dh <= 1; dh++){
    int hh = h + dh; if (hh < 0 || hh >= HH) continue;
    #pragma unroll
    for (int dw = -1; dw <= 1; dw++){
      int ww2 = w + dw; if (ww2 < 0 || ww2 >= WW) continue;
      s += W[(dh + 1) * 3 + (dw + 1)] * bf2f(xch[(sb + hh * WW + ww2) * DH + di]);
    }
  }
  s = s * fsigmoid(s);
  int lscan = (g == 0) ? p : (w * HH + h);
  xcvh[(sb + (long)lscan) * DH + di] = f2bf(s);
}

// ---------------- B/C projection: 4 outputs per position ----------------
__global__ __launch_bounds__(256) void k_bc(const u16* __restrict__ xcvh,
    const float* __restrict__ xpw, float* __restrict__ bc){
  int bg = blockIdx.y;
  int g = bg & 1;
  int p0 = blockIdx.x * 8;
  __shared__ float wl[4][192];
  __shared__ float xr[8][192];
  int tid = threadIdx.x;
  for (int i = tid; i < 4 * 192; i += 256){
    int j = i / 192, c = i - j * 192;
    int k = j >> 1, col = 12 + (j & 1);
    wl[j][c] = xpw[(long)g * 5376 + (k * 14 + col) * 192 + c];
  }
  for (int i = tid; i < 8 * 192; i += 256){
    xr[i / 192][i % 192] = bf2f(xcvh[((long)bg * LTOK + p0 + i / 192) * DH + (i % 192)]);
  }
  __syncthreads();
  int pos = tid >> 5, j = tid & 31;
  if (j < 4){
    float s = 0.f;
    for (int c = 0; c < 192; c++) s += xr[pos][c] * wl[j][c];
    int k = j >> 1;
    bc[(((long)(bg * 2 + k)) * LTOK + p0 + pos) * 2 + (j & 1)] = s;
  }
}

// ---------------- chunked parallel selective scan (precomputed a, dt*B*x) ----------------
__global__ __launch_bounds__(192) void k_scan_p1(const unsigned* __restrict__ pck,
    float* __restrict__ cP, float* __restrict__ cS){
  int bg = blockIdx.x, k = blockIdx.y, c = blockIdx.z;
  int z = bg * 2 + k;
  int di = threadIdx.x;
  const unsigned* pk = pck + (long)z * LTOK * 192 + di;
  float P = 1.f, S = 0.f;
  int l  = (k == 0) ? c * CHS : (LTOK - 1 - c * CHS);
  int dl = (k == 0) ? 1 : -1;
  for (int s = 0; s < CHS; s++, l += dl){
    unsigned v = pk[(long)l * 192];
    float a   = bf2f((u16)(v & 0xFFFFu));
    float dBx = bf2f((u16)(v >> 16));
    P *= a;
    S = a * S + dBx;
  }
  long idx = ((long)z * NCHK + c) * 192 + di;
  cP[idx] = P;
  cS[idx] = S;
}

__global__ __launch_bounds__(192) void k_scan_p2(const float* __restrict__ cP,
    const float* __restrict__ cS, float* __restrict__ h0){
  int z = blockIdx.x;              // 0..31
  int di = threadIdx.x;
  float h = 0.f;
  for (int c = 0; c < NCHK; c++){
    long idx = ((long)z * NCHK + c) * 192 + di;
    h0[idx] = h;
    h = cP[idx] * h + cS[idx];
  }
}

__global__ __launch_bounds__(192) void k_scan_p3(const unsigned* __restrict__ pck,
    const u16* __restrict__ xcvh, const float* __restrict__ bc,
    const float* __restrict__ ds, const float* __restrict__ h0,
    u16* __restrict__ ydir){
  int bg = blockIdx.x, c = blockIdx.y;
  int g = bg & 1;
  int di = threadIdx.x;
  const u16* xc = xcvh + (long)bg * LTOK * 192 + di;
  u16* yo = ydir + (long)bg * LTOK * 192 + di;
  #pragma unroll
  for (int k = 0; k < 2; k++){
    int z = bg * 2 + k, gk = g * 2 + k;
    float Dv = ds[gk * 192 + di];
    const unsigned* pk = pck + (long)z * LTOK * 192 + di;
    const float* bcp = bc + (long)z * LTOK * 2;
    int cc = (k == 0) ? c : (NCHK - 1 - c);
    float h = h0[((long)z * NCHK + cc) * 192 + di];
    int l  = (k == 0) ? c * CHS : (c * CHS + CHS - 1);
    int dl = (k == 0) ? 1 : -1;
    for (int s = 0; s < CHS; s++, l += dl){
      unsigned v = pk[(long)l * 192];
      float a   = bf2f((u16)(v & 0xFFFFu));
      float dBx = bf2f((u16)(v >> 16));
      float xv  = bf2f(xc[(long)l * 192]);
      h = a * h + dBx;
      float y = h * bcp[l * 2 + 1] + Dv * xv;
      if (k == 0) yo[(long)l * 192] = f2bf(y);
      else        yo[(long)l * 192] = f2bf(bf2f(yo[(long)l * 192]) + y);
    }
  }
}

// ---------------- combine directions + out-LN + *silu(z) -> bf16 ----------------
__global__ __launch_bounds__(192) void k_combine(const u16* __restrict__ ydir,
    const u16* __restrict__ zh, const float* __restrict__ ong, const float* __restrict__ onb,
    u16* __restrict__ yab){
  __shared__ float sm[3];
  int p = blockIdx.x; int bg = blockIdx.y; int g = bg & 1;
  int h = p >> 6, w = p & 63;
  int l = (g == 0) ? p : (w * HH + h);
  int di = threadIdx.x;
  float y = bf2f(ydir[((long)bg * LTOK + l) * DH + di]);
  float s = blockSum<3>(y, sm);
  float m = s * (1.f / DH);
  float d = y - m;
  float vs = blockSum<3>(d * d, sm);
  float inv = rsqrtf(vs * (1.f / DH) + 1e-5f);
  float yl = d * inv * ong[g * DH + di] + onb[g * DH + di];
  float z = bf2f(zh[((long)bg * LTOK + p) * DH + di]);
  yab[((long)bg * LTOK + p) * DH + di] = f2bf(yl * z * fsigmoid(z));
}

extern "C" void kernel_launch(void* const* d_in, const int* in_sizes, int n_in,
                              void* d_out, int out_size, void* d_ws, size_t ws_size,
                              hipStream_t stream){
  const float* x       = (const float*)d_in[0];
  const float* norm_g  = (const float*)d_in[1];
  const float* norm_b  = (const float*)d_in[2];
  const float* r_w1    = (const float*)d_in[3];
  const float* r_b1    = (const float*)d_in[4];
  const float* r_w2    = (const float*)d_in[5];
  const float* r_b2    = (const float*)d_in[6];
  const float* in_proj = (const float*)d_in[7];
  const float* conv_w  = (const float*)d_in[8];
  const float* conv_b  = (const float*)d_in[9];
  const float* xp_w    = (const float*)d_in[10];
  const float* dt_w    = (const float*)d_in[11];
  const float* dt_b    = (const float*)d_in[12];
  const float* A_log   = (const float*)d_in[13];
  const float* Ds      = (const float*)d_in[14];
  const float* on_g    = (const float*)d_in[15];
  const float* on_b    = (const float*)d_in[16];
  const float* op_w    = (const float*)d_in[17];
  const float* ci_w1   = (const float*)d_in[18];
  const float* ci_b1   = (const float*)d_in[19];
  const float* ci_w2   = (const float*)d_in[20];
  const float* ci_b2   = (const float*)d_in[21];
  const float* proj_w  = (const float*)d_in[22];
  const float* proj_b  = (const float*)d_in[23];
  const float* skip    = (const float*)d_in[24];
  float* out = (float*)d_out;
  float* ws  = (float*)d_ws;

  // Regions (floats):
  // R12 = ws[0 .. 2*BLC)      : xn fp32 (BLC) + xcbh bf16 region  -> later pck u32 (2*BLC)
  // R3  = [2*BLC .. 2.5*BLC)  : zh bf16 -> ycat bf16
  // R4  = [2.5B .. 3*BLC)     : xcvh bf16 -> yab bf16
  // R5  = [3*BLC .. 3.5*BLC)  : As bf16 -> ydir bf16
  float* xn   = ws;
  float* xcb  = ws + BLC;
  float* R3   = ws + 2 * BLC;
  float* R4   = R3 + BLC / 2;
  float* R5   = R4 + BLC / 2;
  float* pp   = R5 + BLC / 2;
  int*  sidx  = (int*)(pp + NB * 16 * CH);
  int*  inv   = sidx + NB * CH;
  u16*  wip   = (u16*)(inv + NB * CH);   // 2*384*192
  u16*  wop   = wip + 2 * 384 * 192;     // 2*192*192
  u16*  wpj   = wop + 2 * 192 * 192;     // 384*384
  u16*  w1g   = wpj + 384 * 384;         // NB*32*384
  u16*  w2p   = w1g + NB * 32 * CH;      // 384*32
  u16*  Mw    = w2p + CH * 32;           // 4*192*192
  float* b1p  = (float*)(Mw + 4 * 192 * 192);
  float* Atab = b1p + 32;                // 4*192
  u16*  hidp  = (u16*)(Atab + 4 * 192);  // NB*4096*32
  float* bc   = (float*)(hidp + (long)NB * LTOK * 32);  // 32*4096*2
  float* cP   = bc + 32 * LTOK * 2;
  float* cS   = cP + CST;
  float* h0   = cS + CST;

  size_t need = ((size_t)(2 * BLC) + 3 * (BLC / 2) + NB * 16 * CH + 32 * LTOK * 2 + 3 * CST + 64) * 4
              + (size_t)(2 * NB * CH) * 4 + (size_t)(4 * 192 + 32) * 4
              + ((size_t)2*384*192 + 2*192*192 + 384*384 + NB*32*CH + CH*32 + 4*192*192
                 + (size_t)NB * LTOK * 32) * 2
              + 8192;
  if (ws_size < need) return;

  // aliases
  u16*  As   = (u16*)R5;
  u16*  zh   = (u16*)R3;
  u16*  xcbh = (u16*)xcb;               // bf16 conv input (half of xcb region)
  u16*  xcvh = (u16*)R4;
  unsigned* pck = (unsigned*)ws;        // spans R12 (xn, xcbh both dead by then)
  u16*  ydir = (u16*)R5;
  u16*  yab  = (u16*)R4;
  u16*  ycat = (u16*)R3;
  u16*  gab  = (u16*)xcb;
  // NOTE: gab aliases xcb region, but pck (u32, 2*BLC) also covers it; gab is
  // written by MODE 4 AFTER pck's last reader (scan_p3) -> safe.

  k_ln<<<NB * LTOK, 128, 0, stream>>>(x, norm_g, norm_b, xn);
  k_cast<<<(2*384*192 + 255)/256, 256, 0, stream>>>(in_proj, wip, 2*384*192);
  k_cast<<<(2*192*192 + 255)/256, 256, 0, stream>>>(op_w,    wop, 2*192*192);
  k_cast<<<(384*384   + 255)/256, 256, 0, stream>>>(proj_w,  wpj, 384*384);
  k_prepA<<<3, 256, 0, stream>>>(A_log, Atab);
  k_prepM<<<dim3(144, 4), 256, 0, stream>>>(dt_w, xp_w, Mw);
  k_pool<<<dim3(3, 16, NB), 128, 0, stream>>>(xn, pp);
  k_score<<<NB, 384, 0, stream>>>(pp, r_w1, r_b1, r_w2, r_b2, sidx, inv);
  k_castgather<<<NB * LTOK, 384, 0, stream>>>(xn, sidx, As);
  k_prepw<<<NB + 1, 256, 0, stream>>>(ci_w1, ci_b1, ci_w2, sidx, w1g, w2p, b1p);

  // in_proj: per (b,g): [4096x192]@[384x192]^T -> xcbh bf16 + zh bf16
  k_mm<128, 1><<<dim3(3, 32, 16), 256, 0, stream>>>(
      As, CH, (long)LTOK * CH, 192,
      wip, (long)384 * 192,
      (float*)xcbh, zh, (long)2 * LTOK * DH, (long)LTOK * DH, 0,
      192, 2, nullptr, nullptr, nullptr, nullptr, nullptr);

  // gate stage 1 (uses As; before R5 is recycled by scan p3)
  k_hid<<<dim3(32, NB), 256, 0, stream>>>(As, w1g, b1p, hidp);

  k_conv<<<(int)(((long)NB * 2 * LTOK * DH + 255) / 256), 256, 0, stream>>>(xcbh, conv_w, conv_b, xcvh);
  k_bc<<<dim3(LTOK / 8, NB * 2), 256, 0, stream>>>(xcvh, xp_w, bc);

  // fused dt GEMM -> packed (dt*B*x, a) bf16x2 (overwrites xn+xcbh regions)
  k_dt<<<dim3(3, 32, 32), 256, 0, stream>>>(xcvh, Mw, dt_b, Atab, bc, pck);

  k_scan_p1<<<dim3(NB * 2, 2, NCHK), 192, 0, stream>>>(pck, cP, cS);
  k_scan_p2<<<32, 192, 0, stream>>>(cP, cS, h0);
  k_scan_p3<<<dim3(NB * 2, NCHK), 192, 0, stream>>>(pck, xcvh, bc, Ds, h0, ydir);

  k_combine<<<dim3(LTOK, NB * 2), 192, 0, stream>>>(ydir, zh, on_g, on_b, yab);

  // out_proj: per (b,g): [4096x192]@[192x192]^T -> ycat bf16 (col offset g*192)
  k_mm<64, 2><<<dim3(3, 32, 16), 256, 0, stream>>>(
      yab, DH, (long)2 * LTOK * DH, (long)LTOK * DH,
      wop, (long)192 * 192,
      nullptr, ycat, (long)LTOK * CH, 192, CH,
      192, 2, nullptr, nullptr, nullptr, nullptr, nullptr);

  // gate stage 2 + un-sort gather + multiply
  k_mm<128, 4><<<dim3(3, 256, 1), 256, 0, stream>>>(
      hidp, 32, 0, 0,
      w2p, 0,
      nullptr, gab, 0, 0, CH,
      32, 1, ci_b2, nullptr, nullptr, ycat, inv);

  // final: out = x + skip * (gab @ proj_w^T + proj_b)
  k_mm<128, 3><<<dim3(3, 256, 1), 256, 0, stream>>>(
      gab, CH, 0, 0,
      wpj, 0,
      out, nullptr, 0, 0, CH,
      CH, 1, proj_b, x, skip, nullptr, nullptr);
}

// Round 8
// 474.176 us; speedup vs baseline: 17.7285x; 1.1533x over previous
//
#include <hip/hip_runtime.h>
#include <math.h>

// Problem constants (fixed by the reference module)
#define NB 8
#define LTOK 4096
#define CH 384
#define DH 192
#define HH 64
#define WW 64
#define NCHK 128     // chunks per sequence
#define CHS 32       // steps per chunk (LTOK / NCHK)

static constexpr long BLC  = (long)NB * LTOK * CH;   // 12,582,912 elements
static constexpr long CST  = (long)32 * NCHK * DH;   // 786,432 per chunk-state buffer

typedef unsigned short u16;
typedef u16   u16x8 __attribute__((ext_vector_type(8)));
typedef short s16x8 __attribute__((ext_vector_type(8)));
typedef float f32x4 __attribute__((ext_vector_type(4)));

__device__ inline u16 f2bf(float f){
  unsigned int u = __float_as_uint(f);
  return (u16)((u + 0x7FFFu + ((u >> 16) & 1u)) >> 16);
}
__device__ inline float bf2f(u16 h){ return __uint_as_float(((unsigned int)h) << 16); }
__device__ inline float fsigmoid(float x){ return 1.f / (1.f + __expf(-x)); }

template<int NW>
__device__ inline float blockSum(float v, float* sm){
  #pragma unroll
  for (int o = 32; o > 0; o >>= 1) v += __shfl_down(v, o);
  int lane = threadIdx.x & 63, wv = threadIdx.x >> 6;
  if (lane == 0) sm[wv] = v;
  __syncthreads();
  if (threadIdx.x == 0){ float t = 0.f; for (int i = 0; i < NW; i++) t += sm[i]; sm[0] = t; }
  __syncthreads();
  float t = sm[0];
  __syncthreads();
  return t;
}

// ---------------- LayerNorm over C=384 per token ----------------
__global__ __launch_bounds__(128) void k_ln(const float* __restrict__ x,
    const float* __restrict__ g, const float* __restrict__ b, float* __restrict__ xn){
  __shared__ float sm[2];
  long row = blockIdx.x;
  int t = threadIdx.x;
  const float* xr = x + row * CH;
  float v0 = xr[t], v1 = xr[t + 128], v2 = xr[t + 256];
  float s = blockSum<2>(v0 + v1 + v2, sm);
  float m = s * (1.f / CH);
  float d0 = v0 - m, d1 = v1 - m, d2 = v2 - m;
  float vs = blockSum<2>(d0*d0 + d1*d1 + d2*d2, sm);
  float inv = rsqrtf(vs * (1.f / CH) + 1e-5f);
  float* o = xn + row * CH;
  o[t]       = d0 * inv * g[t]       + b[t];
  o[t + 128] = d1 * inv * g[t + 128] + b[t + 128];
  o[t + 256] = d2 * inv * g[t + 256] + b[t + 256];
}

// ---------------- partial pooling ----------------
__global__ __launch_bounds__(128) void k_pool(const float* __restrict__ xn, float* __restrict__ pp){
  int c = blockIdx.x * 128 + threadIdx.x;
  int chunk = blockIdx.y, b = blockIdx.z;
  long base = ((long)b * LTOK + chunk * 256) * CH;
  float s = 0.f;
  for (int n = 0; n < 256; n++) s += xn[base + (long)n * CH + c];
  pp[((long)b * 16 + chunk) * CH + c] = s;
}

// ---------------- score MLP + stable argsort (descending) ----------------
__global__ __launch_bounds__(384) void k_score(const float* __restrict__ pp,
    const float* __restrict__ w1, const float* __restrict__ b1,
    const float* __restrict__ w2, const float* __restrict__ b2,
    int* __restrict__ sidx, int* __restrict__ inv){
  __shared__ float poolv[CH];
  __shared__ float hid[192];
  __shared__ float sc[CH];
  int b = blockIdx.x, t = threadIdx.x;
  float s = 0.f;
  for (int ch = 0; ch < 16; ch++) s += pp[((long)b * 16 + ch) * CH + t];
  poolv[t] = s * (1.f / LTOK);
  __syncthreads();
  if (t < 192){
    float h = b1[t];
    for (int c = 0; c < CH; c++) h += poolv[c] * w1[t * CH + c];
    hid[t] = fmaxf(h, 0.f);
  }
  __syncthreads();
  {
    float h = b2[t];
    for (int j = 0; j < 192; j++) h += hid[j] * w2[t * 192 + j];
    sc[t] = 1.f / (1.f + expf(-h));
  }
  __syncthreads();
  float mys = sc[t];
  int rank = 0;
  for (int j = 0; j < CH; j++){
    float o = sc[j];
    rank += (o > mys) || (o == mys && j < t);
  }
  sidx[b * CH + rank] = t;
  inv[b * CH + t] = rank;
}

// ---------------- cast fp32 -> bf16 (weights) ----------------
__global__ __launch_bounds__(256) void k_cast(const float* __restrict__ s,
    u16* __restrict__ d, int n){
  int i = blockIdx.x * 256 + threadIdx.x;
  if (i < n) d[i] = f2bf(s[i]);
}

// ---------------- precompute A table: Atab = -exp(A_log) ----------------
__global__ __launch_bounds__(256) void k_prepA(const float* __restrict__ alog,
    float* __restrict__ Atab){
  int i = blockIdx.x * 256 + threadIdx.x;
  if (i < 4 * 192) Atab[i] = -expf(alog[i]);
}

// ---------------- prep conv weights: tap-major bf16 [g][9][DH] ----------------
__global__ __launch_bounds__(256) void k_prepcw(const float* __restrict__ cw,
    u16* __restrict__ cwb){
  int i = blockIdx.x * 256 + threadIdx.x;
  if (i < 2 * 9 * DH){
    int g = i / (9 * DH); int r = i - g * 9 * DH;
    int tap = r / DH; int di = r - tap * DH;
    cwb[i] = f2bf(cw[((long)g * DH + di) * 9 + tap]);
  }
}

// ---------------- gather sorted channels + cast to bf16 ----------------
__global__ __launch_bounds__(384) void k_castgather(const float* __restrict__ xn,
    const int* __restrict__ sidx, u16* __restrict__ As){
  long row = blockIdx.x;
  int b = (int)(row >> 12);
  int t = threadIdx.x;
  int c = sidx[b * CH + t];
  As[row * CH + t] = f2bf(xn[row * CH + c]);
}

// ---------------- prep gate-MLP weights: gathered w1 (per batch), padded w2, b1 ----------------
__global__ __launch_bounds__(256) void k_prepw(const float* __restrict__ w1,
    const float* __restrict__ b1, const float* __restrict__ w2,
    const int* __restrict__ sidx, u16* __restrict__ w1g, u16* __restrict__ w2p,
    float* __restrict__ b1p){
  int b = blockIdx.x, tid = threadIdx.x;
  if (b < NB){
    const int* sx = sidx + b * CH;
    for (int i = tid; i < 32 * CH; i += 256){
      int j = i / CH, r = i - j * CH;
      float v = (j < 24) ? w1[j * CH + sx[r]] : 0.f;
      w1g[(long)b * 32 * CH + i] = f2bf(v);
    }
  } else {
    for (int i = tid; i < CH * 32; i += 256){
      int n = i >> 5, j = i & 31;
      w2p[i] = f2bf((j < 24) ? w2[n * 24 + j] : 0.f);
    }
    if (tid < 32) b1p[tid] = (tid < 24) ? b1[tid] : 0.f;
  }
}

// ---------------- prep fused dt matrices ----------------
__global__ __launch_bounds__(256) void k_prepM(const float* __restrict__ dtw,
    const float* __restrict__ xpw, u16* __restrict__ Mw){
  int gk = blockIdx.y;
  int g = gk >> 1, k = gk & 1;
  int idx = blockIdx.x * 256 + threadIdx.x;   // < 36864
  int di = idx / 192, c = idx - di * 192;
  float s = 0.f;
  #pragma unroll
  for (int r = 0; r < 12; r++)
    s += dtw[((long)gk * 192 + di) * 12 + r] * xpw[(long)g * 5376 + (k * 14 + r) * 192 + c];
  Mw[(long)gk * 36864 + idx] = f2bf(s);
}

// ---------------- gate stage 1: hid = relu(As @ w1g^T + b1p), bf16 out ----------------
__global__ __launch_bounds__(256) void k_hid(const u16* __restrict__ As,
    const u16* __restrict__ w1g, const float* __restrict__ b1p,
    u16* __restrict__ hidp){
  __shared__ u16 sA[128 * 32];
  __shared__ u16 sB[32 * 32];
  int b = blockIdx.y;
  const u16* Ab = As + (long)b * LTOK * CH;
  const u16* Bb = w1g + (long)b * 32 * CH;
  int tid = threadIdx.x;
  int m0 = blockIdx.x * 128;
  int wv = tid >> 6, l = tid & 63;
  int wm = wv * 32;
  int kg = l >> 4, lr = l & 15;

  f32x4 acc[2][2];
  #pragma unroll
  for (int i = 0; i < 2; i++)
    #pragma unroll
    for (int j = 0; j < 2; j++)
      #pragma unroll
      for (int r = 0; r < 4; r++) acc[i][j][r] = 0.f;

  int aoffU[2], boffU[2];
  #pragma unroll
  for (int i = 0; i < 2; i++){
    int r = wm + i * 16 + lr;
    aoffU[i] = r * 32 + ((kg * 8) ^ ((r & 3) << 3));
  }
  #pragma unroll
  for (int j = 0; j < 2; j++){
    int r = j * 16 + lr;
    boffU[j] = r * 32 + ((kg * 8) ^ ((r & 3) << 3));
  }

  u16x8 ra[2], rbv;
  #pragma unroll
  for (int q = 0; q < 2; q++){
    int i = q * 256 + tid; int row = i >> 2, sl = i & 3, ss = sl ^ (row & 3);
    ra[q] = *(const u16x8*)(Ab + (long)(m0 + row) * CH + ss * 8);
  }
  if (tid < 128){
    int row = tid >> 2, sl = tid & 3, ss = sl ^ (row & 3);
    rbv = *(const u16x8*)(Bb + (long)row * CH + ss * 8);
  }

  const int nks = CH / 32;   // 12
  for (int ks = 0; ks < nks; ks++){
    __syncthreads();
    #pragma unroll
    for (int q = 0; q < 2; q++){
      int i = q * 256 + tid; int row = i >> 2, sl = i & 3;
      *(u16x8*)(sA + row * 32 + sl * 8) = ra[q];
    }
    if (tid < 128){
      int row = tid >> 2, sl = tid & 3;
      *(u16x8*)(sB + row * 32 + sl * 8) = rbv;
    }
    __syncthreads();
    if (ks + 1 < nks){
      int k0 = (ks + 1) * 32;
      #pragma unroll
      for (int q = 0; q < 2; q++){
        int i = q * 256 + tid; int row = i >> 2, sl = i & 3, ss = sl ^ (row & 3);
        ra[q] = *(const u16x8*)(Ab + (long)(m0 + row) * CH + k0 + ss * 8);
      }
      if (tid < 128){
        int row = tid >> 2, sl = tid & 3, ss = sl ^ (row & 3);
        rbv = *(const u16x8*)(Bb + (long)row * CH + k0 + ss * 8);
      }
    }
    s16x8 af[2], bfr[2];
    #pragma unroll
    for (int i = 0; i < 2; i++) af[i] = *(const s16x8*)(sA + aoffU[i]);
    #pragma unroll
    for (int j = 0; j < 2; j++) bfr[j] = *(const s16x8*)(sB + boffU[j]);
    #pragma unroll
    for (int i = 0; i < 2; i++)
      #pragma unroll
      for (int j = 0; j < 2; j++)
        acc[i][j] = __builtin_amdgcn_mfma_f32_16x16x32_bf16(af[i], bfr[j], acc[i][j], 0, 0, 0);
  }

  #pragma unroll
  for (int i = 0; i < 2; i++)
    #pragma unroll
    for (int j = 0; j < 2; j++)
      #pragma unroll
      for (int r = 0; r < 4; r++){
        int m = m0 + wm + i * 16 + kg * 4 + r;
        int n = j * 16 + lr;
        float v = fmaxf(acc[i][j][r] + b1p[n], 0.f);
        hidp[((long)b * LTOK + m) * 32 + n] = f2bf(v);
      }
}

// ---------------- bf16 MFMA GEMM: C = A @ B^T ----------------
// MODE 1: split epilogue: n<192 -> ((u16*)Cf) bf16 [m*192+n]; n>=192 -> Ch bf16 [m*192+n-192]
// MODE 2: Ch bf16 [m*ldc+n]
// MODE 3: Cf fp32 = resid + skip*(v + bias[n])
// MODE 4: gate = sigmoid(v+bias[n]); Ch[m*ldc+n] = bf16(gate * bf2f(gy[m*ldc+ginv[(m>>12)*CH+n]]))
template<int BN, int MODE>
__global__ __launch_bounds__(256) void k_mm(
    const u16* __restrict__ A, int lda, long aOuter, long aInner,
    const u16* __restrict__ B, long bInner,
    float* __restrict__ Cf, u16* __restrict__ Ch,
    long cOuter, long cInner, int ldc,
    int K, int innerCnt,
    const float* __restrict__ bias, const float* __restrict__ resid,
    const float* __restrict__ skip,
    const u16* __restrict__ gy, const int* __restrict__ ginv){
  constexpr int BM = 128;
  constexpr int AI = 2;
  constexpr int BI = (BN * 32) / (256 * 8);
  constexpr int NJ = BN / 32;
  __shared__ u16 sA[BM * 32];
  __shared__ u16 sB[BN * 32];

  int bz = blockIdx.z;
  int bo = bz / innerCnt, bi_ = bz - bo * innerCnt;
  const u16* Ab = A + (long)bo * aOuter + (long)bi_ * aInner;
  const u16* Bb = B + (long)bi_ * bInner;
  int tid = threadIdx.x;
  int m0 = blockIdx.y * BM, n0 = blockIdx.x * BN;
  int wv = tid >> 6, l = tid & 63;
  int wm = (wv >> 1) * 64, wn = (wv & 1) * (BN / 2);
  int kg = l >> 4, lr = l & 15;

  f32x4 acc[4][NJ];
  #pragma unroll
  for (int i = 0; i < 4; i++)
    #pragma unroll
    for (int j = 0; j < NJ; j++)
      #pragma unroll
      for (int r = 0; r < 4; r++) acc[i][j][r] = 0.f;

  int aoffU[4], boffU[NJ];
  #pragma unroll
  for (int i = 0; i < 4; i++){
    int r = wm + i * 16 + lr;
    aoffU[i] = r * 32 + ((kg * 8) ^ ((r & 3) << 3));
  }
  #pragma unroll
  for (int j = 0; j < NJ; j++){
    int r = wn + j * 16 + lr;
    boffU[j] = r * 32 + ((kg * 8) ^ ((r & 3) << 3));
  }

  u16x8 ra[AI], rb[BI];
  #pragma unroll
  for (int q = 0; q < AI; q++){
    int i = q * 256 + tid; int row = i >> 2, sl = i & 3, ss = sl ^ (row & 3);
    ra[q] = *(const u16x8*)(Ab + (long)(m0 + row) * lda + ss * 8);
  }
  #pragma unroll
  for (int q = 0; q < BI; q++){
    int i = q * 256 + tid; int row = i >> 2, sl = i & 3, ss = sl ^ (row & 3);
    rb[q] = *(const u16x8*)(Bb + (long)(n0 + row) * K + ss * 8);
  }

  int nks = K >> 5;
  for (int ks = 0; ks < nks; ks++){
    __syncthreads();
    #pragma unroll
    for (int q = 0; q < AI; q++){
      int i = q * 256 + tid; int row = i >> 2, sl = i & 3;
      *(u16x8*)(sA + row * 32 + sl * 8) = ra[q];
    }
    #pragma unroll
    for (int q = 0; q < BI; q++){
      int i = q * 256 + tid; int row = i >> 2, sl = i & 3;
      *(u16x8*)(sB + row * 32 + sl * 8) = rb[q];
    }
    __syncthreads();
    if (ks + 1 < nks){
      int k0 = (ks + 1) * 32;
      #pragma unroll
      for (int q = 0; q < AI; q++){
        int i = q * 256 + tid; int row = i >> 2, sl = i & 3, ss = sl ^ (row & 3);
        ra[q] = *(const u16x8*)(Ab + (long)(m0 + row) * lda + k0 + ss * 8);
      }
      #pragma unroll
      for (int q = 0; q < BI; q++){
        int i = q * 256 + tid; int row = i >> 2, sl = i & 3, ss = sl ^ (row & 3);
        rb[q] = *(const u16x8*)(Bb + (long)(n0 + row) * K + k0 + ss * 8);
      }
    }
    s16x8 af[4];
    #pragma unroll
    for (int i = 0; i < 4; i++) af[i] = *(const s16x8*)(sA + aoffU[i]);
    s16x8 bfr[NJ];
    #pragma unroll
    for (int j = 0; j < NJ; j++) bfr[j] = *(const s16x8*)(sB + boffU[j]);
    #pragma unroll
    for (int i = 0; i < 4; i++)
      #pragma unroll
      for (int j = 0; j < NJ; j++)
        acc[i][j] = __builtin_amdgcn_mfma_f32_16x16x32_bf16(af[i], bfr[j], acc[i][j], 0, 0, 0);
  }

  long zc = (long)bo * cOuter + (long)bi_ * cInner;
  #pragma unroll
  for (int i = 0; i < 4; i++){
    #pragma unroll
    for (int j = 0; j < NJ; j++){
      #pragma unroll
      for (int r = 0; r < 4; r++){
        int m = m0 + wm + i * 16 + kg * 4 + r;
        int n = n0 + wn + j * 16 + lr;
        float v = acc[i][j][r];
        if constexpr (MODE == 1){
          if (n < 192) ((u16*)Cf)[zc + (long)m * 192 + n] = f2bf(v);
          else         Ch[zc + (long)m * 192 + (n - 192)] = f2bf(v);
        } else if constexpr (MODE == 2){
          Ch[zc + (long)m * ldc + n] = f2bf(v);
        } else if constexpr (MODE == 3){
          float vb = v + bias[n];
          long o = (long)m * ldc + n;
          Cf[o] = resid[o] + skip[0] * vb;
        } else {
          float gate = fsigmoid(v + bias[n]);
          int bt = m >> 12;
          float yr = bf2f(gy[(long)m * ldc + ginv[bt * CH + n]]);
          Ch[(long)m * ldc + n] = f2bf(yr * gate);
        }
      }
    }
  }
}

// ---------------- fused dt GEMM: dtraw = xcvh @ M^T; epilogue packs (dt*B*x, a) bf16x2 ----------------
__global__ __launch_bounds__(256) void k_dt(
    const u16* __restrict__ xcvh, const u16* __restrict__ Mw,
    const float* __restrict__ dtb, const float* __restrict__ Atab,
    const float* __restrict__ bc, unsigned* __restrict__ pck){
  constexpr int BM = 128, AI = 2, NJ = 2;
  __shared__ u16 sA[BM * 32];
  __shared__ u16 sB[64 * 32];
  int z = blockIdx.z;                 // bg*2 + k
  int bg = z >> 1, kk_ = z & 1, g = bg & 1, gk = g * 2 + kk_;
  const u16* Ab = xcvh + (long)bg * LTOK * 192;
  const u16* Bb = Mw + (long)gk * 36864;
  int tid = threadIdx.x;
  int m0 = blockIdx.y * BM, n0 = blockIdx.x * 64;
  int wv = tid >> 6, l = tid & 63;
  int wm = (wv >> 1) * 64, wn = (wv & 1) * 32;
  int kg = l >> 4, lr = l & 15;

  f32x4 acc[4][NJ];
  #pragma unroll
  for (int i = 0; i < 4; i++)
    #pragma unroll
    for (int j = 0; j < NJ; j++)
      #pragma unroll
      for (int r = 0; r < 4; r++) acc[i][j][r] = 0.f;

  int aoffU[4], boffU[NJ];
  #pragma unroll
  for (int i = 0; i < 4; i++){
    int r = wm + i * 16 + lr;
    aoffU[i] = r * 32 + ((kg * 8) ^ ((r & 3) << 3));
  }
  #pragma unroll
  for (int j = 0; j < NJ; j++){
    int r = wn + j * 16 + lr;
    boffU[j] = r * 32 + ((kg * 8) ^ ((r & 3) << 3));
  }

  u16x8 ra[AI], rb0;
  #pragma unroll
  for (int q = 0; q < AI; q++){
    int i = q * 256 + tid; int row = i >> 2, sl = i & 3, ss = sl ^ (row & 3);
    ra[q] = *(const u16x8*)(Ab + (long)(m0 + row) * 192 + ss * 8);
  }
  {
    int row = tid >> 2, sl = tid & 3, ss = sl ^ (row & 3);
    rb0 = *(const u16x8*)(Bb + (long)(n0 + row) * 192 + ss * 8);
  }

  const int nks = 6;   // K = 192
  for (int ks = 0; ks < nks; ks++){
    __syncthreads();
    #pragma unroll
    for (int q = 0; q < AI; q++){
      int i = q * 256 + tid; int row = i >> 2, sl = i & 3;
      *(u16x8*)(sA + row * 32 + sl * 8) = ra[q];
    }
    {
      int row = tid >> 2, sl = tid & 3;
      *(u16x8*)(sB + row * 32 + sl * 8) = rb0;
    }
    __syncthreads();
    if (ks + 1 < nks){
      int k0 = (ks + 1) * 32;
      #pragma unroll
      for (int q = 0; q < AI; q++){
        int i = q * 256 + tid; int row = i >> 2, sl = i & 3, ss = sl ^ (row & 3);
        ra[q] = *(const u16x8*)(Ab + (long)(m0 + row) * 192 + k0 + ss * 8);
      }
      {
        int row = tid >> 2, sl = tid & 3, ss = sl ^ (row & 3);
        rb0 = *(const u16x8*)(Bb + (long)(n0 + row) * 192 + k0 + ss * 8);
      }
    }
    s16x8 af[4], bfr[NJ];
    #pragma unroll
    for (int i = 0; i < 4; i++) af[i] = *(const s16x8*)(sA + aoffU[i]);
    #pragma unroll
    for (int j = 0; j < NJ; j++) bfr[j] = *(const s16x8*)(sB + boffU[j]);
    #pragma unroll
    for (int i = 0; i < 4; i++)
      #pragma unroll
      for (int j = 0; j < NJ; j++)
        acc[i][j] = __builtin_amdgcn_mfma_f32_16x16x32_bf16(af[i], bfr[j], acc[i][j], 0, 0, 0);
  }

  #pragma unroll
  for (int i = 0; i < 4; i++){
    #pragma unroll
    for (int j = 0; j < NJ; j++){
      #pragma unroll
      for (int r = 0; r < 4; r++){
        int m = m0 + wm + i * 16 + kg * 4 + r;
        int n = n0 + wn + j * 16 + lr;
        float rr = acc[i][j][r] + dtb[gk * 192 + n];
        float dtv = __logf(1.f + __expf(rr));
        float av  = __expf(Atab[gk * 192 + n] * dtv);
        float Bv  = bc[((long)z * LTOK + m) * 2];
        float xv  = bf2f(xcvh[((long)bg * LTOK + m) * 192 + n]);
        pck[((long)z * LTOK + m) * 192 + n] =
            ((unsigned)f2bf(dtv * Bv * xv) << 16) | (unsigned)f2bf(av);
      }
    }
  }
}

// ---------------- depthwise 3x3 conv, channel-vectorized (u16x8/thread) ----------------
__global__ __launch_bounds__(192) void k_conv(const u16* __restrict__ xch,
    const u16* __restrict__ cwb, const float* __restrict__ cb, u16* __restrict__ xcvh){
  int tid = threadIdx.x;
  int chg = tid % 24, pp = tid / 24;    // 24 channel-groups x 8 positions
  int p = blockIdx.x * 8 + pp;
  int bg = blockIdx.y; int g = bg & 1;
  int h = p >> 6, w = p & 63;
  int di = chg * 8;
  long sb = (long)bg * LTOK;

  // hoist 9 weight vectors (L1-resident)
  u16x8 wv[9];
  #pragma unroll
  for (int t = 0; t < 9; t++)
    wv[t] = *(const u16x8*)(cwb + ((long)g * 9 + t) * DH + di);

  float acc[8];
  #pragma unroll
  for (int j = 0; j < 8; j++) acc[j] = cb[g * DH + di + j];

  #pragma unroll
  for (int dh = -1; dh <= 1; dh++){
    int hh = h + dh; if (hh < 0 || hh >= HH) continue;
    #pragma unroll
    for (int dw = -1; dw <= 1; dw++){
      int ww2 = w + dw; if (ww2 < 0 || ww2 >= WW) continue;
      u16x8 xv = *(const u16x8*)(xch + (sb + hh * WW + ww2) * DH + di);
      int t = (dh + 1) * 3 + (dw + 1);
      #pragma unroll
      for (int j = 0; j < 8; j++) acc[j] += bf2f(wv[t][j]) * bf2f(xv[j]);
    }
  }

  u16x8 ov;
  #pragma unroll
  for (int j = 0; j < 8; j++){
    float s = acc[j];
    s = s * fsigmoid(s);
    ov[j] = f2bf(s);
  }
  int lscan = (g == 0) ? p : (w * HH + h);
  *(u16x8*)(xcvh + (sb + lscan) * DH + di) = ov;
}

// ---------------- B/C projection: 4 outputs per position ----------------
__global__ __launch_bounds__(256) void k_bc(const u16* __restrict__ xcvh,
    const float* __restrict__ xpw, float* __restrict__ bc){
  int bg = blockIdx.y;
  int g = bg & 1;
  int p0 = blockIdx.x * 8;
  __shared__ float wl[4][192];
  __shared__ float xr[8][192];
  int tid = threadIdx.x;
  for (int i = tid; i < 4 * 192; i += 256){
    int j = i / 192, c = i - j * 192;
    int k = j >> 1, col = 12 + (j & 1);
    wl[j][c] = xpw[(long)g * 5376 + (k * 14 + col) * 192 + c];
  }
  for (int i = tid; i < 8 * 192; i += 256){
    xr[i / 192][i % 192] = bf2f(xcvh[((long)bg * LTOK + p0 + i / 192) * DH + (i % 192)]);
  }
  __syncthreads();
  int pos = tid >> 5, j = tid & 31;
  if (j < 4){
    float s = 0.f;
    for (int c = 0; c < 192; c++) s += xr[pos][c] * wl[j][c];
    int k = j >> 1;
    bc[(((long)(bg * 2 + k)) * LTOK + p0 + pos) * 2 + (j & 1)] = s;
  }
}

// ---------------- chunked parallel selective scan (precomputed a, dt*B*x) ----------------
__global__ __launch_bounds__(192) void k_scan_p1(const unsigned* __restrict__ pck,
    float* __restrict__ cP, float* __restrict__ cS){
  int bg = blockIdx.x, k = blockIdx.y, c = blockIdx.z;
  int z = bg * 2 + k;
  int di = threadIdx.x;
  const unsigned* pk = pck + (long)z * LTOK * 192 + di;
  float P = 1.f, S = 0.f;
  int l  = (k == 0) ? c * CHS : (LTOK - 1 - c * CHS);
  int dl = (k == 0) ? 1 : -1;
  for (int s = 0; s < CHS; s++, l += dl){
    unsigned v = pk[(long)l * 192];
    float a   = bf2f((u16)(v & 0xFFFFu));
    float dBx = bf2f((u16)(v >> 16));
    P *= a;
    S = a * S + dBx;
  }
  long idx = ((long)z * NCHK + c) * 192 + di;
  cP[idx] = P;
  cS[idx] = S;
}

__global__ __launch_bounds__(192) void k_scan_p2(const float* __restrict__ cP,
    const float* __restrict__ cS, float* __restrict__ h0){
  int z = blockIdx.x;              // 0..31
  int di = threadIdx.x;
  float h = 0.f;
  for (int c = 0; c < NCHK; c++){
    long idx = ((long)z * NCHK + c) * 192 + di;
    h0[idx] = h;
    h = cP[idx] * h + cS[idx];
  }
}

__global__ __launch_bounds__(192) void k_scan_p3(const unsigned* __restrict__ pck,
    const u16* __restrict__ xcvh, const float* __restrict__ bc,
    const float* __restrict__ ds, const float* __restrict__ h0,
    u16* __restrict__ ydir){
  int bg = blockIdx.x, c = blockIdx.y;
  int g = bg & 1;
  int di = threadIdx.x;
  const u16* xc = xcvh + (long)bg * LTOK * 192 + di;
  u16* yo = ydir + (long)bg * LTOK * 192 + di;
  #pragma unroll
  for (int k = 0; k < 2; k++){
    int z = bg * 2 + k, gk = g * 2 + k;
    float Dv = ds[gk * 192 + di];
    const unsigned* pk = pck + (long)z * LTOK * 192 + di;
    const float* bcp = bc + (long)z * LTOK * 2;
    int cc = (k == 0) ? c : (NCHK - 1 - c);
    float h = h0[((long)z * NCHK + cc) * 192 + di];
    int l  = (k == 0) ? c * CHS : (c * CHS + CHS - 1);
    int dl = (k == 0) ? 1 : -1;
    for (int s = 0; s < CHS; s++, l += dl){
      unsigned v = pk[(long)l * 192];
      float a   = bf2f((u16)(v & 0xFFFFu));
      float dBx = bf2f((u16)(v >> 16));
      float xv  = bf2f(xc[(long)l * 192]);
      h = a * h + dBx;
      float y = h * bcp[l * 2 + 1] + Dv * xv;
      if (k == 0) yo[(long)l * 192] = f2bf(y);
      else        yo[(long)l * 192] = f2bf(bf2f(yo[(long)l * 192]) + y);
    }
  }
}

// ---------------- combine directions + out-LN + *silu(z) -> bf16 ----------------
__global__ __launch_bounds__(192) void k_combine(const u16* __restrict__ ydir,
    const u16* __restrict__ zh, const float* __restrict__ ong, const float* __restrict__ onb,
    u16* __restrict__ yab){
  __shared__ float sm[3];
  int p = blockIdx.x; int bg = blockIdx.y; int g = bg & 1;
  int h = p >> 6, w = p & 63;
  int l = (g == 0) ? p : (w * HH + h);
  int di = threadIdx.x;
  float y = bf2f(ydir[((long)bg * LTOK + l) * DH + di]);
  float s = blockSum<3>(y, sm);
  float m = s * (1.f / DH);
  float d = y - m;
  float vs = blockSum<3>(d * d, sm);
  float inv = rsqrtf(vs * (1.f / DH) + 1e-5f);
  float yl = d * inv * ong[g * DH + di] + onb[g * DH + di];
  float z = bf2f(zh[((long)bg * LTOK + p) * DH + di]);
  yab[((long)bg * LTOK + p) * DH + di] = f2bf(yl * z * fsigmoid(z));
}

extern "C" void kernel_launch(void* const* d_in, const int* in_sizes, int n_in,
                              void* d_out, int out_size, void* d_ws, size_t ws_size,
                              hipStream_t stream){
  const float* x       = (const float*)d_in[0];
  const float* norm_g  = (const float*)d_in[1];
  const float* norm_b  = (const float*)d_in[2];
  const float* r_w1    = (const float*)d_in[3];
  const float* r_b1    = (const float*)d_in[4];
  const float* r_w2    = (const float*)d_in[5];
  const float* r_b2    = (const float*)d_in[6];
  const float* in_proj = (const float*)d_in[7];
  const float* conv_w  = (const float*)d_in[8];
  const float* conv_b  = (const float*)d_in[9];
  const float* xp_w    = (const float*)d_in[10];
  const float* dt_w    = (const float*)d_in[11];
  const float* dt_b    = (const float*)d_in[12];
  const float* A_log   = (const float*)d_in[13];
  const float* Ds      = (const float*)d_in[14];
  const float* on_g    = (const float*)d_in[15];
  const float* on_b    = (const float*)d_in[16];
  const float* op_w    = (const float*)d_in[17];
  const float* ci_w1   = (const float*)d_in[18];
  const float* ci_b1   = (const float*)d_in[19];
  const float* ci_w2   = (const float*)d_in[20];
  const float* ci_b2   = (const float*)d_in[21];
  const float* proj_w  = (const float*)d_in[22];
  const float* proj_b  = (const float*)d_in[23];
  const float* skip    = (const float*)d_in[24];
  float* out = (float*)d_out;
  float* ws  = (float*)d_ws;

  // Regions (floats):
  // R12 = ws[0 .. 2*BLC)      : xn fp32 (BLC) + xcbh bf16 region  -> later pck u32 (2*BLC)
  // R3  = [2*BLC .. 2.5*BLC)  : zh bf16 -> ycat bf16
  // R4  = [2.5B .. 3*BLC)     : xcvh bf16 -> yab bf16
  // R5  = [3*BLC .. 3.5*BLC)  : As bf16 -> ydir bf16
  float* xn   = ws;
  float* xcb  = ws + BLC;
  float* R3   = ws + 2 * BLC;
  float* R4   = R3 + BLC / 2;
  float* R5   = R4 + BLC / 2;
  float* pp   = R5 + BLC / 2;
  int*  sidx  = (int*)(pp + NB * 16 * CH);
  int*  inv   = sidx + NB * CH;
  u16*  wip   = (u16*)(inv + NB * CH);   // 2*384*192
  u16*  wop   = wip + 2 * 384 * 192;     // 2*192*192
  u16*  wpj   = wop + 2 * 192 * 192;     // 384*384
  u16*  w1g   = wpj + 384 * 384;         // NB*32*384
  u16*  w2p   = w1g + NB * 32 * CH;      // 384*32
  u16*  Mw    = w2p + CH * 32;           // 4*192*192
  u16*  cwb   = Mw + 4 * 192 * 192;      // 2*9*192
  float* b1p  = (float*)(cwb + 2 * 9 * DH);
  float* Atab = b1p + 32;                // 4*192
  u16*  hidp  = (u16*)(Atab + 4 * 192);  // NB*4096*32
  float* bc   = (float*)(hidp + (long)NB * LTOK * 32);  // 32*4096*2
  float* cP   = bc + 32 * LTOK * 2;
  float* cS   = cP + CST;
  float* h0   = cS + CST;

  size_t need = ((size_t)(2 * BLC) + 3 * (BLC / 2) + NB * 16 * CH + 32 * LTOK * 2 + 3 * CST + 64) * 4
              + (size_t)(2 * NB * CH) * 4 + (size_t)(4 * 192 + 32) * 4
              + ((size_t)2*384*192 + 2*192*192 + 384*384 + NB*32*CH + CH*32 + 4*192*192
                 + 2*9*DH + (size_t)NB * LTOK * 32) * 2
              + 8192;
  if (ws_size < need) return;

  // aliases
  u16*  As   = (u16*)R5;
  u16*  zh   = (u16*)R3;
  u16*  xcbh = (u16*)xcb;               // bf16 conv input (half of xcb region)
  u16*  xcvh = (u16*)R4;
  unsigned* pck = (unsigned*)ws;        // spans R12 (xn, xcbh both dead by then)
  u16*  ydir = (u16*)R5;
  u16*  yab  = (u16*)R4;
  u16*  ycat = (u16*)R3;
  u16*  gab  = (u16*)xcb;
  // gab aliases into pck's region but is written only after pck's last reader.

  k_ln<<<NB * LTOK, 128, 0, stream>>>(x, norm_g, norm_b, xn);
  k_cast<<<(2*384*192 + 255)/256, 256, 0, stream>>>(in_proj, wip, 2*384*192);
  k_cast<<<(2*192*192 + 255)/256, 256, 0, stream>>>(op_w,    wop, 2*192*192);
  k_cast<<<(384*384   + 255)/256, 256, 0, stream>>>(proj_w,  wpj, 384*384);
  k_prepA<<<3, 256, 0, stream>>>(A_log, Atab);
  k_prepcw<<<(2*9*DH + 255)/256, 256, 0, stream>>>(conv_w, cwb);
  k_prepM<<<dim3(144, 4), 256, 0, stream>>>(dt_w, xp_w, Mw);
  k_pool<<<dim3(3, 16, NB), 128, 0, stream>>>(xn, pp);
  k_score<<<NB, 384, 0, stream>>>(pp, r_w1, r_b1, r_w2, r_b2, sidx, inv);
  k_castgather<<<NB * LTOK, 384, 0, stream>>>(xn, sidx, As);
  k_prepw<<<NB + 1, 256, 0, stream>>>(ci_w1, ci_b1, ci_w2, sidx, w1g, w2p, b1p);

  // in_proj: per (b,g): [4096x192]@[384x192]^T -> xcbh bf16 + zh bf16
  k_mm<128, 1><<<dim3(3, 32, 16), 256, 0, stream>>>(
      As, CH, (long)LTOK * CH, 192,
      wip, (long)384 * 192,
      (float*)xcbh, zh, (long)2 * LTOK * DH, (long)LTOK * DH, 0,
      192, 2, nullptr, nullptr, nullptr, nullptr, nullptr);

  // gate stage 1 (uses As; before R5 is recycled by scan p3)
  k_hid<<<dim3(32, NB), 256, 0, stream>>>(As, w1g, b1p, hidp);

  k_conv<<<dim3(LTOK / 8, NB * 2), 192, 0, stream>>>(xcbh, cwb, conv_b, xcvh);
  k_bc<<<dim3(LTOK / 8, NB * 2), 256, 0, stream>>>(xcvh, xp_w, bc);

  // fused dt GEMM -> packed (dt*B*x, a) bf16x2 (overwrites xn+xcbh regions)
  k_dt<<<dim3(3, 32, 32), 256, 0, stream>>>(xcvh, Mw, dt_b, Atab, bc, pck);

  k_scan_p1<<<dim3(NB * 2, 2, NCHK), 192, 0, stream>>>(pck, cP, cS);
  k_scan_p2<<<32, 192, 0, stream>>>(cP, cS, h0);
  k_scan_p3<<<dim3(NB * 2, NCHK), 192, 0, stream>>>(pck, xcvh, bc, Ds, h0, ydir);

  k_combine<<<dim3(LTOK, NB * 2), 192, 0, stream>>>(ydir, zh, on_g, on_b, yab);

  // out_proj: per (b,g): [4096x192]@[192x192]^T -> ycat bf16 (col offset g*192)
  k_mm<64, 2><<<dim3(3, 32, 16), 256, 0, stream>>>(
      yab, DH, (long)2 * LTOK * DH, (long)LTOK * DH,
      wop, (long)192 * 192,
      nullptr, ycat, (long)LTOK * CH, 192, CH,
      192, 2, nullptr, nullptr, nullptr, nullptr, nullptr);

  // gate stage 2 + un-sort gather + multiply
  k_mm<128, 4><<<dim3(3, 256, 1), 256, 0, stream>>>(
      hidp, 32, 0, 0,
      w2p, 0,
      nullptr, gab, 0, 0, CH,
      32, 1, ci_b2, nullptr, nullptr, ycat, inv);

  // final: out = x + skip * (gab @ proj_w^T + proj_b)
  k_mm<128, 3><<<dim3(3, 256, 1), 256, 0, stream>>>(
      gab, CH, 0, 0,
      wpj, 0,
      out, nullptr, 0, 0, CH,
      CH, 1, proj_b, x, skip, nullptr, nullptr);
}

// Round 9
// 395.198 us; speedup vs baseline: 21.2714x; 1.1998x over previous
//
#include <hip/hip_runtime.h>
#include <math.h>

// Problem constants (fixed by the reference module)
#define NB 8
#define LTOK 4096
#define CH 384
#define DH 192
#define HH 64
#define WW 64
#define NCHK 128     // chunks per sequence
#define CHS 32       // steps per chunk (LTOK / NCHK)

static constexpr long BLC  = (long)NB * LTOK * CH;   // 12,582,912 elements
static constexpr long CST  = (long)32 * NCHK * DH;   // 786,432 per chunk-state buffer

typedef unsigned short u16;
typedef u16   u16x8 __attribute__((ext_vector_type(8)));
typedef short s16x8 __attribute__((ext_vector_type(8)));
typedef float f32x4 __attribute__((ext_vector_type(4)));

__device__ inline u16 f2bf(float f){
  unsigned int u = __float_as_uint(f);
  return (u16)((u + 0x7FFFu + ((u >> 16) & 1u)) >> 16);
}
__device__ inline float bf2f(u16 h){ return __uint_as_float(((unsigned int)h) << 16); }
__device__ inline float fsigmoid(float x){ return 1.f / (1.f + __expf(-x)); }

// LDS scan-buffer column swizzle: spreads kg-lanes across banks (2-way max)
#define SCOL(ml, c) ((c) ^ ((((ml) >> 2) & 3) << 4))

template<int NW>
__device__ inline float blockSum(float v, float* sm){
  #pragma unroll
  for (int o = 32; o > 0; o >>= 1) v += __shfl_down(v, o);
  int lane = threadIdx.x & 63, wv = threadIdx.x >> 6;
  if (lane == 0) sm[wv] = v;
  __syncthreads();
  if (threadIdx.x == 0){ float t = 0.f; for (int i = 0; i < NW; i++) t += sm[i]; sm[0] = t; }
  __syncthreads();
  float t = sm[0];
  __syncthreads();
  return t;
}

// ---------------- LayerNorm over C=384 per token ----------------
__global__ __launch_bounds__(128) void k_ln(const float* __restrict__ x,
    const float* __restrict__ g, const float* __restrict__ b, float* __restrict__ xn){
  __shared__ float sm[2];
  long row = blockIdx.x;
  int t = threadIdx.x;
  const float* xr = x + row * CH;
  float v0 = xr[t], v1 = xr[t + 128], v2 = xr[t + 256];
  float s = blockSum<2>(v0 + v1 + v2, sm);
  float m = s * (1.f / CH);
  float d0 = v0 - m, d1 = v1 - m, d2 = v2 - m;
  float vs = blockSum<2>(d0*d0 + d1*d1 + d2*d2, sm);
  float inv = rsqrtf(vs * (1.f / CH) + 1e-5f);
  float* o = xn + row * CH;
  o[t]       = d0 * inv * g[t]       + b[t];
  o[t + 128] = d1 * inv * g[t + 128] + b[t + 128];
  o[t + 256] = d2 * inv * g[t + 256] + b[t + 256];
}

// ---------------- partial pooling ----------------
__global__ __launch_bounds__(128) void k_pool(const float* __restrict__ xn, float* __restrict__ pp){
  int c = blockIdx.x * 128 + threadIdx.x;
  int chunk = blockIdx.y, b = blockIdx.z;
  long base = ((long)b * LTOK + chunk * 256) * CH;
  float s = 0.f;
  for (int n = 0; n < 256; n++) s += xn[base + (long)n * CH + c];
  pp[((long)b * 16 + chunk) * CH + c] = s;
}

// ---------------- score MLP + stable argsort (descending) ----------------
__global__ __launch_bounds__(384) void k_score(const float* __restrict__ pp,
    const float* __restrict__ w1, const float* __restrict__ b1,
    const float* __restrict__ w2, const float* __restrict__ b2,
    int* __restrict__ sidx, int* __restrict__ inv){
  __shared__ float poolv[CH];
  __shared__ float hid[192];
  __shared__ float sc[CH];
  int b = blockIdx.x, t = threadIdx.x;
  float s = 0.f;
  for (int ch = 0; ch < 16; ch++) s += pp[((long)b * 16 + ch) * CH + t];
  poolv[t] = s * (1.f / LTOK);
  __syncthreads();
  if (t < 192){
    float h = b1[t];
    for (int c = 0; c < CH; c++) h += poolv[c] * w1[t * CH + c];
    hid[t] = fmaxf(h, 0.f);
  }
  __syncthreads();
  {
    float h = b2[t];
    for (int j = 0; j < 192; j++) h += hid[j] * w2[t * 192 + j];
    sc[t] = 1.f / (1.f + expf(-h));
  }
  __syncthreads();
  float mys = sc[t];
  int rank = 0;
  for (int j = 0; j < CH; j++){
    float o = sc[j];
    rank += (o > mys) || (o == mys && j < t);
  }
  sidx[b * CH + rank] = t;
  inv[b * CH + t] = rank;
}

// ---------------- cast fp32 -> bf16 (weights) ----------------
__global__ __launch_bounds__(256) void k_cast(const float* __restrict__ s,
    u16* __restrict__ d, int n){
  int i = blockIdx.x * 256 + threadIdx.x;
  if (i < n) d[i] = f2bf(s[i]);
}

// ---------------- precompute A table: Atab = -exp(A_log) ----------------
__global__ __launch_bounds__(256) void k_prepA(const float* __restrict__ alog,
    float* __restrict__ Atab){
  int i = blockIdx.x * 256 + threadIdx.x;
  if (i < 4 * 192) Atab[i] = -expf(alog[i]);
}

// ---------------- prep conv weights: tap-major bf16 [g][9][DH] ----------------
__global__ __launch_bounds__(256) void k_prepcw(const float* __restrict__ cw,
    u16* __restrict__ cwb){
  int i = blockIdx.x * 256 + threadIdx.x;
  if (i < 2 * 9 * DH){
    int g = i / (9 * DH); int r = i - g * 9 * DH;
    int tap = r / DH; int di = r - tap * DH;
    cwb[i] = f2bf(cw[((long)g * DH + di) * 9 + tap]);
  }
}

// ---------------- gather sorted channels + cast to bf16 ----------------
__global__ __launch_bounds__(384) void k_castgather(const float* __restrict__ xn,
    const int* __restrict__ sidx, u16* __restrict__ As){
  long row = blockIdx.x;
  int b = (int)(row >> 12);
  int t = threadIdx.x;
  int c = sidx[b * CH + t];
  As[row * CH + t] = f2bf(xn[row * CH + c]);
}

// ---------------- prep gate-MLP weights: gathered w1 (per batch), padded w2, b1 ----------------
__global__ __launch_bounds__(256) void k_prepw(const float* __restrict__ w1,
    const float* __restrict__ b1, const float* __restrict__ w2,
    const int* __restrict__ sidx, u16* __restrict__ w1g, u16* __restrict__ w2p,
    float* __restrict__ b1p){
  int b = blockIdx.x, tid = threadIdx.x;
  if (b < NB){
    const int* sx = sidx + b * CH;
    for (int i = tid; i < 32 * CH; i += 256){
      int j = i / CH, r = i - j * CH;
      float v = (j < 24) ? w1[j * CH + sx[r]] : 0.f;
      w1g[(long)b * 32 * CH + i] = f2bf(v);
    }
  } else {
    for (int i = tid; i < CH * 32; i += 256){
      int n = i >> 5, j = i & 31;
      w2p[i] = f2bf((j < 24) ? w2[n * 24 + j] : 0.f);
    }
    if (tid < 32) b1p[tid] = (tid < 24) ? b1[tid] : 0.f;
  }
}

// ---------------- prep fused dt matrices ----------------
__global__ __launch_bounds__(256) void k_prepM(const float* __restrict__ dtw,
    const float* __restrict__ xpw, u16* __restrict__ Mw){
  int gk = blockIdx.y;
  int g = gk >> 1, k = gk & 1;
  int idx = blockIdx.x * 256 + threadIdx.x;   // < 36864
  int di = idx / 192, c = idx - di * 192;
  float s = 0.f;
  #pragma unroll
  for (int r = 0; r < 12; r++)
    s += dtw[((long)gk * 192 + di) * 12 + r] * xpw[(long)g * 5376 + (k * 14 + r) * 192 + c];
  Mw[(long)gk * 36864 + idx] = f2bf(s);
}

// ---------------- gate stage 1: hid = relu(As @ w1g^T + b1p), bf16 out ----------------
__global__ __launch_bounds__(256) void k_hid(const u16* __restrict__ As,
    const u16* __restrict__ w1g, const float* __restrict__ b1p,
    u16* __restrict__ hidp){
  __shared__ u16 sA[128 * 32];
  __shared__ u16 sB[32 * 32];
  int b = blockIdx.y;
  const u16* Ab = As + (long)b * LTOK * CH;
  const u16* Bb = w1g + (long)b * 32 * CH;
  int tid = threadIdx.x;
  int m0 = blockIdx.x * 128;
  int wv = tid >> 6, l = tid & 63;
  int wm = wv * 32;
  int kg = l >> 4, lr = l & 15;

  f32x4 acc[2][2];
  #pragma unroll
  for (int i = 0; i < 2; i++)
    #pragma unroll
    for (int j = 0; j < 2; j++)
      #pragma unroll
      for (int r = 0; r < 4; r++) acc[i][j][r] = 0.f;

  int aoffU[2], boffU[2];
  #pragma unroll
  for (int i = 0; i < 2; i++){
    int r = wm + i * 16 + lr;
    aoffU[i] = r * 32 + ((kg * 8) ^ ((r & 3) << 3));
  }
  #pragma unroll
  for (int j = 0; j < 2; j++){
    int r = j * 16 + lr;
    boffU[j] = r * 32 + ((kg * 8) ^ ((r & 3) << 3));
  }

  u16x8 ra[2], rbv;
  #pragma unroll
  for (int q = 0; q < 2; q++){
    int i = q * 256 + tid; int row = i >> 2, sl = i & 3, ss = sl ^ (row & 3);
    ra[q] = *(const u16x8*)(Ab + (long)(m0 + row) * CH + ss * 8);
  }
  if (tid < 128){
    int row = tid >> 2, sl = tid & 3, ss = sl ^ (row & 3);
    rbv = *(const u16x8*)(Bb + (long)row * CH + ss * 8);
  }

  const int nks = CH / 32;   // 12
  for (int ks = 0; ks < nks; ks++){
    __syncthreads();
    #pragma unroll
    for (int q = 0; q < 2; q++){
      int i = q * 256 + tid; int row = i >> 2, sl = i & 3;
      *(u16x8*)(sA + row * 32 + sl * 8) = ra[q];
    }
    if (tid < 128){
      int row = tid >> 2, sl = tid & 3;
      *(u16x8*)(sB + row * 32 + sl * 8) = rbv;
    }
    __syncthreads();
    if (ks + 1 < nks){
      int k0 = (ks + 1) * 32;
      #pragma unroll
      for (int q = 0; q < 2; q++){
        int i = q * 256 + tid; int row = i >> 2, sl = i & 3, ss = sl ^ (row & 3);
        ra[q] = *(const u16x8*)(Ab + (long)(m0 + row) * CH + k0 + ss * 8);
      }
      if (tid < 128){
        int row = tid >> 2, sl = tid & 3, ss = sl ^ (row & 3);
        rbv = *(const u16x8*)(Bb + (long)row * CH + k0 + ss * 8);
      }
    }
    s16x8 af[2], bfr[2];
    #pragma unroll
    for (int i = 0; i < 2; i++) af[i] = *(const s16x8*)(sA + aoffU[i]);
    #pragma unroll
    for (int j = 0; j < 2; j++) bfr[j] = *(const s16x8*)(sB + boffU[j]);
    #pragma unroll
    for (int i = 0; i < 2; i++)
      #pragma unroll
      for (int j = 0; j < 2; j++)
        acc[i][j] = __builtin_amdgcn_mfma_f32_16x16x32_bf16(af[i], bfr[j], acc[i][j], 0, 0, 0);
  }

  #pragma unroll
  for (int i = 0; i < 2; i++)
    #pragma unroll
    for (int j = 0; j < 2; j++)
      #pragma unroll
      for (int r = 0; r < 4; r++){
        int m = m0 + wm + i * 16 + kg * 4 + r;
        int n = j * 16 + lr;
        float v = fmaxf(acc[i][j][r] + b1p[n], 0.f);
        hidp[((long)b * LTOK + m) * 32 + n] = f2bf(v);
      }
}

// ---------------- bf16 MFMA GEMM: C = A @ B^T ----------------
// MODE 1: split epilogue: n<192 -> ((u16*)Cf) bf16 [m*192+n]; n>=192 -> Ch bf16 [m*192+n-192]
// MODE 2: Ch bf16 [m*ldc+n]
// MODE 3: Cf fp32 = resid + skip*(v + bias[n])
// MODE 4: gate = sigmoid(v+bias[n]); Ch[m*ldc+n] = bf16(gate * bf2f(gy[m*ldc+ginv[(m>>12)*CH+n]]))
template<int BN, int MODE>
__global__ __launch_bounds__(256) void k_mm(
    const u16* __restrict__ A, int lda, long aOuter, long aInner,
    const u16* __restrict__ B, long bInner,
    float* __restrict__ Cf, u16* __restrict__ Ch,
    long cOuter, long cInner, int ldc,
    int K, int innerCnt,
    const float* __restrict__ bias, const float* __restrict__ resid,
    const float* __restrict__ skip,
    const u16* __restrict__ gy, const int* __restrict__ ginv){
  constexpr int BM = 128;
  constexpr int AI = 2;
  constexpr int BI = (BN * 32) / (256 * 8);
  constexpr int NJ = BN / 32;
  __shared__ u16 sA[BM * 32];
  __shared__ u16 sB[BN * 32];

  int bz = blockIdx.z;
  int bo = bz / innerCnt, bi_ = bz - bo * innerCnt;
  const u16* Ab = A + (long)bo * aOuter + (long)bi_ * aInner;
  const u16* Bb = B + (long)bi_ * bInner;
  int tid = threadIdx.x;
  int m0 = blockIdx.y * BM, n0 = blockIdx.x * BN;
  int wv = tid >> 6, l = tid & 63;
  int wm = (wv >> 1) * 64, wn = (wv & 1) * (BN / 2);
  int kg = l >> 4, lr = l & 15;

  f32x4 acc[4][NJ];
  #pragma unroll
  for (int i = 0; i < 4; i++)
    #pragma unroll
    for (int j = 0; j < NJ; j++)
      #pragma unroll
      for (int r = 0; r < 4; r++) acc[i][j][r] = 0.f;

  int aoffU[4], boffU[NJ];
  #pragma unroll
  for (int i = 0; i < 4; i++){
    int r = wm + i * 16 + lr;
    aoffU[i] = r * 32 + ((kg * 8) ^ ((r & 3) << 3));
  }
  #pragma unroll
  for (int j = 0; j < NJ; j++){
    int r = wn + j * 16 + lr;
    boffU[j] = r * 32 + ((kg * 8) ^ ((r & 3) << 3));
  }

  u16x8 ra[AI], rb[BI];
  #pragma unroll
  for (int q = 0; q < AI; q++){
    int i = q * 256 + tid; int row = i >> 2, sl = i & 3, ss = sl ^ (row & 3);
    ra[q] = *(const u16x8*)(Ab + (long)(m0 + row) * lda + ss * 8);
  }
  #pragma unroll
  for (int q = 0; q < BI; q++){
    int i = q * 256 + tid; int row = i >> 2, sl = i & 3, ss = sl ^ (row & 3);
    rb[q] = *(const u16x8*)(Bb + (long)(n0 + row) * K + ss * 8);
  }

  int nks = K >> 5;
  for (int ks = 0; ks < nks; ks++){
    __syncthreads();
    #pragma unroll
    for (int q = 0; q < AI; q++){
      int i = q * 256 + tid; int row = i >> 2, sl = i & 3;
      *(u16x8*)(sA + row * 32 + sl * 8) = ra[q];
    }
    #pragma unroll
    for (int q = 0; q < BI; q++){
      int i = q * 256 + tid; int row = i >> 2, sl = i & 3;
      *(u16x8*)(sB + row * 32 + sl * 8) = rb[q];
    }
    __syncthreads();
    if (ks + 1 < nks){
      int k0 = (ks + 1) * 32;
      #pragma unroll
      for (int q = 0; q < AI; q++){
        int i = q * 256 + tid; int row = i >> 2, sl = i & 3, ss = sl ^ (row & 3);
        ra[q] = *(const u16x8*)(Ab + (long)(m0 + row) * lda + k0 + ss * 8);
      }
      #pragma unroll
      for (int q = 0; q < BI; q++){
        int i = q * 256 + tid; int row = i >> 2, sl = i & 3, ss = sl ^ (row & 3);
        rb[q] = *(const u16x8*)(Bb + (long)(n0 + row) * K + k0 + ss * 8);
      }
    }
    s16x8 af[4];
    #pragma unroll
    for (int i = 0; i < 4; i++) af[i] = *(const s16x8*)(sA + aoffU[i]);
    s16x8 bfr[NJ];
    #pragma unroll
    for (int j = 0; j < NJ; j++) bfr[j] = *(const s16x8*)(sB + boffU[j]);
    #pragma unroll
    for (int i = 0; i < 4; i++)
      #pragma unroll
      for (int j = 0; j < NJ; j++)
        acc[i][j] = __builtin_amdgcn_mfma_f32_16x16x32_bf16(af[i], bfr[j], acc[i][j], 0, 0, 0);
  }

  long zc = (long)bo * cOuter + (long)bi_ * cInner;
  #pragma unroll
  for (int i = 0; i < 4; i++){
    #pragma unroll
    for (int j = 0; j < NJ; j++){
      #pragma unroll
      for (int r = 0; r < 4; r++){
        int m = m0 + wm + i * 16 + kg * 4 + r;
        int n = n0 + wn + j * 16 + lr;
        float v = acc[i][j][r];
        if constexpr (MODE == 1){
          if (n < 192) ((u16*)Cf)[zc + (long)m * 192 + n] = f2bf(v);
          else         Ch[zc + (long)m * 192 + (n - 192)] = f2bf(v);
        } else if constexpr (MODE == 2){
          Ch[zc + (long)m * ldc + n] = f2bf(v);
        } else if constexpr (MODE == 3){
          float vb = v + bias[n];
          long o = (long)m * ldc + n;
          Cf[o] = resid[o] + skip[0] * vb;
        } else {
          float gate = fsigmoid(v + bias[n]);
          int bt = m >> 12;
          float yr = bf2f(gy[(long)m * ldc + ginv[bt * CH + n]]);
          Ch[(long)m * ldc + n] = f2bf(yr * gate);
        }
      }
    }
  }
}

// ---------------- fused dt GEMM + chunk-scan (p1) ----------------
// dtraw = xcvh @ M^T; epilogue: dt=softplus(raw+b), a=exp(A*dt), dBx=dt*B*x;
// writes pk16 = bf16(dt); in-block LDS scan of 4 chunks x 64 channels -> cP/cS.
__global__ __launch_bounds__(256) void k_dt(
    const u16* __restrict__ xcvh, const u16* __restrict__ Mw,
    const float* __restrict__ dtb, const float* __restrict__ Atab,
    const float* __restrict__ bc, u16* __restrict__ pk16,
    float* __restrict__ cP, float* __restrict__ cS){
  constexpr int BM = 128, AI = 2, NJ = 2;
  __shared__ unsigned sMem[BM * 64];     // 32 KB: GEMM staging (12 KB) then scan buffer
  u16* sA = (u16*)sMem;                  // 128*32 u16 = 8 KB
  u16* sB = (u16*)(sMem + 2048);         // 64*32 u16 = 4 KB

  int z = blockIdx.z;                 // bg*2 + k
  int bg = z >> 1, kk_ = z & 1, g = bg & 1, gk = g * 2 + kk_;
  const u16* Ab = xcvh + (long)bg * LTOK * 192;
  const u16* Bb = Mw + (long)gk * 36864;
  int tid = threadIdx.x;
  int m0 = blockIdx.y * BM, n0 = blockIdx.x * 64;
  int wv = tid >> 6, l = tid & 63;
  int wm = (wv >> 1) * 64, wn = (wv & 1) * 32;
  int kg = l >> 4, lr = l & 15;

  f32x4 acc[4][NJ];
  #pragma unroll
  for (int i = 0; i < 4; i++)
    #pragma unroll
    for (int j = 0; j < NJ; j++)
      #pragma unroll
      for (int r = 0; r < 4; r++) acc[i][j][r] = 0.f;

  int aoffU[4], boffU[NJ];
  #pragma unroll
  for (int i = 0; i < 4; i++){
    int r = wm + i * 16 + lr;
    aoffU[i] = r * 32 + ((kg * 8) ^ ((r & 3) << 3));
  }
  #pragma unroll
  for (int j = 0; j < NJ; j++){
    int r = wn + j * 16 + lr;
    boffU[j] = r * 32 + ((kg * 8) ^ ((r & 3) << 3));
  }

  u16x8 ra[AI], rb0;
  #pragma unroll
  for (int q = 0; q < AI; q++){
    int i = q * 256 + tid; int row = i >> 2, sl = i & 3, ss = sl ^ (row & 3);
    ra[q] = *(const u16x8*)(Ab + (long)(m0 + row) * 192 + ss * 8);
  }
  {
    int row = tid >> 2, sl = tid & 3, ss = sl ^ (row & 3);
    rb0 = *(const u16x8*)(Bb + (long)(n0 + row) * 192 + ss * 8);
  }

  const int nks = 6;   // K = 192
  for (int ks = 0; ks < nks; ks++){
    __syncthreads();
    #pragma unroll
    for (int q = 0; q < AI; q++){
      int i = q * 256 + tid; int row = i >> 2, sl = i & 3;
      *(u16x8*)(sA + row * 32 + sl * 8) = ra[q];
    }
    {
      int row = tid >> 2, sl = tid & 3;
      *(u16x8*)(sB + row * 32 + sl * 8) = rb0;
    }
    __syncthreads();
    if (ks + 1 < nks){
      int k0 = (ks + 1) * 32;
      #pragma unroll
      for (int q = 0; q < AI; q++){
        int i = q * 256 + tid; int row = i >> 2, sl = i & 3, ss = sl ^ (row & 3);
        ra[q] = *(const u16x8*)(Ab + (long)(m0 + row) * 192 + k0 + ss * 8);
      }
      {
        int row = tid >> 2, sl = tid & 3, ss = sl ^ (row & 3);
        rb0 = *(const u16x8*)(Bb + (long)(n0 + row) * 192 + k0 + ss * 8);
      }
    }
    s16x8 af[4], bfr[NJ];
    #pragma unroll
    for (int i = 0; i < 4; i++) af[i] = *(const s16x8*)(sA + aoffU[i]);
    #pragma unroll
    for (int j = 0; j < NJ; j++) bfr[j] = *(const s16x8*)(sB + boffU[j]);
    #pragma unroll
    for (int i = 0; i < 4; i++)
      #pragma unroll
      for (int j = 0; j < NJ; j++)
        acc[i][j] = __builtin_amdgcn_mfma_f32_16x16x32_bf16(af[i], bfr[j], acc[i][j], 0, 0, 0);
  }

  // epilogue: compute dt/a/dBx, write pk16, keep packed (dBx,a) in registers
  unsigned pkreg[4][NJ][4];
  #pragma unroll
  for (int i = 0; i < 4; i++){
    #pragma unroll
    for (int j = 0; j < NJ; j++){
      #pragma unroll
      for (int r = 0; r < 4; r++){
        int m = m0 + wm + i * 16 + kg * 4 + r;
        int n = n0 + wn + j * 16 + lr;
        float rr = acc[i][j][r] + dtb[gk * 192 + n];
        float dtv = __logf(1.f + __expf(rr));
        float av  = __expf(Atab[gk * 192 + n] * dtv);
        float Bv  = bc[((long)z * LTOK + m) * 2];
        float xv  = bf2f(xcvh[((long)bg * LTOK + m) * 192 + n]);
        pk16[((long)z * LTOK + m) * 192 + n] = f2bf(dtv);
        pkreg[i][j][r] = ((unsigned)f2bf(dtv * Bv * xv) << 16) | (unsigned)f2bf(av);
      }
    }
  }

  __syncthreads();   // all waves done reading sA/sB
  #pragma unroll
  for (int i = 0; i < 4; i++){
    #pragma unroll
    for (int j = 0; j < NJ; j++){
      #pragma unroll
      for (int r = 0; r < 4; r++){
        int ml = wm + i * 16 + kg * 4 + r;
        int cl = wn + j * 16 + lr;
        sMem[ml * 64 + SCOL(ml, cl)] = pkreg[i][j][r];
      }
    }
  }
  __syncthreads();

  // chunk scan: thread = (chunk-in-tile, channel)
  int cc = tid >> 6, nn = tid & 63;
  float P = 1.f, S = 0.f;
  if (kk_ == 0){
    for (int s = 0; s < CHS; s++){
      int row = cc * CHS + s;
      unsigned v = sMem[row * 64 + SCOL(row, nn)];
      float a = bf2f((u16)(v & 0xFFFFu));
      float dBx = bf2f((u16)(v >> 16));
      P *= a; S = a * S + dBx;
    }
  } else {
    for (int s = CHS - 1; s >= 0; s--){
      int row = cc * CHS + s;
      unsigned v = sMem[row * 64 + SCOL(row, nn)];
      float a = bf2f((u16)(v & 0xFFFFu));
      float dBx = bf2f((u16)(v >> 16));
      P *= a; S = a * S + dBx;
    }
  }
  int cglob = (kk_ == 0) ? (blockIdx.y * 4 + cc)
                         : ((LTOK - m0) / CHS - cc - 1);
  long idx = ((long)z * NCHK + cglob) * 192 + n0 + nn;
  cP[idx] = P;
  cS[idx] = S;
}

// ---------------- depthwise 3x3 conv (u16x8/thread) + fused B/C projection ----------------
__global__ __launch_bounds__(192) void k_conv(const u16* __restrict__ xch,
    const u16* __restrict__ cwb, const float* __restrict__ cb,
    const float* __restrict__ xpw, u16* __restrict__ xcvh,
    float* __restrict__ bc){
  __shared__ float red[8][4][25];
  int tid = threadIdx.x;
  int chg = tid % 24, pp = tid / 24;    // 24 channel-groups x 8 positions
  int p = blockIdx.x * 8 + pp;
  int bg = blockIdx.y; int g = bg & 1;
  int h = p >> 6, w = p & 63;
  int di = chg * 8;
  long sb = (long)bg * LTOK;

  u16x8 wv[9];
  #pragma unroll
  for (int t = 0; t < 9; t++)
    wv[t] = *(const u16x8*)(cwb + ((long)g * 9 + t) * DH + di);

  float acc[8];
  #pragma unroll
  for (int j = 0; j < 8; j++) acc[j] = cb[g * DH + di + j];

  #pragma unroll
  for (int dh = -1; dh <= 1; dh++){
    int hh = h + dh; if (hh < 0 || hh >= HH) continue;
    #pragma unroll
    for (int dw = -1; dw <= 1; dw++){
      int ww2 = w + dw; if (ww2 < 0 || ww2 >= WW) continue;
      u16x8 xv = *(const u16x8*)(xch + (sb + hh * WW + ww2) * DH + di);
      int t = (dh + 1) * 3 + (dw + 1);
      #pragma unroll
      for (int j = 0; j < 8; j++) acc[j] += bf2f(wv[t][j]) * bf2f(xv[j]);
    }
  }

  u16x8 ov;
  #pragma unroll
  for (int j = 0; j < 8; j++){
    float s = acc[j];
    acc[j] = s * fsigmoid(s);         // post-silu fp32, reused for B/C dot
    ov[j] = f2bf(acc[j]);
  }
  int lscan = (g == 0) ? p : (w * HH + h);
  *(u16x8*)(xcvh + (sb + lscan) * DH + di) = ov;

  // B/C projection partials: 4 dots over this thread's 8 channels
  #pragma unroll
  for (int j = 0; j < 4; j++){
    int k = j >> 1, ci = j & 1;
    const float* wl = xpw + (long)g * 5376 + (k * 14 + 12 + ci) * 192 + di;
    float sacc = 0.f;
    #pragma unroll
    for (int q = 0; q < 8; q++) sacc += acc[q] * wl[q];
    red[pp][j][chg] = sacc;
  }
  __syncthreads();
  if (tid < 32){
    int pos = tid >> 2, j = tid & 3;
    float ssum = 0.f;
    #pragma unroll
    for (int q = 0; q < 24; q++) ssum += red[pos][j][q];
    int p2 = blockIdx.x * 8 + pos;
    int h2 = p2 >> 6, w2 = p2 & 63;
    int ls = (g == 0) ? p2 : (w2 * HH + h2);
    int k = j >> 1;
    bc[(((long)(bg * 2 + k)) * LTOK + ls) * 2 + (j & 1)] = ssum;
  }
}

// ---------------- scan p2: sequential composition over 128 chunks ----------------
__global__ __launch_bounds__(192) void k_scan_p2(const float* __restrict__ cP,
    const float* __restrict__ cS, float* __restrict__ h0){
  int z = blockIdx.x;              // 0..31
  int di = threadIdx.x;
  float h = 0.f;
  for (int c = 0; c < NCHK; c++){
    long idx = ((long)z * NCHK + c) * 192 + di;
    h0[idx] = h;
    h = cP[idx] * h + cS[idx];
  }
}

// ---------------- scan p3: recompute per-step from dt; write fwd, add bwd ----------------
__global__ __launch_bounds__(192) void k_scan_p3(const u16* __restrict__ pk16,
    const u16* __restrict__ xcvh, const float* __restrict__ bc,
    const float* __restrict__ Atab, const float* __restrict__ ds,
    const float* __restrict__ h0, u16* __restrict__ ydir){
  int bg = blockIdx.x, c = blockIdx.y;
  int g = bg & 1;
  int di = threadIdx.x;
  const u16* xc = xcvh + (long)bg * LTOK * 192 + di;
  u16* yo = ydir + (long)bg * LTOK * 192 + di;
  #pragma unroll
  for (int k = 0; k < 2; k++){
    int z = bg * 2 + k, gk = g * 2 + k;
    float Dv = ds[gk * 192 + di];
    float Av = Atab[gk * 192 + di];
    const u16* pk = pk16 + (long)z * LTOK * 192 + di;
    const float* bcp = bc + (long)z * LTOK * 2;
    int cc = (k == 0) ? c : (NCHK - 1 - c);
    float h = h0[((long)z * NCHK + cc) * 192 + di];
    int l  = (k == 0) ? c * CHS : (c * CHS + CHS - 1);
    int dl = (k == 0) ? 1 : -1;
    for (int s = 0; s < CHS; s++, l += dl){
      float dtv = bf2f(pk[(long)l * 192]);
      float av  = __expf(Av * dtv);
      float xv  = bf2f(xc[(long)l * 192]);
      float Bv  = bcp[l * 2], Cv = bcp[l * 2 + 1];
      h = av * h + dtv * Bv * xv;
      float y = h * Cv + Dv * xv;
      if (k == 0) yo[(long)l * 192] = f2bf(y);
      else        yo[(long)l * 192] = f2bf(bf2f(yo[(long)l * 192]) + y);
    }
  }
}

// ---------------- combine directions + out-LN + *silu(z) -> bf16 ----------------
__global__ __launch_bounds__(192) void k_combine(const u16* __restrict__ ydir,
    const u16* __restrict__ zh, const float* __restrict__ ong, const float* __restrict__ onb,
    u16* __restrict__ yab){
  __shared__ float sm[3];
  int p = blockIdx.x; int bg = blockIdx.y; int g = bg & 1;
  int h = p >> 6, w = p & 63;
  int l = (g == 0) ? p : (w * HH + h);
  int di = threadIdx.x;
  float y = bf2f(ydir[((long)bg * LTOK + l) * DH + di]);
  float s = blockSum<3>(y, sm);
  float m = s * (1.f / DH);
  float d = y - m;
  float vs = blockSum<3>(d * d, sm);
  float inv = rsqrtf(vs * (1.f / DH) + 1e-5f);
  float yl = d * inv * ong[g * DH + di] + onb[g * DH + di];
  float z = bf2f(zh[((long)bg * LTOK + p) * DH + di]);
  yab[((long)bg * LTOK + p) * DH + di] = f2bf(yl * z * fsigmoid(z));
}

extern "C" void kernel_launch(void* const* d_in, const int* in_sizes, int n_in,
                              void* d_out, int out_size, void* d_ws, size_t ws_size,
                              hipStream_t stream){
  const float* x       = (const float*)d_in[0];
  const float* norm_g  = (const float*)d_in[1];
  const float* norm_b  = (const float*)d_in[2];
  const float* r_w1    = (const float*)d_in[3];
  const float* r_b1    = (const float*)d_in[4];
  const float* r_w2    = (const float*)d_in[5];
  const float* r_b2    = (const float*)d_in[6];
  const float* in_proj = (const float*)d_in[7];
  const float* conv_w  = (const float*)d_in[8];
  const float* conv_b  = (const float*)d_in[9];
  const float* xp_w    = (const float*)d_in[10];
  const float* dt_w    = (const float*)d_in[11];
  const float* dt_b    = (const float*)d_in[12];
  const float* A_log   = (const float*)d_in[13];
  const float* Ds      = (const float*)d_in[14];
  const float* on_g    = (const float*)d_in[15];
  const float* on_b    = (const float*)d_in[16];
  const float* op_w    = (const float*)d_in[17];
  const float* ci_w1   = (const float*)d_in[18];
  const float* ci_b1   = (const float*)d_in[19];
  const float* ci_w2   = (const float*)d_in[20];
  const float* ci_b2   = (const float*)d_in[21];
  const float* proj_w  = (const float*)d_in[22];
  const float* proj_b  = (const float*)d_in[23];
  const float* skip    = (const float*)d_in[24];
  float* out = (float*)d_out;
  float* ws  = (float*)d_ws;

  // Regions (floats):
  // R1 = ws[0 .. BLC)         : xn fp32 -> pk16 u16 (BLC u16 needed = BLC/2 floats, fits)
  // R2 = [BLC .. 2*BLC)       : xcbh bf16 -> gab bf16
  // R3 = [2*BLC .. 2.5*BLC)   : zh bf16 -> ycat bf16
  // R4 = [2.5B .. 3*BLC)      : xcvh bf16 -> yab bf16
  // R5 = [3*BLC .. 3.5*BLC)   : As bf16 -> ydir bf16
  float* xn   = ws;
  float* xcb  = ws + BLC;
  float* R3   = ws + 2 * BLC;
  float* R4   = R3 + BLC / 2;
  float* R5   = R4 + BLC / 2;
  float* pp   = R5 + BLC / 2;
  int*  sidx  = (int*)(pp + NB * 16 * CH);
  int*  inv   = sidx + NB * CH;
  u16*  wip   = (u16*)(inv + NB * CH);   // 2*384*192
  u16*  wop   = wip + 2 * 384 * 192;     // 2*192*192
  u16*  wpj   = wop + 2 * 192 * 192;     // 384*384
  u16*  w1g   = wpj + 384 * 384;         // NB*32*384
  u16*  w2p   = w1g + NB * 32 * CH;      // 384*32
  u16*  Mw    = w2p + CH * 32;           // 4*192*192
  u16*  cwb   = Mw + 4 * 192 * 192;      // 2*9*192
  float* b1p  = (float*)(cwb + 2 * 9 * DH);
  float* Atab = b1p + 32;                // 4*192
  u16*  hidp  = (u16*)(Atab + 4 * 192);  // NB*4096*32
  float* bc   = (float*)(hidp + (long)NB * LTOK * 32);  // 32*4096*2
  float* cP   = bc + 32 * LTOK * 2;
  float* cS   = cP + CST;
  float* h0   = cS + CST;

  size_t need = ((size_t)(2 * BLC) + 3 * (BLC / 2) + NB * 16 * CH + 32 * LTOK * 2 + 3 * CST + 64) * 4
              + (size_t)(2 * NB * CH) * 4 + (size_t)(4 * 192 + 32) * 4
              + ((size_t)2*384*192 + 2*192*192 + 384*384 + NB*32*CH + CH*32 + 4*192*192
                 + 2*9*DH + (size_t)NB * LTOK * 32) * 2
              + 8192;
  if (ws_size < need) return;

  // aliases
  u16*  As   = (u16*)R5;
  u16*  zh   = (u16*)R3;
  u16*  xcbh = (u16*)xcb;               // bf16 conv input
  u16*  xcvh = (u16*)R4;
  u16*  pk16 = (u16*)ws;                // bf16 dt stash in R1 (xn dead after castgather)
  u16*  ydir = (u16*)R5;
  u16*  yab  = (u16*)R4;
  u16*  ycat = (u16*)R3;
  u16*  gab  = (u16*)xcb;               // R2, free after conv

  k_ln<<<NB * LTOK, 128, 0, stream>>>(x, norm_g, norm_b, xn);
  k_cast<<<(2*384*192 + 255)/256, 256, 0, stream>>>(in_proj, wip, 2*384*192);
  k_cast<<<(2*192*192 + 255)/256, 256, 0, stream>>>(op_w,    wop, 2*192*192);
  k_cast<<<(384*384   + 255)/256, 256, 0, stream>>>(proj_w,  wpj, 384*384);
  k_prepA<<<3, 256, 0, stream>>>(A_log, Atab);
  k_prepcw<<<(2*9*DH + 255)/256, 256, 0, stream>>>(conv_w, cwb);
  k_prepM<<<dim3(144, 4), 256, 0, stream>>>(dt_w, xp_w, Mw);
  k_pool<<<dim3(3, 16, NB), 128, 0, stream>>>(xn, pp);
  k_score<<<NB, 384, 0, stream>>>(pp, r_w1, r_b1, r_w2, r_b2, sidx, inv);
  k_castgather<<<NB * LTOK, 384, 0, stream>>>(xn, sidx, As);
  k_prepw<<<NB + 1, 256, 0, stream>>>(ci_w1, ci_b1, ci_w2, sidx, w1g, w2p, b1p);

  // in_proj: per (b,g): [4096x192]@[384x192]^T -> xcbh bf16 + zh bf16
  k_mm<128, 1><<<dim3(3, 32, 16), 256, 0, stream>>>(
      As, CH, (long)LTOK * CH, 192,
      wip, (long)384 * 192,
      (float*)xcbh, zh, (long)2 * LTOK * DH, (long)LTOK * DH, 0,
      192, 2, nullptr, nullptr, nullptr, nullptr, nullptr);

  // gate stage 1 (uses As; before R5 is recycled by scan p3)
  k_hid<<<dim3(32, NB), 256, 0, stream>>>(As, w1g, b1p, hidp);

  // conv + fused B/C projection
  k_conv<<<dim3(LTOK / 8, NB * 2), 192, 0, stream>>>(xcbh, cwb, conv_b, xp_w, xcvh, bc);

  // fused dt GEMM + chunk scan (p1) -> pk16 (dt bf16) + cP/cS
  k_dt<<<dim3(3, 32, 32), 256, 0, stream>>>(xcvh, Mw, dt_b, Atab, bc, pk16, cP, cS);

  k_scan_p2<<<32, 192, 0, stream>>>(cP, cS, h0);
  k_scan_p3<<<dim3(NB * 2, NCHK), 192, 0, stream>>>(pk16, xcvh, bc, Atab, Ds, h0, ydir);

  k_combine<<<dim3(LTOK, NB * 2), 192, 0, stream>>>(ydir, zh, on_g, on_b, yab);

  // out_proj: per (b,g): [4096x192]@[192x192]^T -> ycat bf16 (col offset g*192)
  k_mm<64, 2><<<dim3(3, 32, 16), 256, 0, stream>>>(
      yab, DH, (long)2 * LTOK * DH, (long)LTOK * DH,
      wop, (long)192 * 192,
      nullptr, ycat, (long)LTOK * CH, 192, CH,
      192, 2, nullptr, nullptr, nullptr, nullptr, nullptr);

  // gate stage 2 + un-sort gather + multiply
  k_mm<128, 4><<<dim3(3, 256, 1), 256, 0, stream>>>(
      hidp, 32, 0, 0,
      w2p, 0,
      nullptr, gab, 0, 0, CH,
      32, 1, ci_b2, nullptr, nullptr, ycat, inv);

  // final: out = x + skip * (gab @ proj_w^T + proj_b)
  k_mm<128, 3><<<dim3(3, 256, 1), 256, 0, stream>>>(
      gab, CH, 0, 0,
      wpj, 0,
      out, nullptr, 0, 0, CH,
      CH, 1, proj_b, x, skip, nullptr, nullptr);
}

// Round 11
// 369.782 us; speedup vs baseline: 22.7335x; 1.0687x over previous
//
#include <hip/hip_runtime.h>
#include <math.h>

// Problem constants (fixed by the reference module)
#define NB 8
#define LTOK 4096
#define CH 384
#define DH 192
#define HH 64
#define WW 64
#define NCHK 128     // chunks per sequence
#define CHS 32       // steps per chunk (LTOK / NCHK)

static constexpr long BLC  = (long)NB * LTOK * CH;   // 12,582,912 elements
static constexpr long CST  = (long)32 * NCHK * DH;   // 786,432 per chunk-state buffer

typedef unsigned short u16;
typedef u16   u16x8 __attribute__((ext_vector_type(8)));
typedef short s16x8 __attribute__((ext_vector_type(8)));
typedef float f32x4 __attribute__((ext_vector_type(4)));

__device__ inline u16 f2bf(float f){
  unsigned int u = __float_as_uint(f);
  return (u16)((u + 0x7FFFu + ((u >> 16) & 1u)) >> 16);
}
__device__ inline float bf2f(u16 h){ return __uint_as_float(((unsigned int)h) << 16); }
__device__ inline float fsigmoid(float x){ return 1.f / (1.f + __expf(-x)); }

// LDS scan-buffer column swizzle: spreads kg-lanes across banks (2-way max)
#define SCOL(ml, c) ((c) ^ ((((ml) >> 2) & 3) << 4))

template<int NW>
__device__ inline float blockSum(float v, float* sm){
  #pragma unroll
  for (int o = 32; o > 0; o >>= 1) v += __shfl_down(v, o);
  int lane = threadIdx.x & 63, wv = threadIdx.x >> 6;
  if (lane == 0) sm[wv] = v;
  __syncthreads();
  if (threadIdx.x == 0){ float t = 0.f; for (int i = 0; i < NW; i++) t += sm[i]; sm[0] = t; }
  __syncthreads();
  float t = sm[0];
  __syncthreads();
  return t;
}

// ---------------- LayerNorm over C=384 per token ----------------
__global__ __launch_bounds__(128) void k_ln(const float* __restrict__ x,
    const float* __restrict__ g, const float* __restrict__ b, float* __restrict__ xn){
  __shared__ float sm[2];
  long row = blockIdx.x;
  int t = threadIdx.x;
  const float* xr = x + row * CH;
  float v0 = xr[t], v1 = xr[t + 128], v2 = xr[t + 256];
  float s = blockSum<2>(v0 + v1 + v2, sm);
  float m = s * (1.f / CH);
  float d0 = v0 - m, d1 = v1 - m, d2 = v2 - m;
  float vs = blockSum<2>(d0*d0 + d1*d1 + d2*d2, sm);
  float inv = rsqrtf(vs * (1.f / CH) + 1e-5f);
  float* o = xn + row * CH;
  o[t]       = d0 * inv * g[t]       + b[t];
  o[t + 128] = d1 * inv * g[t + 128] + b[t + 128];
  o[t + 256] = d2 * inv * g[t + 256] + b[t + 256];
}

// ---------------- partial pooling ----------------
__global__ __launch_bounds__(128) void k_pool(const float* __restrict__ xn, float* __restrict__ pp){
  int c = blockIdx.x * 128 + threadIdx.x;
  int chunk = blockIdx.y, b = blockIdx.z;
  long base = ((long)b * LTOK + chunk * 256) * CH;
  float s = 0.f;
  for (int n = 0; n < 256; n++) s += xn[base + (long)n * CH + c];
  pp[((long)b * 16 + chunk) * CH + c] = s;
}

// ---------------- score MLP + stable argsort (descending) ----------------
__global__ __launch_bounds__(384) void k_score(const float* __restrict__ pp,
    const float* __restrict__ w1, const float* __restrict__ b1,
    const float* __restrict__ w2, const float* __restrict__ b2,
    int* __restrict__ sidx, int* __restrict__ inv){
  __shared__ float poolv[CH];
  __shared__ float hid[192];
  __shared__ float sc[CH];
  int b = blockIdx.x, t = threadIdx.x;
  float s = 0.f;
  for (int ch = 0; ch < 16; ch++) s += pp[((long)b * 16 + ch) * CH + t];
  poolv[t] = s * (1.f / LTOK);
  __syncthreads();
  if (t < 192){
    float h = b1[t];
    for (int c = 0; c < CH; c++) h += poolv[c] * w1[t * CH + c];
    hid[t] = fmaxf(h, 0.f);
  }
  __syncthreads();
  {
    float h = b2[t];
    for (int j = 0; j < 192; j++) h += hid[j] * w2[t * 192 + j];
    sc[t] = 1.f / (1.f + expf(-h));
  }
  __syncthreads();
  float mys = sc[t];
  int rank = 0;
  for (int j = 0; j < CH; j++){
    float o = sc[j];
    rank += (o > mys) || (o == mys && j < t);
  }
  sidx[b * CH + rank] = t;
  inv[b * CH + t] = rank;
}

// ---------------- cast fp32 -> bf16 (weights) ----------------
__global__ __launch_bounds__(256) void k_cast(const float* __restrict__ s,
    u16* __restrict__ d, int n){
  int i = blockIdx.x * 256 + threadIdx.x;
  if (i < n) d[i] = f2bf(s[i]);
}

// ---------------- precompute A table: Atab = -exp(A_log) ----------------
__global__ __launch_bounds__(256) void k_prepA(const float* __restrict__ alog,
    float* __restrict__ Atab){
  int i = blockIdx.x * 256 + threadIdx.x;
  if (i < 4 * 192) Atab[i] = -expf(alog[i]);
}

// ---------------- prep conv weights: tap-major bf16 [g][9][DH] ----------------
__global__ __launch_bounds__(256) void k_prepcw(const float* __restrict__ cw,
    u16* __restrict__ cwb){
  int i = blockIdx.x * 256 + threadIdx.x;
  if (i < 2 * 9 * DH){
    int g = i / (9 * DH); int r = i - g * 9 * DH;
    int tap = r / DH; int di = r - tap * DH;
    cwb[i] = f2bf(cw[((long)g * DH + di) * 9 + tap]);
  }
}

// ---------------- gather sorted channels + cast to bf16 ----------------
__global__ __launch_bounds__(384) void k_castgather(const float* __restrict__ xn,
    const int* __restrict__ sidx, u16* __restrict__ As){
  long row = blockIdx.x;
  int b = (int)(row >> 12);
  int t = threadIdx.x;
  int c = sidx[b * CH + t];
  As[row * CH + t] = f2bf(xn[row * CH + c]);
}

// ---------------- prep gate-MLP weights: gathered w1 (per batch), padded w2, b1 ----------------
__global__ __launch_bounds__(256) void k_prepw(const float* __restrict__ w1,
    const float* __restrict__ b1, const float* __restrict__ w2,
    const int* __restrict__ sidx, u16* __restrict__ w1g, u16* __restrict__ w2p,
    float* __restrict__ b1p){
  int b = blockIdx.x, tid = threadIdx.x;
  if (b < NB){
    const int* sx = sidx + b * CH;
    for (int i = tid; i < 32 * CH; i += 256){
      int j = i / CH, r = i - j * CH;
      float v = (j < 24) ? w1[j * CH + sx[r]] : 0.f;
      w1g[(long)b * 32 * CH + i] = f2bf(v);
    }
  } else {
    for (int i = tid; i < CH * 32; i += 256){
      int n = i >> 5, j = i & 31;
      w2p[i] = f2bf((j < 24) ? w2[n * 24 + j] : 0.f);
    }
    if (tid < 32) b1p[tid] = (tid < 24) ? b1[tid] : 0.f;
  }
}

// ---------------- prep fused dt matrices ----------------
__global__ __launch_bounds__(256) void k_prepM(const float* __restrict__ dtw,
    const float* __restrict__ xpw, u16* __restrict__ Mw){
  int gk = blockIdx.y;
  int g = gk >> 1, k = gk & 1;
  int idx = blockIdx.x * 256 + threadIdx.x;   // < 36864
  int di = idx / 192, c = idx - di * 192;
  float s = 0.f;
  #pragma unroll
  for (int r = 0; r < 12; r++)
    s += dtw[((long)gk * 192 + di) * 12 + r] * xpw[(long)g * 5376 + (k * 14 + r) * 192 + c];
  Mw[(long)gk * 36864 + idx] = f2bf(s);
}

// ---------------- gate stage 1: hid = relu(As @ w1g^T + b1p), bf16 out ----------------
__global__ __launch_bounds__(256) void k_hid(const u16* __restrict__ As,
    const u16* __restrict__ w1g, const float* __restrict__ b1p,
    u16* __restrict__ hidp){
  __shared__ u16 sA[128 * 32];
  __shared__ u16 sB[32 * 32];
  int b = blockIdx.y;
  const u16* Ab = As + (long)b * LTOK * CH;
  const u16* Bb = w1g + (long)b * 32 * CH;
  int tid = threadIdx.x;
  int m0 = blockIdx.x * 128;
  int wv = tid >> 6, l = tid & 63;
  int wm = wv * 32;
  int kg = l >> 4, lr = l & 15;

  f32x4 acc[2][2];
  #pragma unroll
  for (int i = 0; i < 2; i++)
    #pragma unroll
    for (int j = 0; j < 2; j++)
      #pragma unroll
      for (int r = 0; r < 4; r++) acc[i][j][r] = 0.f;

  int aoffU[2], boffU[2];
  #pragma unroll
  for (int i = 0; i < 2; i++){
    int r = wm + i * 16 + lr;
    aoffU[i] = r * 32 + ((kg * 8) ^ ((r & 3) << 3));
  }
  #pragma unroll
  for (int j = 0; j < 2; j++){
    int r = j * 16 + lr;
    boffU[j] = r * 32 + ((kg * 8) ^ ((r & 3) << 3));
  }

  u16x8 ra[2], rbv;
  #pragma unroll
  for (int q = 0; q < 2; q++){
    int i = q * 256 + tid; int row = i >> 2, sl = i & 3, ss = sl ^ (row & 3);
    ra[q] = *(const u16x8*)(Ab + (long)(m0 + row) * CH + ss * 8);
  }
  if (tid < 128){
    int row = tid >> 2, sl = tid & 3, ss = sl ^ (row & 3);
    rbv = *(const u16x8*)(Bb + (long)row * CH + ss * 8);
  }

  const int nks = CH / 32;   // 12
  for (int ks = 0; ks < nks; ks++){
    __syncthreads();
    #pragma unroll
    for (int q = 0; q < 2; q++){
      int i = q * 256 + tid; int row = i >> 2, sl = i & 3;
      *(u16x8*)(sA + row * 32 + sl * 8) = ra[q];
    }
    if (tid < 128){
      int row = tid >> 2, sl = tid & 3;
      *(u16x8*)(sB + row * 32 + sl * 8) = rbv;
    }
    __syncthreads();
    if (ks + 1 < nks){
      int k0 = (ks + 1) * 32;
      #pragma unroll
      for (int q = 0; q < 2; q++){
        int i = q * 256 + tid; int row = i >> 2, sl = i & 3, ss = sl ^ (row & 3);
        ra[q] = *(const u16x8*)(Ab + (long)(m0 + row) * CH + k0 + ss * 8);
      }
      if (tid < 128){
        int row = tid >> 2, sl = tid & 3, ss = sl ^ (row & 3);
        rbv = *(const u16x8*)(Bb + (long)row * CH + k0 + ss * 8);
      }
    }
    s16x8 af[2], bfr[2];
    #pragma unroll
    for (int i = 0; i < 2; i++) af[i] = *(const s16x8*)(sA + aoffU[i]);
    #pragma unroll
    for (int j = 0; j < 2; j++) bfr[j] = *(const s16x8*)(sB + boffU[j]);
    #pragma unroll
    for (int i = 0; i < 2; i++)
      #pragma unroll
      for (int j = 0; j < 2; j++)
        acc[i][j] = __builtin_amdgcn_mfma_f32_16x16x32_bf16(af[i], bfr[j], acc[i][j], 0, 0, 0);
  }

  #pragma unroll
  for (int i = 0; i < 2; i++)
    #pragma unroll
    for (int j = 0; j < 2; j++)
      #pragma unroll
      for (int r = 0; r < 4; r++){
        int m = m0 + wm + i * 16 + kg * 4 + r;
        int n = j * 16 + lr;
        float v = fmaxf(acc[i][j][r] + b1p[n], 0.f);
        hidp[((long)b * LTOK + m) * 32 + n] = f2bf(v);
      }
}

// ---------------- bf16 MFMA GEMM: C = A @ B^T ----------------
// MODE 1: split epilogue: n<192 -> ((u16*)Cf) bf16 [m*192+n]; n>=192 -> Ch bf16 [m*192+n-192]
// MODE 2: Ch bf16 [m*ldc+n]
// MODE 3: Cf fp32 = resid + skip*(v + bias[n])
// MODE 4: gate = sigmoid(v+bias[n]); Ch[m*ldc+n] = bf16(gate * bf2f(gy[m*ldc+ginv[(m>>12)*CH+n]]))
template<int BN, int MODE>
__global__ __launch_bounds__(256) void k_mm(
    const u16* __restrict__ A, int lda, long aOuter, long aInner,
    const u16* __restrict__ B, long bInner,
    float* __restrict__ Cf, u16* __restrict__ Ch,
    long cOuter, long cInner, int ldc,
    int K, int innerCnt,
    const float* __restrict__ bias, const float* __restrict__ resid,
    const float* __restrict__ skip,
    const u16* __restrict__ gy, const int* __restrict__ ginv){
  constexpr int BM = 128;
  constexpr int AI = 2;
  constexpr int BI = (BN * 32) / (256 * 8);
  constexpr int NJ = BN / 32;
  __shared__ u16 sA[BM * 32];
  __shared__ u16 sB[BN * 32];

  int bz = blockIdx.z;
  int bo = bz / innerCnt, bi_ = bz - bo * innerCnt;
  const u16* Ab = A + (long)bo * aOuter + (long)bi_ * aInner;
  const u16* Bb = B + (long)bi_ * bInner;
  int tid = threadIdx.x;
  int m0 = blockIdx.y * BM, n0 = blockIdx.x * BN;
  int wv = tid >> 6, l = tid & 63;
  int wm = (wv >> 1) * 64, wn = (wv & 1) * (BN / 2);
  int kg = l >> 4, lr = l & 15;

  f32x4 acc[4][NJ];
  #pragma unroll
  for (int i = 0; i < 4; i++)
    #pragma unroll
    for (int j = 0; j < NJ; j++)
      #pragma unroll
      for (int r = 0; r < 4; r++) acc[i][j][r] = 0.f;

  int aoffU[4], boffU[NJ];
  #pragma unroll
  for (int i = 0; i < 4; i++){
    int r = wm + i * 16 + lr;
    aoffU[i] = r * 32 + ((kg * 8) ^ ((r & 3) << 3));
  }
  #pragma unroll
  for (int j = 0; j < NJ; j++){
    int r = wn + j * 16 + lr;
    boffU[j] = r * 32 + ((kg * 8) ^ ((r & 3) << 3));
  }

  u16x8 ra[AI], rb[BI];
  #pragma unroll
  for (int q = 0; q < AI; q++){
    int i = q * 256 + tid; int row = i >> 2, sl = i & 3, ss = sl ^ (row & 3);
    ra[q] = *(const u16x8*)(Ab + (long)(m0 + row) * lda + ss * 8);
  }
  #pragma unroll
  for (int q = 0; q < BI; q++){
    int i = q * 256 + tid; int row = i >> 2, sl = i & 3, ss = sl ^ (row & 3);
    rb[q] = *(const u16x8*)(Bb + (long)(n0 + row) * K + ss * 8);
  }

  int nks = K >> 5;
  for (int ks = 0; ks < nks; ks++){
    __syncthreads();
    #pragma unroll
    for (int q = 0; q < AI; q++){
      int i = q * 256 + tid; int row = i >> 2, sl = i & 3;
      *(u16x8*)(sA + row * 32 + sl * 8) = ra[q];
    }
    #pragma unroll
    for (int q = 0; q < BI; q++){
      int i = q * 256 + tid; int row = i >> 2, sl = i & 3;
      *(u16x8*)(sB + row * 32 + sl * 8) = rb[q];
    }
    __syncthreads();
    if (ks + 1 < nks){
      int k0 = (ks + 1) * 32;
      #pragma unroll
      for (int q = 0; q < AI; q++){
        int i = q * 256 + tid; int row = i >> 2, sl = i & 3, ss = sl ^ (row & 3);
        ra[q] = *(const u16x8*)(Ab + (long)(m0 + row) * lda + k0 + ss * 8);
      }
      #pragma unroll
      for (int q = 0; q < BI; q++){
        int i = q * 256 + tid; int row = i >> 2, sl = i & 3, ss = sl ^ (row & 3);
        rb[q] = *(const u16x8*)(Bb + (long)(n0 + row) * K + k0 + ss * 8);
      }
    }
    s16x8 af[4];
    #pragma unroll
    for (int i = 0; i < 4; i++) af[i] = *(const s16x8*)(sA + aoffU[i]);
    s16x8 bfr[NJ];
    #pragma unroll
    for (int j = 0; j < NJ; j++) bfr[j] = *(const s16x8*)(sB + boffU[j]);
    #pragma unroll
    for (int i = 0; i < 4; i++)
      #pragma unroll
      for (int j = 0; j < NJ; j++)
        acc[i][j] = __builtin_amdgcn_mfma_f32_16x16x32_bf16(af[i], bfr[j], acc[i][j], 0, 0, 0);
  }

  long zc = (long)bo * cOuter + (long)bi_ * cInner;
  #pragma unroll
  for (int i = 0; i < 4; i++){
    #pragma unroll
    for (int j = 0; j < NJ; j++){
      #pragma unroll
      for (int r = 0; r < 4; r++){
        int m = m0 + wm + i * 16 + kg * 4 + r;
        int n = n0 + wn + j * 16 + lr;
        float v = acc[i][j][r];
        if constexpr (MODE == 1){
          if (n < 192) ((u16*)Cf)[zc + (long)m * 192 + n] = f2bf(v);
          else         Ch[zc + (long)m * 192 + (n - 192)] = f2bf(v);
        } else if constexpr (MODE == 2){
          Ch[zc + (long)m * ldc + n] = f2bf(v);
        } else if constexpr (MODE == 3){
          float vb = v + bias[n];
          long o = (long)m * ldc + n;
          Cf[o] = resid[o] + skip[0] * vb;
        } else {
          float gate = fsigmoid(v + bias[n]);
          int bt = m >> 12;
          float yr = bf2f(gy[(long)m * ldc + ginv[bt * CH + n]]);
          Ch[(long)m * ldc + n] = f2bf(yr * gate);
        }
      }
    }
  }
}

// ---------------- fused dt GEMM + chunk-scan (p1) ----------------
// dtraw = xcvh @ M^T; epilogue: dt=softplus(raw+b), a=exp(A*dt), dBx=dt*B*x;
// xv tile staged in LDS; writes pk16 = bf16(dt); LDS chunk scan -> cP/cS.
__global__ __launch_bounds__(256) void k_dt(
    const u16* __restrict__ xcvh, const u16* __restrict__ Mw,
    const float* __restrict__ dtb, const float* __restrict__ Atab,
    const float* __restrict__ bc, u16* __restrict__ pk16,
    float* __restrict__ cP, float* __restrict__ cS){
  constexpr int BM = 128, AI = 2, NJ = 2;
  __shared__ unsigned sMem[BM * 64];     // 32 KB
  u16* sA  = (u16*)sMem;                 // [0, 8 KB)
  u16* sB  = (u16*)(sMem + 2048);        // [8 KB, 12 KB)
  u16* xvT = (u16*)(sMem + 3072);        // [12 KB, 30 KB): 128 x 72 u16 (stride-padded)

  int z = blockIdx.z;                 // bg*2 + k
  int bg = z >> 1, kk_ = z & 1, g = bg & 1, gk = g * 2 + kk_;
  const u16* Ab = xcvh + (long)bg * LTOK * 192;
  const u16* Bb = Mw + (long)gk * 36864;
  int tid = threadIdx.x;
  int m0 = blockIdx.y * BM, n0 = blockIdx.x * 64;
  int wv = tid >> 6, l = tid & 63;
  int wm = (wv >> 1) * 64, wn = (wv & 1) * 32;
  int kg = l >> 4, lr = l & 15;

  // stage xv tile (rows m0.., cols n0..n0+63) into LDS; region disjoint from sA/sB
  #pragma unroll
  for (int q = 0; q < 4; q++){
    int i8 = q * 256 + tid;            // 1024 u16x8 chunks
    int row = i8 >> 3, c8 = i8 & 7;
    u16x8 v = *(const u16x8*)(Ab + (long)(m0 + row) * 192 + n0 + c8 * 8);
    *(u16x8*)(xvT + row * 72 + c8 * 8) = v;
  }

  f32x4 acc[4][NJ];
  #pragma unroll
  for (int i = 0; i < 4; i++)
    #pragma unroll
    for (int j = 0; j < NJ; j++)
      #pragma unroll
      for (int r = 0; r < 4; r++) acc[i][j][r] = 0.f;

  int aoffU[4], boffU[NJ];
  #pragma unroll
  for (int i = 0; i < 4; i++){
    int r = wm + i * 16 + lr;
    aoffU[i] = r * 32 + ((kg * 8) ^ ((r & 3) << 3));
  }
  #pragma unroll
  for (int j = 0; j < NJ; j++){
    int r = wn + j * 16 + lr;
    boffU[j] = r * 32 + ((kg * 8) ^ ((r & 3) << 3));
  }

  u16x8 ra[AI], rb0;
  #pragma unroll
  for (int q = 0; q < AI; q++){
    int i = q * 256 + tid; int row = i >> 2, sl = i & 3, ss = sl ^ (row & 3);
    ra[q] = *(const u16x8*)(Ab + (long)(m0 + row) * 192 + ss * 8);
  }
  {
    int row = tid >> 2, sl = tid & 3, ss = sl ^ (row & 3);
    rb0 = *(const u16x8*)(Bb + (long)(n0 + row) * 192 + ss * 8);
  }

  const int nks = 6;   // K = 192
  for (int ks = 0; ks < nks; ks++){
    __syncthreads();
    #pragma unroll
    for (int q = 0; q < AI; q++){
      int i = q * 256 + tid; int row = i >> 2, sl = i & 3;
      *(u16x8*)(sA + row * 32 + sl * 8) = ra[q];
    }
    {
      int row = tid >> 2, sl = tid & 3;
      *(u16x8*)(sB + row * 32 + sl * 8) = rb0;
    }
    __syncthreads();
    if (ks + 1 < nks){
      int k0 = (ks + 1) * 32;
      #pragma unroll
      for (int q = 0; q < AI; q++){
        int i = q * 256 + tid; int row = i >> 2, sl = i & 3, ss = sl ^ (row & 3);
        ra[q] = *(const u16x8*)(Ab + (long)(m0 + row) * 192 + k0 + ss * 8);
      }
      {
        int row = tid >> 2, sl = tid & 3, ss = sl ^ (row & 3);
        rb0 = *(const u16x8*)(Bb + (long)(n0 + row) * 192 + k0 + ss * 8);
      }
    }
    s16x8 af[4], bfr[NJ];
    #pragma unroll
    for (int i = 0; i < 4; i++) af[i] = *(const s16x8*)(sA + aoffU[i]);
    #pragma unroll
    for (int j = 0; j < NJ; j++) bfr[j] = *(const s16x8*)(sB + boffU[j]);
    #pragma unroll
    for (int i = 0; i < 4; i++)
      #pragma unroll
      for (int j = 0; j < NJ; j++)
        acc[i][j] = __builtin_amdgcn_mfma_f32_16x16x32_bf16(af[i], bfr[j], acc[i][j], 0, 0, 0);
  }

  // epilogue: dt/a/dBx; xv from LDS; keep packed (dBx,a) in registers
  unsigned pkreg[4][NJ][4];
  float dtbj[NJ], Atlj[NJ];
  #pragma unroll
  for (int j = 0; j < NJ; j++){
    int n = n0 + wn + j * 16 + lr;
    dtbj[j] = dtb[gk * 192 + n];
    Atlj[j] = Atab[gk * 192 + n];
  }
  #pragma unroll
  for (int i = 0; i < 4; i++){
    #pragma unroll
    for (int r = 0; r < 4; r++){
      int ml = wm + i * 16 + kg * 4 + r;
      int m = m0 + ml;
      float Bv = bc[((long)z * LTOK + m) * 2];
      #pragma unroll
      for (int j = 0; j < NJ; j++){
        int n = n0 + wn + j * 16 + lr;
        float rr = acc[i][j][r] + dtbj[j];
        float dtv = __logf(1.f + __expf(rr));
        float av  = __expf(Atlj[j] * dtv);
        float xv  = bf2f(xvT[ml * 72 + wn + j * 16 + lr]);
        pk16[((long)z * LTOK + m) * 192 + n] = f2bf(dtv);
        pkreg[i][j][r] = ((unsigned)f2bf(dtv * Bv * xv) << 16) | (unsigned)f2bf(av);
      }
    }
  }

  __syncthreads();   // all waves done reading sA/sB/xvT
  #pragma unroll
  for (int i = 0; i < 4; i++){
    #pragma unroll
    for (int j = 0; j < NJ; j++){
      #pragma unroll
      for (int r = 0; r < 4; r++){
        int ml = wm + i * 16 + kg * 4 + r;
        int cl = wn + j * 16 + lr;
        sMem[ml * 64 + SCOL(ml, cl)] = pkreg[i][j][r];
      }
    }
  }
  __syncthreads();

  // chunk scan: thread = (chunk-in-tile, channel)
  int cc = tid >> 6, nn = tid & 63;
  float P = 1.f, S = 0.f;
  if (kk_ == 0){
    for (int s = 0; s < CHS; s++){
      int row = cc * CHS + s;
      unsigned v = sMem[row * 64 + SCOL(row, nn)];
      float a = bf2f((u16)(v & 0xFFFFu));
      float dBx = bf2f((u16)(v >> 16));
      P *= a; S = a * S + dBx;
    }
  } else {
    for (int s = CHS - 1; s >= 0; s--){
      int row = cc * CHS + s;
      unsigned v = sMem[row * 64 + SCOL(row, nn)];
      float a = bf2f((u16)(v & 0xFFFFu));
      float dBx = bf2f((u16)(v >> 16));
      P *= a; S = a * S + dBx;
    }
  }
  int cglob = (kk_ == 0) ? (blockIdx.y * 4 + cc)
                         : ((LTOK - m0) / CHS - cc - 1);
  long idx = ((long)z * NCHK + cglob) * 192 + n0 + nn;
  cP[idx] = P;
  cS[idx] = S;
}

// ---------------- depthwise 3x3 conv (u16x8/thread) + fused B/C projection ----------------
__global__ __launch_bounds__(192) void k_conv(const u16* __restrict__ xch,
    const u16* __restrict__ cwb, const float* __restrict__ cb,
    const float* __restrict__ xpw, u16* __restrict__ xcvh,
    float* __restrict__ bc){
  __shared__ float red[8][4][25];
  int tid = threadIdx.x;
  int chg = tid % 24, pp = tid / 24;    // 24 channel-groups x 8 positions
  int p = blockIdx.x * 8 + pp;
  int bg = blockIdx.y; int g = bg & 1;
  int h = p >> 6, w = p & 63;
  int di = chg * 8;
  long sb = (long)bg * LTOK;

  u16x8 wv[9];
  #pragma unroll
  for (int t = 0; t < 9; t++)
    wv[t] = *(const u16x8*)(cwb + ((long)g * 9 + t) * DH + di);

  float acc[8];
  #pragma unroll
  for (int j = 0; j < 8; j++) acc[j] = cb[g * DH + di + j];

  #pragma unroll
  for (int dh = -1; dh <= 1; dh++){
    int hh = h + dh; if (hh < 0 || hh >= HH) continue;
    #pragma unroll
    for (int dw = -1; dw <= 1; dw++){
      int ww2 = w + dw; if (ww2 < 0 || ww2 >= WW) continue;
      u16x8 xv = *(const u16x8*)(xch + (sb + hh * WW + ww2) * DH + di);
      int t = (dh + 1) * 3 + (dw + 1);
      #pragma unroll
      for (int j = 0; j < 8; j++) acc[j] += bf2f(wv[t][j]) * bf2f(xv[j]);
    }
  }

  u16x8 ov;
  #pragma unroll
  for (int j = 0; j < 8; j++){
    float s = acc[j];
    acc[j] = s * fsigmoid(s);         // post-silu fp32, reused for B/C dot
    ov[j] = f2bf(acc[j]);
  }
  int lscan = (g == 0) ? p : (w * HH + h);
  *(u16x8*)(xcvh + (sb + lscan) * DH + di) = ov;

  // B/C projection partials
  #pragma unroll
  for (int j = 0; j < 4; j++){
    int k = j >> 1, ci = j & 1;
    const float* wl = xpw + (long)g * 5376 + (k * 14 + 12 + ci) * 192 + di;
    float sacc = 0.f;
    #pragma unroll
    for (int q = 0; q < 8; q++) sacc += acc[q] * wl[q];
    red[pp][j][chg] = sacc;
  }
  __syncthreads();
  if (tid < 32){
    int pos = tid >> 2, j = tid & 3;
    float ssum = 0.f;
    #pragma unroll
    for (int q = 0; q < 24; q++) ssum += red[pos][j][q];
    int p2 = blockIdx.x * 8 + pos;
    int h2 = p2 >> 6, w2 = p2 & 63;
    int ls = (g == 0) ? p2 : (w2 * HH + h2);
    int k = j >> 1;
    bc[(((long)(bg * 2 + k)) * LTOK + ls) * 2 + (j & 1)] = ssum;
  }
}

// ---------------- scan p2: sequential composition over 128 chunks ----------------
__global__ __launch_bounds__(192) void k_scan_p2(const float* __restrict__ cP,
    const float* __restrict__ cS, float* __restrict__ h0){
  int z = blockIdx.x;              // 0..31
  int di = threadIdx.x;
  float h = 0.f;
  for (int c = 0; c < NCHK; c++){
    long idx = ((long)z * NCHK + c) * 192 + di;
    h0[idx] = h;
    h = cP[idx] * h + cS[idx];
  }
}

// ---------------- scan p3 fused: both directions in regs + out-LN + silu(z) -> yab ----------------
__global__ __launch_bounds__(192) void k_scan_p3(const u16* __restrict__ pk16,
    const u16* __restrict__ xcvh, const float* __restrict__ bc,
    const float* __restrict__ Atab, const float* __restrict__ ds,
    const float* __restrict__ h0, const u16* __restrict__ zh,
    const float* __restrict__ ong, const float* __restrict__ onb,
    u16* __restrict__ yab){
  __shared__ float yl[CHS][193];
  __shared__ float red[2][32][6];
  __shared__ float minv[2][32];
  int bg = blockIdx.x, c = blockIdx.y;
  int g = bg & 1;
  int di = threadIdx.x;
  const u16* xc = xcvh + (long)bg * LTOK * 192 + di;
  int l0 = c * CHS;
  float yv[CHS];

  // forward direction (k=0)
  {
    int z = bg * 2, gk = g * 2;
    float Dv = ds[gk * 192 + di], Av = Atab[gk * 192 + di];
    const u16* pk = pk16 + (long)z * LTOK * 192 + di;
    const float* bcp = bc + (long)z * LTOK * 2;
    float h = h0[((long)z * NCHK + c) * 192 + di];
    #pragma unroll
    for (int s = 0; s < CHS; s++){
      int l = l0 + s;
      float dtv = bf2f(pk[(long)l * 192]);
      float av  = __expf(Av * dtv);
      float xv  = bf2f(xc[(long)l * 192]);
      float Bv  = bcp[l * 2], Cv = bcp[l * 2 + 1];
      h = av * h + dtv * Bv * xv;
      yv[s] = h * Cv + Dv * xv;
    }
  }
  // backward direction (k=1) covers the same positions
  {
    int z = bg * 2 + 1, gk = g * 2 + 1;
    float Dv = ds[gk * 192 + di], Av = Atab[gk * 192 + di];
    const u16* pk = pk16 + (long)z * LTOK * 192 + di;
    const float* bcp = bc + (long)z * LTOK * 2;
    int cc = NCHK - 1 - c;
    float h = h0[((long)z * NCHK + cc) * 192 + di];
    #pragma unroll
    for (int s = CHS - 1; s >= 0; s--){
      int l = l0 + s;
      float dtv = bf2f(pk[(long)l * 192]);
      float av  = __expf(Av * dtv);
      float xv  = bf2f(xc[(long)l * 192]);
      float Bv  = bcp[l * 2], Cv = bcp[l * 2 + 1];
      h = av * h + dtv * Bv * xv;
      yv[s] += h * Cv + Dv * xv;
    }
  }

  // out-LN across channels per position (192 threads = all channels)
  #pragma unroll
  for (int s = 0; s < CHS; s++) yl[s][di] = yv[s];
  __syncthreads();
  {
    int pos = di & 31, seg = di >> 5;
    float s1 = 0.f, s2 = 0.f;
    #pragma unroll
    for (int q = 0; q < 32; q++){
      float v = yl[pos][seg * 32 + q];
      s1 += v; s2 += v * v;
    }
    red[0][pos][seg] = s1;
    red[1][pos][seg] = s2;
  }
  __syncthreads();
  if (di < 32){
    float s1 = 0.f, s2 = 0.f;
    #pragma unroll
    for (int q = 0; q < 6; q++){ s1 += red[0][di][q]; s2 += red[1][di][q]; }
    float m = s1 * (1.f / DH);
    float var = s2 * (1.f / DH) - m * m;
    minv[0][di] = m;
    minv[1][di] = rsqrtf(var + 1e-5f);
  }
  __syncthreads();

  float gng = ong[g * 192 + di], gnb = onb[g * 192 + di];
  long zbase = (long)bg * LTOK;
  #pragma unroll
  for (int s = 0; s < CHS; s++){
    int l = l0 + s;
    int p = (g == 0) ? l : ((l & 63) * 64 + (l >> 6));
    float m = minv[0][s], inv = minv[1][s];
    float yln = (yv[s] - m) * inv * gng + gnb;
    float z = bf2f(zh[(zbase + p) * 192 + di]);
    yab[(zbase + p) * 192 + di] = f2bf(yln * z * fsigmoid(z));
  }
}

extern "C" void kernel_launch(void* const* d_in, const int* in_sizes, int n_in,
                              void* d_out, int out_size, void* d_ws, size_t ws_size,
                              hipStream_t stream){
  const float* x       = (const float*)d_in[0];
  const float* norm_g  = (const float*)d_in[1];
  const float* norm_b  = (const float*)d_in[2];
  const float* r_w1    = (const float*)d_in[3];
  const float* r_b1    = (const float*)d_in[4];
  const float* r_w2    = (const float*)d_in[5];
  const float* r_b2    = (const float*)d_in[6];
  const float* in_proj = (const float*)d_in[7];
  const float* conv_w  = (const float*)d_in[8];
  const float* conv_b  = (const float*)d_in[9];
  const float* xp_w    = (const float*)d_in[10];
  const float* dt_w    = (const float*)d_in[11];
  const float* dt_b    = (const float*)d_in[12];
  const float* A_log   = (const float*)d_in[13];
  const float* Ds      = (const float*)d_in[14];
  const float* on_g    = (const float*)d_in[15];
  const float* on_b    = (const float*)d_in[16];
  const float* op_w    = (const float*)d_in[17];
  const float* ci_w1   = (const float*)d_in[18];
  const float* ci_b1   = (const float*)d_in[19];
  const float* ci_w2   = (const float*)d_in[20];
  const float* ci_b2   = (const float*)d_in[21];
  const float* proj_w  = (const float*)d_in[22];
  const float* proj_b  = (const float*)d_in[23];
  const float* skip    = (const float*)d_in[24];
  float* out = (float*)d_out;
  float* ws  = (float*)d_ws;

  // Regions (floats):
  // R1 = ws[0 .. BLC)         : xn fp32 -> pk16 u16
  // R2 = [BLC .. 2*BLC)       : xcbh bf16 -> gab bf16
  // R3 = [2*BLC .. 2.5*BLC)   : zh bf16 -> ycat bf16
  // R4 = [2.5B .. 3*BLC)      : xcvh bf16
  // R5 = [3*BLC .. 3.5*BLC)   : As bf16 -> yab bf16
  float* xn   = ws;
  float* xcb  = ws + BLC;
  float* R3   = ws + 2 * BLC;
  float* R4   = R3 + BLC / 2;
  float* R5   = R4 + BLC / 2;
  float* pp   = R5 + BLC / 2;
  int*  sidx  = (int*)(pp + NB * 16 * CH);
  int*  inv   = sidx + NB * CH;
  u16*  wip   = (u16*)(inv + NB * CH);   // 2*384*192
  u16*  wop   = wip + 2 * 384 * 192;     // 2*192*192
  u16*  wpj   = wop + 2 * 192 * 192;     // 384*384
  u16*  w1g   = wpj + 384 * 384;         // NB*32*384
  u16*  w2p   = w1g + NB * 32 * CH;      // 384*32
  u16*  Mw    = w2p + CH * 32;           // 4*192*192
  u16*  cwb   = Mw + 4 * 192 * 192;      // 2*9*192
  float* b1p  = (float*)(cwb + 2 * 9 * DH);
  float* Atab = b1p + 32;                // 4*192
  u16*  hidp  = (u16*)(Atab + 4 * 192);  // NB*4096*32
  float* bc   = (float*)(hidp + (long)NB * LTOK * 32);  // 32*4096*2
  float* cP   = bc + 32 * LTOK * 2;
  float* cS   = cP + CST;
  float* h0   = cS + CST;

  size_t need = ((size_t)(2 * BLC) + 3 * (BLC / 2) + NB * 16 * CH + 32 * LTOK * 2 + 3 * CST + 64) * 4
              + (size_t)(2 * NB * CH) * 4 + (size_t)(4 * 192 + 32) * 4
              + ((size_t)2*384*192 + 2*192*192 + 384*384 + NB*32*CH + CH*32 + 4*192*192
                 + 2*9*DH + (size_t)NB * LTOK * 32) * 2
              + 8192;
  if (ws_size < need) return;

  // aliases
  u16*  As   = (u16*)R5;
  u16*  zh   = (u16*)R3;
  u16*  xcbh = (u16*)xcb;               // bf16 conv input (R2)
  u16*  xcvh = (u16*)R4;
  u16*  pk16 = (u16*)ws;                // bf16 dt stash in R1 (xn dead after castgather)
  u16*  yab  = (u16*)R5;                // As dead after k_hid
  u16*  ycat = (u16*)R3;                // zh dead after fused p3
  u16*  gab  = (u16*)xcb;               // R2, xcbh dead after conv

  k_ln<<<NB * LTOK, 128, 0, stream>>>(x, norm_g, norm_b, xn);
  k_cast<<<(2*384*192 + 255)/256, 256, 0, stream>>>(in_proj, wip, 2*384*192);
  k_cast<<<(2*192*192 + 255)/256, 256, 0, stream>>>(op_w,    wop, 2*192*192);
  k_cast<<<(384*384   + 255)/256, 256, 0, stream>>>(proj_w,  wpj, 384*384);
  k_prepA<<<3, 256, 0, stream>>>(A_log, Atab);
  k_prepcw<<<(2*9*DH + 255)/256, 256, 0, stream>>>(conv_w, cwb);
  k_prepM<<<dim3(144, 4), 256, 0, stream>>>(dt_w, xp_w, Mw);
  k_pool<<<dim3(3, 16, NB), 128, 0, stream>>>(xn, pp);
  k_score<<<NB, 384, 0, stream>>>(pp, r_w1, r_b1, r_w2, r_b2, sidx, inv);
  k_castgather<<<NB * LTOK, 384, 0, stream>>>(xn, sidx, As);
  k_prepw<<<NB + 1, 256, 0, stream>>>(ci_w1, ci_b1, ci_w2, sidx, w1g, w2p, b1p);

  // in_proj: per (b,g): [4096x192]@[384x192]^T -> xcbh bf16 + zh bf16
  k_mm<128, 1><<<dim3(3, 32, 16), 256, 0, stream>>>(
      As, CH, (long)LTOK * CH, 192,
      wip, (long)384 * 192,
      (float*)xcbh, zh, (long)2 * LTOK * DH, (long)LTOK * DH, 0,
      192, 2, nullptr, nullptr, nullptr, nullptr, nullptr);

  // gate stage 1 (uses As; before R5 is recycled as yab)
  k_hid<<<dim3(32, NB), 256, 0, stream>>>(As, w1g, b1p, hidp);

  // conv + fused B/C projection
  k_conv<<<dim3(LTOK / 8, NB * 2), 192, 0, stream>>>(xcbh, cwb, conv_b, xp_w, xcvh, bc);

  // fused dt GEMM + chunk scan (p1) -> pk16 (dt bf16) + cP/cS
  k_dt<<<dim3(3, 32, 32), 256, 0, stream>>>(xcvh, Mw, dt_b, Atab, bc, pk16, cP, cS);

  k_scan_p2<<<32, 192, 0, stream>>>(cP, cS, h0);

  // fused p3: both directions + out-LN + silu(z) -> yab
  k_scan_p3<<<dim3(NB * 2, NCHK), 192, 0, stream>>>(
      pk16, xcvh, bc, Atab, Ds, h0, zh, on_g, on_b, yab);

  // out_proj: per (b,g): [4096x192]@[192x192]^T -> ycat bf16 (col offset g*192)
  k_mm<64, 2><<<dim3(3, 32, 16), 256, 0, stream>>>(
      yab, DH, (long)2 * LTOK * DH, (long)LTOK * DH,
      wop, (long)192 * 192,
      nullptr, ycat, (long)LTOK * CH, 192, CH,
      192, 2, nullptr, nullptr, nullptr, nullptr, nullptr);

  // gate stage 2 + un-sort gather + multiply
  k_mm<128, 4><<<dim3(3, 256, 1), 256, 0, stream>>>(
      hidp, 32, 0, 0,
      w2p, 0,
      nullptr, gab, 0, 0, CH,
      32, 1, ci_b2, nullptr, nullptr, ycat, inv);

  // final: out = x + skip * (gab @ proj_w^T + proj_b)
  k_mm<128, 3><<<dim3(3, 256, 1), 256, 0, stream>>>(
      gab, CH, 0, 0,
      wpj, 0,
      out, nullptr, 0, 0, CH,
      CH, 1, proj_b, x, skip, nullptr, nullptr);
}

// Round 12
// 357.207 us; speedup vs baseline: 23.5338x; 1.0352x over previous
//
#include <hip/hip_runtime.h>
#include <math.h>

// Problem constants (fixed by the reference module)
#define NB 8
#define LTOK 4096
#define CH 384
#define DH 192
#define HH 64
#define WW 64
#define NCHK 128     // chunks per sequence
#define CHS 32       // steps per chunk (LTOK / NCHK)

static constexpr long BLC  = (long)NB * LTOK * CH;   // 12,582,912 elements
static constexpr long CST  = (long)32 * NCHK * DH;   // 786,432 per chunk-state buffer

typedef unsigned short u16;
typedef u16   u16x8 __attribute__((ext_vector_type(8)));
typedef short s16x8 __attribute__((ext_vector_type(8)));
typedef float f32x4 __attribute__((ext_vector_type(4)));

__device__ inline u16 f2bf(float f){
  unsigned int u = __float_as_uint(f);
  return (u16)((u + 0x7FFFu + ((u >> 16) & 1u)) >> 16);
}
__device__ inline float bf2f(u16 h){ return __uint_as_float(((unsigned int)h) << 16); }
__device__ inline float fsigmoid(float x){ return 1.f / (1.f + __expf(-x)); }

// LDS scan-buffer column swizzle: spreads kg-lanes across banks (2-way max)
#define SCOL(ml, c) ((c) ^ ((((ml) >> 2) & 3) << 4))

template<int NW>
__device__ inline float blockSum(float v, float* sm){
  #pragma unroll
  for (int o = 32; o > 0; o >>= 1) v += __shfl_down(v, o);
  int lane = threadIdx.x & 63, wv = threadIdx.x >> 6;
  if (lane == 0) sm[wv] = v;
  __syncthreads();
  if (threadIdx.x == 0){ float t = 0.f; for (int i = 0; i < NW; i++) t += sm[i]; sm[0] = t; }
  __syncthreads();
  float t = sm[0];
  __syncthreads();
  return t;
}

// ---------------- LayerNorm over C=384 per token ----------------
__global__ __launch_bounds__(128) void k_ln(const float* __restrict__ x,
    const float* __restrict__ g, const float* __restrict__ b, float* __restrict__ xn){
  __shared__ float sm[2];
  long row = blockIdx.x;
  int t = threadIdx.x;
  const float* xr = x + row * CH;
  float v0 = xr[t], v1 = xr[t + 128], v2 = xr[t + 256];
  float s = blockSum<2>(v0 + v1 + v2, sm);
  float m = s * (1.f / CH);
  float d0 = v0 - m, d1 = v1 - m, d2 = v2 - m;
  float vs = blockSum<2>(d0*d0 + d1*d1 + d2*d2, sm);
  float inv = rsqrtf(vs * (1.f / CH) + 1e-5f);
  float* o = xn + row * CH;
  o[t]       = d0 * inv * g[t]       + b[t];
  o[t + 128] = d1 * inv * g[t + 128] + b[t + 128];
  o[t + 256] = d2 * inv * g[t + 256] + b[t + 256];
}

// ---------------- partial pooling ----------------
__global__ __launch_bounds__(128) void k_pool(const float* __restrict__ xn, float* __restrict__ pp){
  int c = blockIdx.x * 128 + threadIdx.x;
  int chunk = blockIdx.y, b = blockIdx.z;
  long base = ((long)b * LTOK + chunk * 256) * CH;
  float s = 0.f;
  for (int n = 0; n < 256; n++) s += xn[base + (long)n * CH + c];
  pp[((long)b * 16 + chunk) * CH + c] = s;
}

// ---------------- score MLP + stable argsort (descending) ----------------
__global__ __launch_bounds__(384) void k_score(const float* __restrict__ pp,
    const float* __restrict__ w1, const float* __restrict__ b1,
    const float* __restrict__ w2, const float* __restrict__ b2,
    int* __restrict__ sidx, int* __restrict__ inv){
  __shared__ float poolv[CH];
  __shared__ float hid[192];
  __shared__ float sc[CH];
  int b = blockIdx.x, t = threadIdx.x;
  float s = 0.f;
  for (int ch = 0; ch < 16; ch++) s += pp[((long)b * 16 + ch) * CH + t];
  poolv[t] = s * (1.f / LTOK);
  __syncthreads();
  if (t < 192){
    float h = b1[t];
    for (int c = 0; c < CH; c++) h += poolv[c] * w1[t * CH + c];
    hid[t] = fmaxf(h, 0.f);
  }
  __syncthreads();
  {
    float h = b2[t];
    for (int j = 0; j < 192; j++) h += hid[j] * w2[t * 192 + j];
    sc[t] = 1.f / (1.f + expf(-h));
  }
  __syncthreads();
  float mys = sc[t];
  int rank = 0;
  for (int j = 0; j < CH; j++){
    float o = sc[j];
    rank += (o > mys) || (o == mys && j < t);
  }
  sidx[b * CH + rank] = t;
  inv[b * CH + t] = rank;
}

// ---------------- cast fp32 -> bf16 (weights) ----------------
__global__ __launch_bounds__(256) void k_cast(const float* __restrict__ s,
    u16* __restrict__ d, int n){
  int i = blockIdx.x * 256 + threadIdx.x;
  if (i < n) d[i] = f2bf(s[i]);
}

// ---------------- precompute A table: Atab = -exp(A_log) ----------------
__global__ __launch_bounds__(256) void k_prepA(const float* __restrict__ alog,
    float* __restrict__ Atab){
  int i = blockIdx.x * 256 + threadIdx.x;
  if (i < 4 * 192) Atab[i] = -expf(alog[i]);
}

// ---------------- prep conv weights: tap-major bf16 [g][9][DH] ----------------
__global__ __launch_bounds__(256) void k_prepcw(const float* __restrict__ cw,
    u16* __restrict__ cwb){
  int i = blockIdx.x * 256 + threadIdx.x;
  if (i < 2 * 9 * DH){
    int g = i / (9 * DH); int r = i - g * 9 * DH;
    int tap = r / DH; int di = r - tap * DH;
    cwb[i] = f2bf(cw[((long)g * DH + di) * 9 + tap]);
  }
}

// ---------------- gather sorted channels + cast to bf16 ----------------
__global__ __launch_bounds__(384) void k_castgather(const float* __restrict__ xn,
    const int* __restrict__ sidx, u16* __restrict__ As){
  long row = blockIdx.x;
  int b = (int)(row >> 12);
  int t = threadIdx.x;
  int c = sidx[b * CH + t];
  As[row * CH + t] = f2bf(xn[row * CH + c]);
}

// ---------------- prep gate-MLP weights: gathered w1 (per batch), padded w2, b1 ----------------
__global__ __launch_bounds__(256) void k_prepw(const float* __restrict__ w1,
    const float* __restrict__ b1, const float* __restrict__ w2,
    const int* __restrict__ sidx, u16* __restrict__ w1g, u16* __restrict__ w2p,
    float* __restrict__ b1p){
  int b = blockIdx.x, tid = threadIdx.x;
  if (b < NB){
    const int* sx = sidx + b * CH;
    for (int i = tid; i < 32 * CH; i += 256){
      int j = i / CH, r = i - j * CH;
      float v = (j < 24) ? w1[j * CH + sx[r]] : 0.f;
      w1g[(long)b * 32 * CH + i] = f2bf(v);
    }
  } else {
    for (int i = tid; i < CH * 32; i += 256){
      int n = i >> 5, j = i & 31;
      w2p[i] = f2bf((j < 24) ? w2[n * 24 + j] : 0.f);
    }
    if (tid < 32) b1p[tid] = (tid < 24) ? b1[tid] : 0.f;
  }
}

// ---------------- prep fused dt matrices ----------------
__global__ __launch_bounds__(256) void k_prepM(const float* __restrict__ dtw,
    const float* __restrict__ xpw, u16* __restrict__ Mw){
  int gk = blockIdx.y;
  int g = gk >> 1, k = gk & 1;
  int idx = blockIdx.x * 256 + threadIdx.x;   // < 36864
  int di = idx / 192, c = idx - di * 192;
  float s = 0.f;
  #pragma unroll
  for (int r = 0; r < 12; r++)
    s += dtw[((long)gk * 192 + di) * 12 + r] * xpw[(long)g * 5376 + (k * 14 + r) * 192 + c];
  Mw[(long)gk * 36864 + idx] = f2bf(s);
}

// ---------------- gate stage 1: hid = relu(As @ w1g^T + b1p), bf16 out ----------------
__global__ __launch_bounds__(256) void k_hid(const u16* __restrict__ As,
    const u16* __restrict__ w1g, const float* __restrict__ b1p,
    u16* __restrict__ hidp){
  __shared__ u16 sA[128 * 32];
  __shared__ u16 sB[32 * 32];
  int b = blockIdx.y;
  const u16* Ab = As + (long)b * LTOK * CH;
  const u16* Bb = w1g + (long)b * 32 * CH;
  int tid = threadIdx.x;
  int m0 = blockIdx.x * 128;
  int wv = tid >> 6, l = tid & 63;
  int wm = wv * 32;
  int kg = l >> 4, lr = l & 15;

  f32x4 acc[2][2];
  #pragma unroll
  for (int i = 0; i < 2; i++)
    #pragma unroll
    for (int j = 0; j < 2; j++)
      #pragma unroll
      for (int r = 0; r < 4; r++) acc[i][j][r] = 0.f;

  int aoffU[2], boffU[2];
  #pragma unroll
  for (int i = 0; i < 2; i++){
    int r = wm + i * 16 + lr;
    aoffU[i] = r * 32 + ((kg * 8) ^ ((r & 3) << 3));
  }
  #pragma unroll
  for (int j = 0; j < 2; j++){
    int r = j * 16 + lr;
    boffU[j] = r * 32 + ((kg * 8) ^ ((r & 3) << 3));
  }

  u16x8 ra[2], rbv;
  #pragma unroll
  for (int q = 0; q < 2; q++){
    int i = q * 256 + tid; int row = i >> 2, sl = i & 3, ss = sl ^ (row & 3);
    ra[q] = *(const u16x8*)(Ab + (long)(m0 + row) * CH + ss * 8);
  }
  if (tid < 128){
    int row = tid >> 2, sl = tid & 3, ss = sl ^ (row & 3);
    rbv = *(const u16x8*)(Bb + (long)row * CH + ss * 8);
  }

  const int nks = CH / 32;   // 12
  for (int ks = 0; ks < nks; ks++){
    __syncthreads();
    #pragma unroll
    for (int q = 0; q < 2; q++){
      int i = q * 256 + tid; int row = i >> 2, sl = i & 3;
      *(u16x8*)(sA + row * 32 + sl * 8) = ra[q];
    }
    if (tid < 128){
      int row = tid >> 2, sl = tid & 3;
      *(u16x8*)(sB + row * 32 + sl * 8) = rbv;
    }
    __syncthreads();
    if (ks + 1 < nks){
      int k0 = (ks + 1) * 32;
      #pragma unroll
      for (int q = 0; q < 2; q++){
        int i = q * 256 + tid; int row = i >> 2, sl = i & 3, ss = sl ^ (row & 3);
        ra[q] = *(const u16x8*)(Ab + (long)(m0 + row) * CH + k0 + ss * 8);
      }
      if (tid < 128){
        int row = tid >> 2, sl = tid & 3, ss = sl ^ (row & 3);
        rbv = *(const u16x8*)(Bb + (long)row * CH + k0 + ss * 8);
      }
    }
    s16x8 af[2], bfr[2];
    #pragma unroll
    for (int i = 0; i < 2; i++) af[i] = *(const s16x8*)(sA + aoffU[i]);
    #pragma unroll
    for (int j = 0; j < 2; j++) bfr[j] = *(const s16x8*)(sB + boffU[j]);
    #pragma unroll
    for (int i = 0; i < 2; i++)
      #pragma unroll
      for (int j = 0; j < 2; j++)
        acc[i][j] = __builtin_amdgcn_mfma_f32_16x16x32_bf16(af[i], bfr[j], acc[i][j], 0, 0, 0);
  }

  #pragma unroll
  for (int i = 0; i < 2; i++)
    #pragma unroll
    for (int j = 0; j < 2; j++)
      #pragma unroll
      for (int r = 0; r < 4; r++){
        int m = m0 + wm + i * 16 + kg * 4 + r;
        int n = j * 16 + lr;
        float v = fmaxf(acc[i][j][r] + b1p[n], 0.f);
        hidp[((long)b * LTOK + m) * 32 + n] = f2bf(v);
      }
}

// ---------------- bf16 MFMA GEMM: C = A @ B^T ----------------
// MODE 1: split epilogue: n<192 -> ((u16*)Cf) bf16 [m*192+n]; n>=192 -> Ch bf16 silu(v)
// MODE 2: Ch bf16 [m*ldc+n]
// MODE 3: Cf fp32 = resid + skip*(v + bias[n])
// MODE 4: gate = sigmoid(v+bias[n]); Ch[m*ldc+n] = bf16(gate * bf2f(gy[m*ldc+ginv[(m>>12)*CH+n]]))
template<int BN, int MODE>
__global__ __launch_bounds__(256) void k_mm(
    const u16* __restrict__ A, int lda, long aOuter, long aInner,
    const u16* __restrict__ B, long bInner,
    float* __restrict__ Cf, u16* __restrict__ Ch,
    long cOuter, long cInner, int ldc,
    int K, int innerCnt,
    const float* __restrict__ bias, const float* __restrict__ resid,
    const float* __restrict__ skip,
    const u16* __restrict__ gy, const int* __restrict__ ginv){
  constexpr int BM = 128;
  constexpr int AI = 2;
  constexpr int BI = (BN * 32) / (256 * 8);
  constexpr int NJ = BN / 32;
  __shared__ u16 sA[BM * 32];
  __shared__ u16 sB[BN * 32];

  int bz = blockIdx.z;
  int bo = bz / innerCnt, bi_ = bz - bo * innerCnt;
  const u16* Ab = A + (long)bo * aOuter + (long)bi_ * aInner;
  const u16* Bb = B + (long)bi_ * bInner;
  int tid = threadIdx.x;
  int m0 = blockIdx.y * BM, n0 = blockIdx.x * BN;
  int wv = tid >> 6, l = tid & 63;
  int wm = (wv >> 1) * 64, wn = (wv & 1) * (BN / 2);
  int kg = l >> 4, lr = l & 15;

  f32x4 acc[4][NJ];
  #pragma unroll
  for (int i = 0; i < 4; i++)
    #pragma unroll
    for (int j = 0; j < NJ; j++)
      #pragma unroll
      for (int r = 0; r < 4; r++) acc[i][j][r] = 0.f;

  int aoffU[4], boffU[NJ];
  #pragma unroll
  for (int i = 0; i < 4; i++){
    int r = wm + i * 16 + lr;
    aoffU[i] = r * 32 + ((kg * 8) ^ ((r & 3) << 3));
  }
  #pragma unroll
  for (int j = 0; j < NJ; j++){
    int r = wn + j * 16 + lr;
    boffU[j] = r * 32 + ((kg * 8) ^ ((r & 3) << 3));
  }

  u16x8 ra[AI], rb[BI];
  #pragma unroll
  for (int q = 0; q < AI; q++){
    int i = q * 256 + tid; int row = i >> 2, sl = i & 3, ss = sl ^ (row & 3);
    ra[q] = *(const u16x8*)(Ab + (long)(m0 + row) * lda + ss * 8);
  }
  #pragma unroll
  for (int q = 0; q < BI; q++){
    int i = q * 256 + tid; int row = i >> 2, sl = i & 3, ss = sl ^ (row & 3);
    rb[q] = *(const u16x8*)(Bb + (long)(n0 + row) * K + ss * 8);
  }

  int nks = K >> 5;
  for (int ks = 0; ks < nks; ks++){
    __syncthreads();
    #pragma unroll
    for (int q = 0; q < AI; q++){
      int i = q * 256 + tid; int row = i >> 2, sl = i & 3;
      *(u16x8*)(sA + row * 32 + sl * 8) = ra[q];
    }
    #pragma unroll
    for (int q = 0; q < BI; q++){
      int i = q * 256 + tid; int row = i >> 2, sl = i & 3;
      *(u16x8*)(sB + row * 32 + sl * 8) = rb[q];
    }
    __syncthreads();
    if (ks + 1 < nks){
      int k0 = (ks + 1) * 32;
      #pragma unroll
      for (int q = 0; q < AI; q++){
        int i = q * 256 + tid; int row = i >> 2, sl = i & 3, ss = sl ^ (row & 3);
        ra[q] = *(const u16x8*)(Ab + (long)(m0 + row) * lda + k0 + ss * 8);
      }
      #pragma unroll
      for (int q = 0; q < BI; q++){
        int i = q * 256 + tid; int row = i >> 2, sl = i & 3, ss = sl ^ (row & 3);
        rb[q] = *(const u16x8*)(Bb + (long)(n0 + row) * K + k0 + ss * 8);
      }
    }
    s16x8 af[4];
    #pragma unroll
    for (int i = 0; i < 4; i++) af[i] = *(const s16x8*)(sA + aoffU[i]);
    s16x8 bfr[NJ];
    #pragma unroll
    for (int j = 0; j < NJ; j++) bfr[j] = *(const s16x8*)(sB + boffU[j]);
    #pragma unroll
    for (int i = 0; i < 4; i++)
      #pragma unroll
      for (int j = 0; j < NJ; j++)
        acc[i][j] = __builtin_amdgcn_mfma_f32_16x16x32_bf16(af[i], bfr[j], acc[i][j], 0, 0, 0);
  }

  long zc = (long)bo * cOuter + (long)bi_ * cInner;
  #pragma unroll
  for (int i = 0; i < 4; i++){
    #pragma unroll
    for (int j = 0; j < NJ; j++){
      #pragma unroll
      for (int r = 0; r < 4; r++){
        int m = m0 + wm + i * 16 + kg * 4 + r;
        int n = n0 + wn + j * 16 + lr;
        float v = acc[i][j][r];
        if constexpr (MODE == 1){
          if (n < 192) ((u16*)Cf)[zc + (long)m * 192 + n] = f2bf(v);
          else         Ch[zc + (long)m * 192 + (n - 192)] = f2bf(v * fsigmoid(v));
        } else if constexpr (MODE == 2){
          Ch[zc + (long)m * ldc + n] = f2bf(v);
        } else if constexpr (MODE == 3){
          float vb = v + bias[n];
          long o = (long)m * ldc + n;
          Cf[o] = resid[o] + skip[0] * vb;
        } else {
          float gate = fsigmoid(v + bias[n]);
          int bt = m >> 12;
          float yr = bf2f(gy[(long)m * ldc + ginv[bt * CH + n]]);
          Ch[(long)m * ldc + n] = f2bf(yr * gate);
        }
      }
    }
  }
}

// ---------------- fused dt GEMM + chunk-scan (p1), BM=64 for occupancy ----------------
// dtraw = xcvh @ M^T; epilogue: dt=softplus(raw+b), a=exp(A*dt), dBx=dt*B*x;
// writes pk16 = bf16(dt); LDS chunk scan (2 chunks x 64 ch) -> cP/cS.
__global__ __launch_bounds__(256) void k_dt(
    const u16* __restrict__ xcvh, const u16* __restrict__ Mw,
    const float* __restrict__ dtb, const float* __restrict__ Atab,
    const float* __restrict__ bc, u16* __restrict__ pk16,
    float* __restrict__ cP, float* __restrict__ cS){
  constexpr int NJ = 2;
  __shared__ unsigned sMem[64 * 64];     // 16 KB: GEMM staging (8 KB) then scan buffer
  u16* sA = (u16*)sMem;                  // 64*32 u16 = 4 KB
  u16* sB = (u16*)(sMem + 1024);         // 64*32 u16 = 4 KB

  int z = blockIdx.z;                 // bg*2 + k
  int bg = z >> 1, kk_ = z & 1, g = bg & 1, gk = g * 2 + kk_;
  const u16* Ab = xcvh + (long)bg * LTOK * 192;
  const u16* Bb = Mw + (long)gk * 36864;
  int tid = threadIdx.x;
  int m0 = blockIdx.y * 64, n0 = blockIdx.x * 64;
  int wv = tid >> 6, l = tid & 63;
  int wm = (wv >> 1) * 32, wn = (wv & 1) * 32;
  int kg = l >> 4, lr = l & 15;

  f32x4 acc[2][NJ];
  #pragma unroll
  for (int i = 0; i < 2; i++)
    #pragma unroll
    for (int j = 0; j < NJ; j++)
      #pragma unroll
      for (int r = 0; r < 4; r++) acc[i][j][r] = 0.f;

  int aoffU[2], boffU[NJ];
  #pragma unroll
  for (int i = 0; i < 2; i++){
    int r = wm + i * 16 + lr;
    aoffU[i] = r * 32 + ((kg * 8) ^ ((r & 3) << 3));
  }
  #pragma unroll
  for (int j = 0; j < NJ; j++){
    int r = wn + j * 16 + lr;
    boffU[j] = r * 32 + ((kg * 8) ^ ((r & 3) << 3));
  }

  int srow = tid >> 2, ssl = tid & 3, sss = ssl ^ (srow & 3);
  u16x8 ra, rb0;
  ra  = *(const u16x8*)(Ab + (long)(m0 + srow) * 192 + sss * 8);
  rb0 = *(const u16x8*)(Bb + (long)(n0 + srow) * 192 + sss * 8);

  const int nks = 6;   // K = 192
  for (int ks = 0; ks < nks; ks++){
    __syncthreads();
    *(u16x8*)(sA + srow * 32 + ssl * 8) = ra;
    *(u16x8*)(sB + srow * 32 + ssl * 8) = rb0;
    __syncthreads();
    if (ks + 1 < nks){
      int k0 = (ks + 1) * 32;
      ra  = *(const u16x8*)(Ab + (long)(m0 + srow) * 192 + k0 + sss * 8);
      rb0 = *(const u16x8*)(Bb + (long)(n0 + srow) * 192 + k0 + sss * 8);
    }
    s16x8 af[2], bfr[NJ];
    #pragma unroll
    for (int i = 0; i < 2; i++) af[i] = *(const s16x8*)(sA + aoffU[i]);
    #pragma unroll
    for (int j = 0; j < NJ; j++) bfr[j] = *(const s16x8*)(sB + boffU[j]);
    #pragma unroll
    for (int i = 0; i < 2; i++)
      #pragma unroll
      for (int j = 0; j < NJ; j++)
        acc[i][j] = __builtin_amdgcn_mfma_f32_16x16x32_bf16(af[i], bfr[j], acc[i][j], 0, 0, 0);
  }

  // epilogue: dt/a/dBx; xv from global (coalesced 16-lane rows)
  unsigned pkreg[2][NJ][4];
  float dtbj[NJ], Atlj[NJ];
  #pragma unroll
  for (int j = 0; j < NJ; j++){
    int n = n0 + wn + j * 16 + lr;
    dtbj[j] = dtb[gk * 192 + n];
    Atlj[j] = Atab[gk * 192 + n];
  }
  #pragma unroll
  for (int i = 0; i < 2; i++){
    #pragma unroll
    for (int r = 0; r < 4; r++){
      int ml = wm + i * 16 + kg * 4 + r;
      int m = m0 + ml;
      float Bv = bc[((long)z * LTOK + m) * 2];
      #pragma unroll
      for (int j = 0; j < NJ; j++){
        int n = n0 + wn + j * 16 + lr;
        float rr = acc[i][j][r] + dtbj[j];
        float dtv = __logf(1.f + __expf(rr));
        float av  = __expf(Atlj[j] * dtv);
        float xv  = bf2f(xcvh[((long)bg * LTOK + m) * 192 + n]);
        pk16[((long)z * LTOK + m) * 192 + n] = f2bf(dtv);
        pkreg[i][j][r] = ((unsigned)f2bf(dtv * Bv * xv) << 16) | (unsigned)f2bf(av);
      }
    }
  }

  __syncthreads();   // all waves done reading sA/sB
  #pragma unroll
  for (int i = 0; i < 2; i++){
    #pragma unroll
    for (int j = 0; j < NJ; j++){
      #pragma unroll
      for (int r = 0; r < 4; r++){
        int ml = wm + i * 16 + kg * 4 + r;
        int cl = wn + j * 16 + lr;
        sMem[ml * 64 + SCOL(ml, cl)] = pkreg[i][j][r];
      }
    }
  }
  __syncthreads();

  // chunk scan: thread = (chunk-in-tile 0..1, channel 0..63); tid >= 128 idle
  if (tid < 128){
    int cc = tid >> 6, nn = tid & 63;
    float P = 1.f, S = 0.f;
    if (kk_ == 0){
      for (int s = 0; s < CHS; s++){
        int row = cc * CHS + s;
        unsigned v = sMem[row * 64 + SCOL(row, nn)];
        float a = bf2f((u16)(v & 0xFFFFu));
        float dBx = bf2f((u16)(v >> 16));
        P *= a; S = a * S + dBx;
      }
    } else {
      for (int s = CHS - 1; s >= 0; s--){
        int row = cc * CHS + s;
        unsigned v = sMem[row * 64 + SCOL(row, nn)];
        float a = bf2f((u16)(v & 0xFFFFu));
        float dBx = bf2f((u16)(v >> 16));
        P *= a; S = a * S + dBx;
      }
    }
    int cglob = (kk_ == 0) ? (blockIdx.y * 2 + cc)
                           : (NCHK - 1 - blockIdx.y * 2 - cc);
    long idx = ((long)z * NCHK + cglob) * 192 + n0 + nn;
    cP[idx] = P;
    cS[idx] = S;
  }
}

// ---------------- depthwise 3x3 conv (u16x8/thread) + fused B/C projection ----------------
__global__ __launch_bounds__(192) void k_conv(const u16* __restrict__ xch,
    const u16* __restrict__ cwb, const float* __restrict__ cb,
    const float* __restrict__ xpw, u16* __restrict__ xcvh,
    float* __restrict__ bc){
  __shared__ float red[8][4][25];
  int tid = threadIdx.x;
  int chg = tid % 24, pp = tid / 24;    // 24 channel-groups x 8 positions
  int p = blockIdx.x * 8 + pp;
  int bg = blockIdx.y; int g = bg & 1;
  int h = p >> 6, w = p & 63;
  int di = chg * 8;
  long sb = (long)bg * LTOK;

  u16x8 wv[9];
  #pragma unroll
  for (int t = 0; t < 9; t++)
    wv[t] = *(const u16x8*)(cwb + ((long)g * 9 + t) * DH + di);

  float acc[8];
  #pragma unroll
  for (int j = 0; j < 8; j++) acc[j] = cb[g * DH + di + j];

  #pragma unroll
  for (int dh = -1; dh <= 1; dh++){
    int hh = h + dh; if (hh < 0 || hh >= HH) continue;
    #pragma unroll
    for (int dw = -1; dw <= 1; dw++){
      int ww2 = w + dw; if (ww2 < 0 || ww2 >= WW) continue;
      u16x8 xv = *(const u16x8*)(xch + (sb + hh * WW + ww2) * DH + di);
      int t = (dh + 1) * 3 + (dw + 1);
      #pragma unroll
      for (int j = 0; j < 8; j++) acc[j] += bf2f(wv[t][j]) * bf2f(xv[j]);
    }
  }

  u16x8 ov;
  #pragma unroll
  for (int j = 0; j < 8; j++){
    float s = acc[j];
    acc[j] = s * fsigmoid(s);         // post-silu fp32, reused for B/C dot
    ov[j] = f2bf(acc[j]);
  }
  int lscan = (g == 0) ? p : (w * HH + h);
  *(u16x8*)(xcvh + (sb + lscan) * DH + di) = ov;

  // B/C projection partials
  #pragma unroll
  for (int j = 0; j < 4; j++){
    int k = j >> 1, ci = j & 1;
    const float* wl = xpw + (long)g * 5376 + (k * 14 + 12 + ci) * 192 + di;
    float sacc = 0.f;
    #pragma unroll
    for (int q = 0; q < 8; q++) sacc += acc[q] * wl[q];
    red[pp][j][chg] = sacc;
  }
  __syncthreads();
  if (tid < 32){
    int pos = tid >> 2, j = tid & 3;
    float ssum = 0.f;
    #pragma unroll
    for (int q = 0; q < 24; q++) ssum += red[pos][j][q];
    int p2 = blockIdx.x * 8 + pos;
    int h2 = p2 >> 6, w2 = p2 & 63;
    int ls = (g == 0) ? p2 : (w2 * HH + h2);
    int k = j >> 1;
    bc[(((long)(bg * 2 + k)) * LTOK + ls) * 2 + (j & 1)] = ssum;
  }
}

// ---------------- scan p2: sequential composition over 128 chunks ----------------
__global__ __launch_bounds__(192) void k_scan_p2(const float* __restrict__ cP,
    const float* __restrict__ cS, float* __restrict__ h0){
  int z = blockIdx.x;              // 0..31
  int di = threadIdx.x;
  float h = 0.f;
  for (int c = 0; c < NCHK; c++){
    long idx = ((long)z * NCHK + c) * 192 + di;
    h0[idx] = h;
    h = cP[idx] * h + cS[idx];
  }
}

// ---------------- scan p3 fused: both directions in regs + out-LN + *siluz -> yab ----------------
__global__ __launch_bounds__(192) void k_scan_p3(const u16* __restrict__ pk16,
    const u16* __restrict__ xcvh, const float* __restrict__ bc,
    const float* __restrict__ Atab, const float* __restrict__ ds,
    const float* __restrict__ h0, const u16* __restrict__ zsh,
    const float* __restrict__ ong, const float* __restrict__ onb,
    u16* __restrict__ yab){
  __shared__ float yl[CHS][193];
  __shared__ float red[2][32][6];
  __shared__ float minv[2][32];
  int bg = blockIdx.x, c = blockIdx.y;
  int g = bg & 1;
  int di = threadIdx.x;
  const u16* xc = xcvh + (long)bg * LTOK * 192 + di;
  int l0 = c * CHS;
  float yv[CHS];

  // forward direction (k=0)
  {
    int z = bg * 2, gk = g * 2;
    float Dv = ds[gk * 192 + di], Av = Atab[gk * 192 + di];
    const u16* pk = pk16 + (long)z * LTOK * 192 + di;
    const float* bcp = bc + (long)z * LTOK * 2;
    float h = h0[((long)z * NCHK + c) * 192 + di];
    #pragma unroll
    for (int s = 0; s < CHS; s++){
      int l = l0 + s;
      float dtv = bf2f(pk[(long)l * 192]);
      float av  = __expf(Av * dtv);
      float xv  = bf2f(xc[(long)l * 192]);
      float Bv  = bcp[l * 2], Cv = bcp[l * 2 + 1];
      h = av * h + dtv * Bv * xv;
      yv[s] = h * Cv + Dv * xv;
    }
  }
  // backward direction (k=1) covers the same positions
  {
    int z = bg * 2 + 1, gk = g * 2 + 1;
    float Dv = ds[gk * 192 + di], Av = Atab[gk * 192 + di];
    const u16* pk = pk16 + (long)z * LTOK * 192 + di;
    const float* bcp = bc + (long)z * LTOK * 2;
    int cc = NCHK - 1 - c;
    float h = h0[((long)z * NCHK + cc) * 192 + di];
    #pragma unroll
    for (int s = CHS - 1; s >= 0; s--){
      int l = l0 + s;
      float dtv = bf2f(pk[(long)l * 192]);
      float av  = __expf(Av * dtv);
      float xv  = bf2f(xc[(long)l * 192]);
      float Bv  = bcp[l * 2], Cv = bcp[l * 2 + 1];
      h = av * h + dtv * Bv * xv;
      yv[s] += h * Cv + Dv * xv;
    }
  }

  // out-LN across channels per position (192 threads = all channels)
  #pragma unroll
  for (int s = 0; s < CHS; s++) yl[s][di] = yv[s];
  __syncthreads();
  {
    int pos = di & 31, seg = di >> 5;
    float s1 = 0.f, s2 = 0.f;
    #pragma unroll
    for (int q = 0; q < 32; q++){
      float v = yl[pos][seg * 32 + q];
      s1 += v; s2 += v * v;
    }
    red[0][pos][seg] = s1;
    red[1][pos][seg] = s2;
  }
  __syncthreads();
  if (di < 32){
    float s1 = 0.f, s2 = 0.f;
    #pragma unroll
    for (int q = 0; q < 6; q++){ s1 += red[0][di][q]; s2 += red[1][di][q]; }
    float m = s1 * (1.f / DH);
    float var = s2 * (1.f / DH) - m * m;
    minv[0][di] = m;
    minv[1][di] = rsqrtf(var + 1e-5f);
  }
  __syncthreads();

  float gng = ong[g * 192 + di], gnb = onb[g * 192 + di];
  long zbase = (long)bg * LTOK;
  #pragma unroll
  for (int s = 0; s < CHS; s++){
    int l = l0 + s;
    int p = (g == 0) ? l : ((l & 63) * 64 + (l >> 6));
    float m = minv[0][s], inv = minv[1][s];
    float yln = (yv[s] - m) * inv * gng + gnb;
    float zs = bf2f(zsh[(zbase + p) * 192 + di]);   // pre-silu'd z
    yab[(zbase + p) * 192 + di] = f2bf(yln * zs);
  }
}

extern "C" void kernel_launch(void* const* d_in, const int* in_sizes, int n_in,
                              void* d_out, int out_size, void* d_ws, size_t ws_size,
                              hipStream_t stream){
  const float* x       = (const float*)d_in[0];
  const float* norm_g  = (const float*)d_in[1];
  const float* norm_b  = (const float*)d_in[2];
  const float* r_w1    = (const float*)d_in[3];
  const float* r_b1    = (const float*)d_in[4];
  const float* r_w2    = (const float*)d_in[5];
  const float* r_b2    = (const float*)d_in[6];
  const float* in_proj = (const float*)d_in[7];
  const float* conv_w  = (const float*)d_in[8];
  const float* conv_b  = (const float*)d_in[9];
  const float* xp_w    = (const float*)d_in[10];
  const float* dt_w    = (const float*)d_in[11];
  const float* dt_b    = (const float*)d_in[12];
  const float* A_log   = (const float*)d_in[13];
  const float* Ds      = (const float*)d_in[14];
  const float* on_g    = (const float*)d_in[15];
  const float* on_b    = (const float*)d_in[16];
  const float* op_w    = (const float*)d_in[17];
  const float* ci_w1   = (const float*)d_in[18];
  const float* ci_b1   = (const float*)d_in[19];
  const float* ci_w2   = (const float*)d_in[20];
  const float* ci_b2   = (const float*)d_in[21];
  const float* proj_w  = (const float*)d_in[22];
  const float* proj_b  = (const float*)d_in[23];
  const float* skip    = (const float*)d_in[24];
  float* out = (float*)d_out;
  float* ws  = (float*)d_ws;

  // Regions (floats):
  // R1 = ws[0 .. BLC)         : xn fp32 -> pk16 u16
  // R2 = [BLC .. 2*BLC)       : xcbh bf16 -> gab bf16
  // R3 = [2*BLC .. 2.5*BLC)   : zsh bf16 -> ycat bf16
  // R4 = [2.5B .. 3*BLC)      : xcvh bf16
  // R5 = [3*BLC .. 3.5*BLC)   : As bf16 -> yab bf16
  float* xn   = ws;
  float* xcb  = ws + BLC;
  float* R3   = ws + 2 * BLC;
  float* R4   = R3 + BLC / 2;
  float* R5   = R4 + BLC / 2;
  float* pp   = R5 + BLC / 2;
  int*  sidx  = (int*)(pp + NB * 16 * CH);
  int*  inv   = sidx + NB * CH;
  u16*  wip   = (u16*)(inv + NB * CH);   // 2*384*192
  u16*  wop   = wip + 2 * 384 * 192;     // 2*192*192
  u16*  wpj   = wop + 2 * 192 * 192;     // 384*384
  u16*  w1g   = wpj + 384 * 384;         // NB*32*384
  u16*  w2p   = w1g + NB * 32 * CH;      // 384*32
  u16*  Mw    = w2p + CH * 32;           // 4*192*192
  u16*  cwb   = Mw + 4 * 192 * 192;      // 2*9*192
  float* b1p  = (float*)(cwb + 2 * 9 * DH);
  float* Atab = b1p + 32;                // 4*192
  u16*  hidp  = (u16*)(Atab + 4 * 192);  // NB*4096*32
  float* bc   = (float*)(hidp + (long)NB * LTOK * 32);  // 32*4096*2
  float* cP   = bc + 32 * LTOK * 2;
  float* cS   = cP + CST;
  float* h0   = cS + CST;

  size_t need = ((size_t)(2 * BLC) + 3 * (BLC / 2) + NB * 16 * CH + 32 * LTOK * 2 + 3 * CST + 64) * 4
              + (size_t)(2 * NB * CH) * 4 + (size_t)(4 * 192 + 32) * 4
              + ((size_t)2*384*192 + 2*192*192 + 384*384 + NB*32*CH + CH*32 + 4*192*192
                 + 2*9*DH + (size_t)NB * LTOK * 32) * 2
              + 8192;
  if (ws_size < need) return;

  // aliases
  u16*  As   = (u16*)R5;
  u16*  zsh  = (u16*)R3;                // silu(z) bf16
  u16*  xcbh = (u16*)xcb;               // bf16 conv input (R2)
  u16*  xcvh = (u16*)R4;
  u16*  pk16 = (u16*)ws;                // bf16 dt stash in R1 (xn dead after castgather)
  u16*  yab  = (u16*)R5;                // As dead after k_hid
  u16*  ycat = (u16*)R3;                // zsh dead after fused p3
  u16*  gab  = (u16*)xcb;               // R2, xcbh dead after conv

  k_ln<<<NB * LTOK, 128, 0, stream>>>(x, norm_g, norm_b, xn);
  k_cast<<<(2*384*192 + 255)/256, 256, 0, stream>>>(in_proj, wip, 2*384*192);
  k_cast<<<(2*192*192 + 255)/256, 256, 0, stream>>>(op_w,    wop, 2*192*192);
  k_cast<<<(384*384   + 255)/256, 256, 0, stream>>>(proj_w,  wpj, 384*384);
  k_prepA<<<3, 256, 0, stream>>>(A_log, Atab);
  k_prepcw<<<(2*9*DH + 255)/256, 256, 0, stream>>>(conv_w, cwb);
  k_prepM<<<dim3(144, 4), 256, 0, stream>>>(dt_w, xp_w, Mw);
  k_pool<<<dim3(3, 16, NB), 128, 0, stream>>>(xn, pp);
  k_score<<<NB, 384, 0, stream>>>(pp, r_w1, r_b1, r_w2, r_b2, sidx, inv);
  k_castgather<<<NB * LTOK, 384, 0, stream>>>(xn, sidx, As);
  k_prepw<<<NB + 1, 256, 0, stream>>>(ci_w1, ci_b1, ci_w2, sidx, w1g, w2p, b1p);

  // in_proj: per (b,g): [4096x192]@[384x192]^T -> xcbh bf16 + zsh=silu(z) bf16
  k_mm<128, 1><<<dim3(3, 32, 16), 256, 0, stream>>>(
      As, CH, (long)LTOK * CH, 192,
      wip, (long)384 * 192,
      (float*)xcbh, zsh, (long)2 * LTOK * DH, (long)LTOK * DH, 0,
      192, 2, nullptr, nullptr, nullptr, nullptr, nullptr);

  // gate stage 1 (uses As; before R5 is recycled as yab)
  k_hid<<<dim3(32, NB), 256, 0, stream>>>(As, w1g, b1p, hidp);

  // conv + fused B/C projection
  k_conv<<<dim3(LTOK / 8, NB * 2), 192, 0, stream>>>(xcbh, cwb, conv_b, xp_w, xcvh, bc);

  // fused dt GEMM + chunk scan (p1), BM=64 -> pk16 (dt bf16) + cP/cS
  k_dt<<<dim3(3, 64, 32), 256, 0, stream>>>(xcvh, Mw, dt_b, Atab, bc, pk16, cP, cS);

  k_scan_p2<<<32, 192, 0, stream>>>(cP, cS, h0);

  // fused p3: both directions + out-LN + *silu(z) -> yab
  k_scan_p3<<<dim3(NB * 2, NCHK), 192, 0, stream>>>(
      pk16, xcvh, bc, Atab, Ds, h0, zsh, on_g, on_b, yab);

  // out_proj: per (b,g): [4096x192]@[192x192]^T -> ycat bf16 (col offset g*192)
  k_mm<64, 2><<<dim3(3, 32, 16), 256, 0, stream>>>(
      yab, DH, (long)2 * LTOK * DH, (long)LTOK * DH,
      wop, (long)192 * 192,
      nullptr, ycat, (long)LTOK * CH, 192, CH,
      192, 2, nullptr, nullptr, nullptr, nullptr, nullptr);

  // gate stage 2 + un-sort gather + multiply
  k_mm<128, 4><<<dim3(3, 256, 1), 256, 0, stream>>>(
      hidp, 32, 0, 0,
      w2p, 0,
      nullptr, gab, 0, 0, CH,
      32, 1, ci_b2, nullptr, nullptr, ycat, inv);

  // final: out = x + skip * (gab @ proj_w^T + proj_b)
  k_mm<128, 3><<<dim3(3, 256, 1), 256, 0, stream>>>(
      gab, CH, 0, 0,
      wpj, 0,
      out, nullptr, 0, 0, CH,
      CH, 1, proj_b, x, skip, nullptr, nullptr);
}